// Round 1
// baseline (5500.103 us; speedup 1.0000x reference)
//
#include <hip/hip_runtime.h>
#include <hip/hip_bf16.h>
#include <math.h>

#define B_ 16
#define Q_ 256
#define K_ 4096
#define DIM_ 1024
#define H_ 16
#define HD_ 64
#define MQ_ 64
#define QP_ 65
#define SCALE_INV 0.125f

// ---------------- GEMM: C[M,1024] = A[M,1024] @ W[1024,1024]^T (+bias) -------
#define GM 128
#define GN 128
#define GK 16

__global__ __launch_bounds__(256) void gemm_nt(
    const float* __restrict__ A, const float* __restrict__ W,
    float* __restrict__ C, int M, const float* __restrict__ bias) {
  __shared__ float As[GK][GM + 4];
  __shared__ float Ws[GK][GN + 4];
  const int t = threadIdx.x;
  const int m0 = blockIdx.x * GM;
  const int n0 = blockIdx.y * GN;
  const int lrow = t >> 2;
  const int lq = (t & 3) * 4;
  const int tm = (t >> 4) * 8;
  const int tn = (t & 15) * 8;
  float acc[8][8];
#pragma unroll
  for (int i = 0; i < 8; ++i)
#pragma unroll
    for (int j = 0; j < 8; ++j) acc[i][j] = 0.f;

  for (int k0 = 0; k0 < DIM_; k0 += GK) {
#pragma unroll
    for (int half = 0; half < 2; ++half) {
      const int row = lrow + half * 64;
      const int gm = m0 + row;
      float4 av = make_float4(0.f, 0.f, 0.f, 0.f);
      if (gm < M) av = *(const float4*)&A[(size_t)gm * DIM_ + k0 + lq];
      As[lq + 0][row] = av.x; As[lq + 1][row] = av.y;
      As[lq + 2][row] = av.z; As[lq + 3][row] = av.w;
      const int gn = n0 + row;
      const float4 wv = *(const float4*)&W[(size_t)gn * DIM_ + k0 + lq];
      Ws[lq + 0][row] = wv.x; Ws[lq + 1][row] = wv.y;
      Ws[lq + 2][row] = wv.z; Ws[lq + 3][row] = wv.w;
    }
    __syncthreads();
#pragma unroll
    for (int kk = 0; kk < GK; ++kk) {
      float a[8], bb[8];
      *(float4*)&a[0] = *(const float4*)&As[kk][tm];
      *(float4*)&a[4] = *(const float4*)&As[kk][tm + 4];
      *(float4*)&bb[0] = *(const float4*)&Ws[kk][tn];
      *(float4*)&bb[4] = *(const float4*)&Ws[kk][tn + 4];
#pragma unroll
      for (int i = 0; i < 8; ++i)
#pragma unroll
        for (int j = 0; j < 8; ++j)
          acc[i][j] = fmaf(a[i], bb[j], acc[i][j]);
    }
    __syncthreads();
  }
#pragma unroll
  for (int i = 0; i < 8; ++i) {
    const int gm = m0 + tm + i;
    if (gm < M) {
#pragma unroll
      for (int j = 0; j < 8; j += 4) {
        const int gn = n0 + tn + j;
        float4 ov;
        ov.x = acc[i][j + 0]; ov.y = acc[i][j + 1];
        ov.z = acc[i][j + 2]; ov.w = acc[i][j + 3];
        if (bias) {
          ov.x += bias[gn + 0]; ov.y += bias[gn + 1];
          ov.z += bias[gn + 2]; ov.w += bias[gn + 3];
        }
        *(float4*)&C[(size_t)gm * DIM_ + gn] = ov;
      }
    }
  }
}

// ---------------- Pass A: running max over (h,k) of (dots - lse) -------------
#define KT 64
#define DC 32
#define KSPLIT 4

__device__ __forceinline__ unsigned fflip(float x) {
  const unsigned u = __float_as_uint(x);
  return (u & 0x80000000u) ? ~u : (u | 0x80000000u);
}

__global__ __launch_bounds__(256) void pass_a(
    const float* __restrict__ qh, const float* __restrict__ kh,
    unsigned* __restrict__ sbuf) {
  __shared__ float qs[DC][Q_ + 4];     // [d][q], q/SCALE
  __shared__ float ksm[DC][KT + 4];    // [d][k]
  __shared__ float red[32][KT + 1];
  __shared__ float cmax[KT];
  __shared__ float clse[KT];
  const int blk = blockIdx.x;
  const int b = blk >> 6;
  const int h = (blk >> 2) & 15;
  const int ks0 = (blk & 3) * (K_ / KSPLIT);
  const int t = threadIdx.x;
  const int tq = t >> 3;   // 0..31 : q-rows tq*8..+7
  const int tk = t & 7;    // 0..7  : k-cols tk*8..+7
  float rmax[8];
#pragma unroll
  for (int i = 0; i < 8; ++i) rmax[i] = -3.4e38f;

  for (int k0 = ks0; k0 < ks0 + K_ / KSPLIT; k0 += KT) {
    float acc[8][8];
#pragma unroll
    for (int i = 0; i < 8; ++i)
#pragma unroll
      for (int j = 0; j < 8; ++j) acc[i][j] = 0.f;

    for (int dc = 0; dc < HD_; dc += DC) {
      {
        const float* src = &qh[((size_t)(b * Q_ + t)) * DIM_ + h * HD_ + dc];
#pragma unroll
        for (int u = 0; u < DC / 4; ++u) {
          const float4 vv = *(const float4*)&src[u * 4];
          qs[u * 4 + 0][t] = vv.x * SCALE_INV;
          qs[u * 4 + 1][t] = vv.y * SCALE_INV;
          qs[u * 4 + 2][t] = vv.z * SCALE_INV;
          qs[u * 4 + 3][t] = vv.w * SCALE_INV;
        }
      }
      {
        const int r = t >> 2;
        const int qd = (t & 3) * 8;
        const float* src =
            &kh[((size_t)(b * K_ + k0 + r)) * DIM_ + h * HD_ + dc + qd];
#pragma unroll
        for (int u = 0; u < 2; ++u) {
          const float4 vv = *(const float4*)&src[u * 4];
          ksm[qd + u * 4 + 0][r] = vv.x; ksm[qd + u * 4 + 1][r] = vv.y;
          ksm[qd + u * 4 + 2][r] = vv.z; ksm[qd + u * 4 + 3][r] = vv.w;
        }
      }
      __syncthreads();
#pragma unroll
      for (int d = 0; d < DC; ++d) {
        float a[8], bb[8];
        *(float4*)&a[0] = *(const float4*)&qs[d][tq * 8];
        *(float4*)&a[4] = *(const float4*)&qs[d][tq * 8 + 4];
        *(float4*)&bb[0] = *(const float4*)&ksm[d][tk * 8];
        *(float4*)&bb[4] = *(const float4*)&ksm[d][tk * 8 + 4];
#pragma unroll
        for (int i = 0; i < 8; ++i)
#pragma unroll
          for (int j = 0; j < 8; ++j)
            acc[i][j] = fmaf(a[i], bb[j], acc[i][j]);
      }
      __syncthreads();
    }
    // ---- per-column (k) stats over queries 1..255 ----
#pragma unroll
    for (int j = 0; j < 8; ++j) {
      float m = -3.4e38f;
#pragma unroll
      for (int i = 0; i < 8; ++i) {
        if (tq == 0 && i == 0) continue;  // exclude q==0 from stats
        m = fmaxf(m, acc[i][j]);
      }
      red[tq][tk * 8 + j] = m;
    }
    __syncthreads();
    if (t < KT) {
      float m = -3.4e38f;
      for (int g = 0; g < 32; ++g) m = fmaxf(m, red[g][t]);
      cmax[t] = m;
    }
    __syncthreads();
#pragma unroll
    for (int j = 0; j < 8; ++j) {
      const float m = cmax[tk * 8 + j];
      float s = 0.f;
#pragma unroll
      for (int i = 0; i < 8; ++i) {
        if (tq == 0 && i == 0) continue;
        s += __expf(acc[i][j] - m);
      }
      red[tq][tk * 8 + j] = s;
    }
    __syncthreads();
    if (t < KT) {
      float s = 0.f;
      for (int g = 0; g < 32; ++g) s += red[g][t];
      clse[t] = cmax[t] + logf(s);
    }
    __syncthreads();
#pragma unroll
    for (int i = 0; i < 8; ++i) {
      float v = -3.4e38f;
#pragma unroll
      for (int j = 0; j < 8; ++j) v = fmaxf(v, acc[i][j] - clse[tk * 8 + j]);
      v = fmaxf(v, __shfl_xor(v, 1, 64));
      v = fmaxf(v, __shfl_xor(v, 2, 64));
      v = fmaxf(v, __shfl_xor(v, 4, 64));
      rmax[i] = fmaxf(rmax[i], v);
    }
    __syncthreads();
  }
  if (tk == 0) {
#pragma unroll
    for (int i = 0; i < 8; ++i) {
      const int qi = tq * 8 + i;
      if (qi > 0) atomicMax(&sbuf[b * Q_ + qi], fflip(rmax[i]));
    }
  }
}

// ---------------- top-k (exact jax.lax.top_k semantics) ----------------------
__global__ void topk_kernel(const unsigned* __restrict__ sbuf,
                            int* __restrict__ keep, float* __restrict__ keepf) {
  const int b = blockIdx.x;
  const int lane = threadIdx.x;  // 64 lanes
  unsigned long long pk[4];
#pragma unroll
  for (int j = 0; j < 4; ++j) {
    const int q = 1 + lane + 64 * j;  // 1..256
    if (q <= 255) {
      const unsigned s = sbuf[b * Q_ + q];
      pk[j] = (((unsigned long long)s) << 32) | (unsigned)(256 - q);  // lower q wins ties
    } else {
      pk[j] = 0ull;
    }
  }
  if (lane == 0) { keep[b * QP_] = 0; keepf[b * QP_] = 0.f; }
  for (int it = 0; it < MQ_; ++it) {
    unsigned long long best = pk[0];
#pragma unroll
    for (int j = 1; j < 4; ++j) best = (pk[j] > best) ? pk[j] : best;
    for (int m = 1; m < 64; m <<= 1) {
      const unsigned long long o = __shfl_xor(best, m, 64);
      best = (o > best) ? o : best;
    }
    const int q = 256 - (int)(best & 0xffffffffu);
#pragma unroll
    for (int j = 0; j < 4; ++j)
      if (pk[j] == best) pk[j] = 0ull;
    if (lane == 0) {
      keep[b * QP_ + 1 + it] = q;
      keepf[b * QP_ + 1 + it] = (float)q;
    }
  }
}

// ---------------- Pass B: competitive softmax over kept queries + PV ---------
__global__ __launch_bounds__(256) void pass_b(
    const float* __restrict__ qh, const float* __restrict__ kh,
    const float* __restrict__ vh, const int* __restrict__ keep,
    float* __restrict__ opre) {
  __shared__ float qs[QP_][HD_ + 4];   // kept q rows, scaled
  __shared__ float kv[KT][HD_ + 4];    // K tile, later V tile
  __shared__ float att[QP_][KT + 4];
  __shared__ float cmax[KT];
  __shared__ float crcp[KT];
  const int b = blockIdx.x >> 4;
  const int h = blockIdx.x & 15;
  const int t = threadIdx.x;

  if (t < QP_) {
    const int kq = keep[b * QP_ + t];
    const float* src = &qh[((size_t)(b * Q_ + kq)) * DIM_ + h * HD_];
#pragma unroll
    for (int u = 0; u < HD_ / 4; ++u) {
      float4 vv = *(const float4*)&src[u * 4];
      vv.x *= SCALE_INV; vv.y *= SCALE_INV;
      vv.z *= SCALE_INV; vv.w *= SCALE_INV;
      *(float4*)&qs[t][u * 4] = vv;
    }
  }
  const int c = t & 63;
  const int jg = t >> 6;
  const int j0 = jg * 17;
  const int j1 = (jg == 3) ? QP_ : (j0 + 17);
  const int j2 = t >> 2;
  const int cg = (t & 3) * 16;
  const int r = t >> 2;
  const int qd = (t & 3) * 16;
  float oacc[16], oacc2[16];
#pragma unroll
  for (int u = 0; u < 16; ++u) { oacc[u] = 0.f; oacc2[u] = 0.f; }

  __syncthreads();

  for (int k0 = 0; k0 < K_; k0 += KT) {
    {  // stage K tile
      const float* src = &kh[((size_t)(b * K_ + k0 + r)) * DIM_ + h * HD_ + qd];
#pragma unroll
      for (int u = 0; u < 4; ++u)
        *(float4*)&kv[r][qd + u * 4] = *(const float4*)&src[u * 4];
    }
    __syncthreads();
    {  // QK: each thread one k-column, subset of j rows
      float4 kr[16];
#pragma unroll
      for (int u = 0; u < 16; ++u) kr[u] = *(const float4*)&kv[c][u * 4];
      for (int j = j0; j < j1; ++j) {
        float4 s4 = make_float4(0.f, 0.f, 0.f, 0.f);
#pragma unroll
        for (int u = 0; u < 16; ++u) {
          const float4 qv = *(const float4*)&qs[j][u * 4];
          s4.x = fmaf(qv.x, kr[u].x, s4.x);
          s4.y = fmaf(qv.y, kr[u].y, s4.y);
          s4.z = fmaf(qv.z, kr[u].z, s4.z);
          s4.w = fmaf(qv.w, kr[u].w, s4.w);
        }
        att[j][c] = (s4.x + s4.y) + (s4.z + s4.w);
      }
    }
    __syncthreads();
    {  // stage V tile (kv reuse) + column softmax stats
      const float* src = &vh[((size_t)(b * K_ + k0 + r)) * DIM_ + h * HD_ + qd];
#pragma unroll
      for (int u = 0; u < 4; ++u)
        *(float4*)&kv[r][qd + u * 4] = *(const float4*)&src[u * 4];
      if (t < KT) {
        float m = att[0][t];
        for (int j = 1; j < QP_; ++j) m = fmaxf(m, att[j][t]);
        float s = 0.f;
        for (int j = 0; j < QP_; ++j) s += __expf(att[j][t] - m);
        cmax[t] = m;
        crcp[t] = 1.f / s;
      }
    }
    __syncthreads();
    for (int e = t; e < QP_ * KT; e += 256) {  // normalize
      const int jj = e >> 6;
      const int cc = e & 63;
      att[jj][cc] = __expf(att[jj][cc] - cmax[cc]) * crcp[cc];
    }
    __syncthreads();
    {  // PV accumulate
      for (int ck = 0; ck < KT; ++ck) {
        const float a = att[j2][ck];
        const float4 v0 = *(const float4*)&kv[ck][cg + 0];
        const float4 v1 = *(const float4*)&kv[ck][cg + 4];
        const float4 v2 = *(const float4*)&kv[ck][cg + 8];
        const float4 v3 = *(const float4*)&kv[ck][cg + 12];
        oacc[0] = fmaf(a, v0.x, oacc[0]);   oacc[1] = fmaf(a, v0.y, oacc[1]);
        oacc[2] = fmaf(a, v0.z, oacc[2]);   oacc[3] = fmaf(a, v0.w, oacc[3]);
        oacc[4] = fmaf(a, v1.x, oacc[4]);   oacc[5] = fmaf(a, v1.y, oacc[5]);
        oacc[6] = fmaf(a, v1.z, oacc[6]);   oacc[7] = fmaf(a, v1.w, oacc[7]);
        oacc[8] = fmaf(a, v2.x, oacc[8]);   oacc[9] = fmaf(a, v2.y, oacc[9]);
        oacc[10] = fmaf(a, v2.z, oacc[10]); oacc[11] = fmaf(a, v2.w, oacc[11]);
        oacc[12] = fmaf(a, v3.x, oacc[12]); oacc[13] = fmaf(a, v3.y, oacc[13]);
        oacc[14] = fmaf(a, v3.z, oacc[14]); oacc[15] = fmaf(a, v3.w, oacc[15]);
      }
      if (t < 4) {  // row j = 64
        const int cg2 = t * 16;
        for (int ck = 0; ck < KT; ++ck) {
          const float a = att[64][ck];
          const float4 v0 = *(const float4*)&kv[ck][cg2 + 0];
          const float4 v1 = *(const float4*)&kv[ck][cg2 + 4];
          const float4 v2 = *(const float4*)&kv[ck][cg2 + 8];
          const float4 v3 = *(const float4*)&kv[ck][cg2 + 12];
          oacc2[0] = fmaf(a, v0.x, oacc2[0]);   oacc2[1] = fmaf(a, v0.y, oacc2[1]);
          oacc2[2] = fmaf(a, v0.z, oacc2[2]);   oacc2[3] = fmaf(a, v0.w, oacc2[3]);
          oacc2[4] = fmaf(a, v1.x, oacc2[4]);   oacc2[5] = fmaf(a, v1.y, oacc2[5]);
          oacc2[6] = fmaf(a, v1.z, oacc2[6]);   oacc2[7] = fmaf(a, v1.w, oacc2[7]);
          oacc2[8] = fmaf(a, v2.x, oacc2[8]);   oacc2[9] = fmaf(a, v2.y, oacc2[9]);
          oacc2[10] = fmaf(a, v2.z, oacc2[10]); oacc2[11] = fmaf(a, v2.w, oacc2[11]);
          oacc2[12] = fmaf(a, v3.x, oacc2[12]); oacc2[13] = fmaf(a, v3.w == v3.w ? v3.w : v3.w, oacc2[13]);
          oacc2[13] = fmaf(a, v3.y, oacc2[13] - fmaf(a, v3.y, 0.f));  // (kept simple below)
          oacc2[13] = oacc2[13];
          oacc2[14] = fmaf(a, v3.z, oacc2[14]); oacc2[15] = fmaf(a, v3.w, oacc2[15]);
        }
      }
    }
    __syncthreads();
  }
  {
    float* dst = &opre[((size_t)(b * QP_ + j2)) * DIM_ + h * HD_ + cg];
    *(float4*)&dst[0] = make_float4(oacc[0], oacc[1], oacc[2], oacc[3]);
    *(float4*)&dst[4] = make_float4(oacc[4], oacc[5], oacc[6], oacc[7]);
    *(float4*)&dst[8] = make_float4(oacc[8], oacc[9], oacc[10], oacc[11]);
    *(float4*)&dst[12] = make_float4(oacc[12], oacc[13], oacc[14], oacc[15]);
    if (t < 4) {
      float* dst2 = &opre[((size_t)(b * QP_ + 64)) * DIM_ + h * HD_ + t * 16];
      *(float4*)&dst2[0] = make_float4(oacc2[0], oacc2[1], oacc2[2], oacc2[3]);
      *(float4*)&dst2[4] = make_float4(oacc2[4], oacc2[5], oacc2[6], oacc2[7]);
      *(float4*)&dst2[8] = make_float4(oacc2[8], oacc2[9], oacc2[10], oacc2[11]);
      *(float4*)&dst2[12] = make_float4(oacc2[12], oacc2[13], oacc2[14], oacc2[15]);
    }
  }
}

extern "C" void kernel_launch(void* const* d_in, const int* in_sizes, int n_in,
                              void* d_out, int out_size, void* d_ws, size_t ws_size,
                              hipStream_t stream) {
  const float* q  = (const float*)d_in[0];
  const float* k  = (const float*)d_in[1];
  const float* v  = (const float*)d_in[2];
  const float* Wq = (const float*)d_in[3];
  const float* Wk = (const float*)d_in[4];
  const float* Wv = (const float*)d_in[5];
  const float* Wo = (const float*)d_in[6];
  const float* bo = (const float*)d_in[7];
  float* out = (float*)d_out;

  float* ws = (float*)d_ws;
  float* qh = ws;
  float* kh = qh + (size_t)B_ * Q_ * DIM_;
  float* vh = kh + (size_t)B_ * K_ * DIM_;
  float* opre = vh + (size_t)B_ * K_ * DIM_;
  unsigned* sbuf = (unsigned*)(opre + (size_t)B_ * QP_ * DIM_);
  int* keep = (int*)(sbuf + B_ * Q_);
  float* keepf = out + (size_t)B_ * QP_ * DIM_;

  hipMemsetAsync(sbuf, 0, B_ * Q_ * sizeof(unsigned), stream);

  const dim3 blk(256);
  gemm_nt<<<dim3(B_ * Q_ / GM, DIM_ / GN), blk, 0, stream>>>(q, Wq, qh, B_ * Q_, nullptr);
  gemm_nt<<<dim3(B_ * K_ / GM, DIM_ / GN), blk, 0, stream>>>(k, Wk, kh, B_ * K_, nullptr);
  gemm_nt<<<dim3(B_ * K_ / GM, DIM_ / GN), blk, 0, stream>>>(v, Wv, vh, B_ * K_, nullptr);
  pass_a<<<dim3(B_ * H_ * KSPLIT), blk, 0, stream>>>(qh, kh, sbuf);
  topk_kernel<<<dim3(B_), dim3(64), 0, stream>>>(sbuf, keep, keepf);
  pass_b<<<dim3(B_ * H_), blk, 0, stream>>>(qh, kh, vh, keep, opre);
  gemm_nt<<<dim3((B_ * QP_ + GM - 1) / GM, DIM_ / GN), blk, 0, stream>>>(
      opre, Wo, out, B_ * QP_, bo);
}

// Round 2
// 2786.918 us; speedup vs baseline: 1.9735x; 1.9735x over previous
//
#include <hip/hip_runtime.h>
#include <hip/hip_bf16.h>
#include <math.h>

#define B_ 16
#define Q_ 256
#define K_ 4096
#define DIM_ 1024
#define H_ 16
#define HD_ 64
#define MQ_ 64
#define QP_ 65
#define SCALE_INV 0.125f

typedef unsigned short u16;
typedef __attribute__((ext_vector_type(8))) short bf16x8;
typedef __attribute__((ext_vector_type(4))) float f32x4;

// ---------------- helpers -----------------------------------------------------
__device__ __forceinline__ u16 f2bf_rne(float f) {
  unsigned u = __float_as_uint(f);
  u += 0x7fffu + ((u >> 16) & 1u);
  return (u16)(u >> 16);
}
__device__ __forceinline__ float bf2f(u16 h) {
  return __uint_as_float(((unsigned)h) << 16);
}
__device__ __forceinline__ void gload16(const void* g, void* l) {
  __builtin_amdgcn_global_load_lds(
      (const __attribute__((address_space(1))) unsigned int*)g,
      (__attribute__((address_space(3))) unsigned int*)l, 16, 0, 0);
}

// ---------------- split fp32 -> bf16 hi/lo ------------------------------------
__global__ __launch_bounds__(256) void split_bf16(
    const float* __restrict__ x, u16* __restrict__ hi, u16* __restrict__ lo,
    long n8, int wlo) {
  long i = (long)blockIdx.x * 256 + threadIdx.x;
  const long stride = (long)gridDim.x * 256;
  for (; i < n8; i += stride) {
    const float4 a = ((const float4*)x)[2 * i];
    const float4 b = ((const float4*)x)[2 * i + 1];
    const float xs[8] = {a.x, a.y, a.z, a.w, b.x, b.y, b.z, b.w};
    u16 h[8], l[8];
#pragma unroll
    for (int j = 0; j < 8; ++j) {
      h[j] = f2bf_rne(xs[j]);
      l[j] = f2bf_rne(xs[j] - bf2f(h[j]));
    }
    uint4 hv;
    hv.x = h[0] | ((unsigned)h[1] << 16);
    hv.y = h[2] | ((unsigned)h[3] << 16);
    hv.z = h[4] | ((unsigned)h[5] << 16);
    hv.w = h[6] | ((unsigned)h[7] << 16);
    ((uint4*)hi)[i] = hv;
    if (wlo) {
      uint4 lv;
      lv.x = l[0] | ((unsigned)l[1] << 16);
      lv.y = l[2] | ((unsigned)l[3] << 16);
      lv.z = l[4] | ((unsigned)l[5] << 16);
      lv.w = l[6] | ((unsigned)l[7] << 16);
      ((uint4*)lo)[i] = lv;
    }
  }
}

// ---------------- MFMA GEMM: C[M,1024] = A @ W^T, split-bf16 limbs ------------
// A limbs [M][1024] bf16, W limbs [1024][1024] bf16 (row n = output feature).
// NPROD==3: hi*hi + hi*lo + lo*hi (fp32-class accuracy). NPROD==1: hi*hi.
template <int NPROD>
__global__ __launch_bounds__(256) void mfma_gemm(
    const u16* __restrict__ Ahp, const u16* __restrict__ Alp,
    const u16* __restrict__ Bhp, const u16* __restrict__ Blp,
    float* __restrict__ C) {
  __shared__ u16 Ah_s[128 * 32];
  __shared__ u16 Bh_s[128 * 32];
  __shared__ u16 Al_s[128 * 32];
  __shared__ u16 Bl_s[128 * 32];
  const int t = threadIdx.x;
  const int wave = t >> 6;
  const int lane = t & 63;
  const int wr = wave >> 1;
  const int wc = wave & 1;
  const int n0 = blockIdx.x * 128;  // N-dim fastest: W limbs stay L2-hot
  const int m0 = blockIdx.y * 128;

  // staging geometry: wave stages tile rows [wave*32, wave*32+32), two 1KB loads
  // LDS is linear; global source chunk is pre-swizzled (both-sides rule)
  const int sr0 = wave * 32 + (lane >> 2);
  const int sr1 = sr0 + 16;
  const int sw0 = ((sr0 ^ (sr0 >> 2)) & 3) ^ (lane & 3);
  const int sw1 = ((sr1 ^ (sr1 >> 2)) & 3) ^ (lane & 3);
  const size_t gA0 = (size_t)(m0 + sr0) * DIM_ + sw0 * 8;
  const size_t gA1 = (size_t)(m0 + sr1) * DIM_ + sw1 * 8;
  const size_t gB0 = (size_t)(n0 + sr0) * DIM_ + sw0 * 8;
  const size_t gB1 = (size_t)(n0 + sr1) * DIM_ + sw1 * 8;
  u16* const lA0 = &Ah_s[(wave * 32) * 32];
  u16* const lA1 = &Ah_s[(wave * 32 + 16) * 32];
  u16* const lB0 = &Bh_s[(wave * 32) * 32];
  u16* const lB1 = &Bh_s[(wave * 32 + 16) * 32];
  u16* const lAl0 = &Al_s[(wave * 32) * 32];
  u16* const lAl1 = &Al_s[(wave * 32 + 16) * 32];
  u16* const lBl0 = &Bl_s[(wave * 32) * 32];
  u16* const lBl1 = &Bl_s[(wave * 32 + 16) * 32];

  // fragment LDS offsets (u16 units), k0-invariant; swizzled read side
  int aoff[4], boff[4];
#pragma unroll
  for (int m = 0; m < 4; ++m) {
    const int r = wr * 64 + m * 16 + (lane & 15);
    const int p = ((r ^ (r >> 2)) & 3) ^ (lane >> 4);
    aoff[m] = r * 32 + p * 8;
  }
#pragma unroll
  for (int n = 0; n < 4; ++n) {
    const int r = wc * 64 + n * 16 + (lane & 15);
    const int p = ((r ^ (r >> 2)) & 3) ^ (lane >> 4);
    boff[n] = r * 32 + p * 8;
  }

  f32x4 acc[4][4];
#pragma unroll
  for (int m = 0; m < 4; ++m)
#pragma unroll
    for (int n = 0; n < 4; ++n) acc[m][n] = (f32x4)(0.f);

  for (int k0 = 0; k0 < DIM_; k0 += 32) {
    gload16(Ahp + gA0 + k0, lA0);
    gload16(Ahp + gA1 + k0, lA1);
    gload16(Bhp + gB0 + k0, lB0);
    gload16(Bhp + gB1 + k0, lB1);
    if (NPROD == 3) {
      gload16(Alp + gA0 + k0, lAl0);
      gload16(Alp + gA1 + k0, lAl1);
      gload16(Blp + gB0 + k0, lBl0);
      gload16(Blp + gB1 + k0, lBl1);
    }
    __syncthreads();
    {
      bf16x8 af[4], bfr[4];
#pragma unroll
      for (int m = 0; m < 4; ++m) af[m] = *(const bf16x8*)&Ah_s[aoff[m]];
#pragma unroll
      for (int n = 0; n < 4; ++n) bfr[n] = *(const bf16x8*)&Bh_s[boff[n]];
#pragma unroll
      for (int m = 0; m < 4; ++m)
#pragma unroll
        for (int n = 0; n < 4; ++n)
          acc[m][n] = __builtin_amdgcn_mfma_f32_16x16x32_bf16(
              af[m], bfr[n], acc[m][n], 0, 0, 0);
      if (NPROD == 3) {
        // hi * lo (af still holds A_hi)
#pragma unroll
        for (int n = 0; n < 4; ++n) bfr[n] = *(const bf16x8*)&Bl_s[boff[n]];
#pragma unroll
        for (int m = 0; m < 4; ++m)
#pragma unroll
          for (int n = 0; n < 4; ++n)
            acc[m][n] = __builtin_amdgcn_mfma_f32_16x16x32_bf16(
                af[m], bfr[n], acc[m][n], 0, 0, 0);
        // lo * hi
#pragma unroll
        for (int m = 0; m < 4; ++m) af[m] = *(const bf16x8*)&Al_s[aoff[m]];
#pragma unroll
        for (int n = 0; n < 4; ++n) bfr[n] = *(const bf16x8*)&Bh_s[boff[n]];
#pragma unroll
        for (int m = 0; m < 4; ++m)
#pragma unroll
          for (int n = 0; n < 4; ++n)
            acc[m][n] = __builtin_amdgcn_mfma_f32_16x16x32_bf16(
                af[m], bfr[n], acc[m][n], 0, 0, 0);
      }
    }
    __syncthreads();
  }
  // C/D layout: col = lane&15, row = (lane>>4)*4 + j  (m89-verified)
#pragma unroll
  for (int m = 0; m < 4; ++m) {
    const int row = m0 + wr * 64 + m * 16 + (lane >> 4) * 4;
#pragma unroll
    for (int n = 0; n < 4; ++n) {
      const int col = n0 + wc * 64 + n * 16 + (lane & 15);
#pragma unroll
      for (int j = 0; j < 4; ++j)
        C[(size_t)(row + j) * DIM_ + col] = acc[m][n][j];
    }
  }
}

// ---------------- fp32 GEMM (q-proj, Wo, and fallback) ------------------------
#define GM 128
#define GN 128
#define GK 16

__global__ __launch_bounds__(256) void gemm_nt(
    const float* __restrict__ A, const float* __restrict__ W,
    float* __restrict__ C, int M, const float* __restrict__ bias) {
  __shared__ float As[GK][GM + 4];
  __shared__ float Ws[GK][GN + 4];
  const int t = threadIdx.x;
  const int m0 = blockIdx.x * GM;
  const int n0 = blockIdx.y * GN;
  const int lrow = t >> 2;
  const int lq = (t & 3) * 4;
  const int tm = (t >> 4) * 8;
  const int tn = (t & 15) * 8;
  float acc[8][8];
#pragma unroll
  for (int i = 0; i < 8; ++i)
#pragma unroll
    for (int j = 0; j < 8; ++j) acc[i][j] = 0.f;

  for (int k0 = 0; k0 < DIM_; k0 += GK) {
#pragma unroll
    for (int half = 0; half < 2; ++half) {
      const int row = lrow + half * 64;
      const int gm = m0 + row;
      float4 av = make_float4(0.f, 0.f, 0.f, 0.f);
      if (gm < M) av = *(const float4*)&A[(size_t)gm * DIM_ + k0 + lq];
      As[lq + 0][row] = av.x; As[lq + 1][row] = av.y;
      As[lq + 2][row] = av.z; As[lq + 3][row] = av.w;
      const int gn = n0 + row;
      const float4 wv = *(const float4*)&W[(size_t)gn * DIM_ + k0 + lq];
      Ws[lq + 0][row] = wv.x; Ws[lq + 1][row] = wv.y;
      Ws[lq + 2][row] = wv.z; Ws[lq + 3][row] = wv.w;
    }
    __syncthreads();
#pragma unroll
    for (int kk = 0; kk < GK; ++kk) {
      float a[8], bb[8];
      *(float4*)&a[0] = *(const float4*)&As[kk][tm];
      *(float4*)&a[4] = *(const float4*)&As[kk][tm + 4];
      *(float4*)&bb[0] = *(const float4*)&Ws[kk][tn];
      *(float4*)&bb[4] = *(const float4*)&Ws[kk][tn + 4];
#pragma unroll
      for (int i = 0; i < 8; ++i)
#pragma unroll
        for (int j = 0; j < 8; ++j)
          acc[i][j] = fmaf(a[i], bb[j], acc[i][j]);
    }
    __syncthreads();
  }
#pragma unroll
  for (int i = 0; i < 8; ++i) {
    const int gm = m0 + tm + i;
    if (gm < M) {
#pragma unroll
      for (int j = 0; j < 8; j += 4) {
        const int gn = n0 + tn + j;
        float4 ov;
        ov.x = acc[i][j + 0]; ov.y = acc[i][j + 1];
        ov.z = acc[i][j + 2]; ov.w = acc[i][j + 3];
        if (bias) {
          ov.x += bias[gn + 0]; ov.y += bias[gn + 1];
          ov.z += bias[gn + 2]; ov.w += bias[gn + 3];
        }
        *(float4*)&C[(size_t)gm * DIM_ + gn] = ov;
      }
    }
  }
}

// ---------------- Pass A: running max over (h,k) of (dots - lse) -------------
#define KT 64
#define DC 32
#define KSPLIT 4

__device__ __forceinline__ unsigned fflip(float x) {
  const unsigned u = __float_as_uint(x);
  return (u & 0x80000000u) ? ~u : (u | 0x80000000u);
}

__global__ __launch_bounds__(256) void pass_a(
    const float* __restrict__ qh, const float* __restrict__ kh,
    unsigned* __restrict__ sbuf) {
  __shared__ float qs[DC][Q_ + 4];     // [d][q], q/SCALE
  __shared__ float ksm[DC][KT + 4];    // [d][k]
  __shared__ float red[32][KT + 1];
  __shared__ float cmax[KT];
  __shared__ float clse[KT];
  const int blk = blockIdx.x;
  const int b = blk >> 6;
  const int h = (blk >> 2) & 15;
  const int ks0 = (blk & 3) * (K_ / KSPLIT);
  const int t = threadIdx.x;
  const int tq = t >> 3;
  const int tk = t & 7;
  float rmax[8];
#pragma unroll
  for (int i = 0; i < 8; ++i) rmax[i] = -3.4e38f;

  for (int k0 = ks0; k0 < ks0 + K_ / KSPLIT; k0 += KT) {
    float acc[8][8];
#pragma unroll
    for (int i = 0; i < 8; ++i)
#pragma unroll
      for (int j = 0; j < 8; ++j) acc[i][j] = 0.f;

    for (int dc = 0; dc < HD_; dc += DC) {
      {
        const float* src = &qh[((size_t)(b * Q_ + t)) * DIM_ + h * HD_ + dc];
#pragma unroll
        for (int u = 0; u < DC / 4; ++u) {
          const float4 vv = *(const float4*)&src[u * 4];
          qs[u * 4 + 0][t] = vv.x * SCALE_INV;
          qs[u * 4 + 1][t] = vv.y * SCALE_INV;
          qs[u * 4 + 2][t] = vv.z * SCALE_INV;
          qs[u * 4 + 3][t] = vv.w * SCALE_INV;
        }
      }
      {
        const int r = t >> 2;
        const int qd = (t & 3) * 8;
        const float* src =
            &kh[((size_t)(b * K_ + k0 + r)) * DIM_ + h * HD_ + dc + qd];
#pragma unroll
        for (int u = 0; u < 2; ++u) {
          const float4 vv = *(const float4*)&src[u * 4];
          ksm[qd + u * 4 + 0][r] = vv.x; ksm[qd + u * 4 + 1][r] = vv.y;
          ksm[qd + u * 4 + 2][r] = vv.z; ksm[qd + u * 4 + 3][r] = vv.w;
        }
      }
      __syncthreads();
#pragma unroll
      for (int d = 0; d < DC; ++d) {
        float a[8], bb[8];
        *(float4*)&a[0] = *(const float4*)&qs[d][tq * 8];
        *(float4*)&a[4] = *(const float4*)&qs[d][tq * 8 + 4];
        *(float4*)&bb[0] = *(const float4*)&ksm[d][tk * 8];
        *(float4*)&bb[4] = *(const float4*)&ksm[d][tk * 8 + 4];
#pragma unroll
        for (int i = 0; i < 8; ++i)
#pragma unroll
          for (int j = 0; j < 8; ++j)
            acc[i][j] = fmaf(a[i], bb[j], acc[i][j]);
      }
      __syncthreads();
    }
#pragma unroll
    for (int j = 0; j < 8; ++j) {
      float m = -3.4e38f;
#pragma unroll
      for (int i = 0; i < 8; ++i) {
        if (tq == 0 && i == 0) continue;
        m = fmaxf(m, acc[i][j]);
      }
      red[tq][tk * 8 + j] = m;
    }
    __syncthreads();
    if (t < KT) {
      float m = -3.4e38f;
      for (int g = 0; g < 32; ++g) m = fmaxf(m, red[g][t]);
      cmax[t] = m;
    }
    __syncthreads();
#pragma unroll
    for (int j = 0; j < 8; ++j) {
      const float m = cmax[tk * 8 + j];
      float s = 0.f;
#pragma unroll
      for (int i = 0; i < 8; ++i) {
        if (tq == 0 && i == 0) continue;
        s += __expf(acc[i][j] - m);
      }
      red[tq][tk * 8 + j] = s;
    }
    __syncthreads();
    if (t < KT) {
      float s = 0.f;
      for (int g = 0; g < 32; ++g) s += red[g][t];
      clse[t] = cmax[t] + logf(s);
    }
    __syncthreads();
#pragma unroll
    for (int i = 0; i < 8; ++i) {
      float v = -3.4e38f;
#pragma unroll
      for (int j = 0; j < 8; ++j) v = fmaxf(v, acc[i][j] - clse[tk * 8 + j]);
      v = fmaxf(v, __shfl_xor(v, 1, 64));
      v = fmaxf(v, __shfl_xor(v, 2, 64));
      v = fmaxf(v, __shfl_xor(v, 4, 64));
      rmax[i] = fmaxf(rmax[i], v);
    }
    __syncthreads();
  }
  if (tk == 0) {
#pragma unroll
    for (int i = 0; i < 8; ++i) {
      const int qi = tq * 8 + i;
      if (qi > 0) atomicMax(&sbuf[b * Q_ + qi], fflip(rmax[i]));
    }
  }
}

// ---------------- top-k (exact jax.lax.top_k semantics) ----------------------
__global__ void topk_kernel(const unsigned* __restrict__ sbuf,
                            int* __restrict__ keep, float* __restrict__ keepf) {
  const int b = blockIdx.x;
  const int lane = threadIdx.x;
  unsigned long long pk[4];
#pragma unroll
  for (int j = 0; j < 4; ++j) {
    const int q = 1 + lane + 64 * j;
    if (q <= 255) {
      const unsigned s = sbuf[b * Q_ + q];
      pk[j] = (((unsigned long long)s) << 32) | (unsigned)(256 - q);
    } else {
      pk[j] = 0ull;
    }
  }
  if (lane == 0) { keep[b * QP_] = 0; keepf[b * QP_] = 0.f; }
  for (int it = 0; it < MQ_; ++it) {
    unsigned long long best = pk[0];
#pragma unroll
    for (int j = 1; j < 4; ++j) best = (pk[j] > best) ? pk[j] : best;
    for (int m = 1; m < 64; m <<= 1) {
      const unsigned long long o = __shfl_xor(best, m, 64);
      best = (o > best) ? o : best;
    }
    const int q = 256 - (int)(best & 0xffffffffu);
#pragma unroll
    for (int j = 0; j < 4; ++j)
      if (pk[j] == best) pk[j] = 0ull;
    if (lane == 0) {
      keep[b * QP_ + 1 + it] = q;
      keepf[b * QP_ + 1 + it] = (float)q;
    }
  }
}

// ---------------- Pass B: competitive softmax over kept queries + PV ---------
__global__ __launch_bounds__(256) void pass_b(
    const float* __restrict__ qh, const float* __restrict__ kh,
    const float* __restrict__ vh, const int* __restrict__ keep,
    float* __restrict__ opre) {
  __shared__ float qs[QP_][HD_ + 4];
  __shared__ float kv[KT][HD_ + 4];
  __shared__ float att[QP_][KT + 4];
  __shared__ float cmax[KT];
  __shared__ float crcp[KT];
  const int b = blockIdx.x >> 4;
  const int h = blockIdx.x & 15;
  const int t = threadIdx.x;

  if (t < QP_) {
    const int kq = keep[b * QP_ + t];
    const float* src = &qh[((size_t)(b * Q_ + kq)) * DIM_ + h * HD_];
#pragma unroll
    for (int u = 0; u < HD_ / 4; ++u) {
      float4 vv = *(const float4*)&src[u * 4];
      vv.x *= SCALE_INV; vv.y *= SCALE_INV;
      vv.z *= SCALE_INV; vv.w *= SCALE_INV;
      *(float4*)&qs[t][u * 4] = vv;
    }
  }
  const int c = t & 63;
  const int jg = t >> 6;
  const int j0 = jg * 17;
  const int j1 = (jg == 3) ? QP_ : (j0 + 17);
  const int j2 = t >> 2;
  const int cg = (t & 3) * 16;
  const int r = t >> 2;
  const int qd = (t & 3) * 16;
  float oacc[16], oacc2[16];
#pragma unroll
  for (int u = 0; u < 16; ++u) { oacc[u] = 0.f; oacc2[u] = 0.f; }

  __syncthreads();

  for (int k0 = 0; k0 < K_; k0 += KT) {
    {
      const float* src = &kh[((size_t)(b * K_ + k0 + r)) * DIM_ + h * HD_ + qd];
#pragma unroll
      for (int u = 0; u < 4; ++u)
        *(float4*)&kv[r][qd + u * 4] = *(const float4*)&src[u * 4];
    }
    __syncthreads();
    {
      float4 kr[16];
#pragma unroll
      for (int u = 0; u < 16; ++u) kr[u] = *(const float4*)&kv[c][u * 4];
      for (int j = j0; j < j1; ++j) {
        float4 s4 = make_float4(0.f, 0.f, 0.f, 0.f);
#pragma unroll
        for (int u = 0; u < 16; ++u) {
          const float4 qv = *(const float4*)&qs[j][u * 4];
          s4.x = fmaf(qv.x, kr[u].x, s4.x);
          s4.y = fmaf(qv.y, kr[u].y, s4.y);
          s4.z = fmaf(qv.z, kr[u].z, s4.z);
          s4.w = fmaf(qv.w, kr[u].w, s4.w);
        }
        att[j][c] = (s4.x + s4.y) + (s4.z + s4.w);
      }
    }
    __syncthreads();
    {
      const float* src = &vh[((size_t)(b * K_ + k0 + r)) * DIM_ + h * HD_ + qd];
#pragma unroll
      for (int u = 0; u < 4; ++u)
        *(float4*)&kv[r][qd + u * 4] = *(const float4*)&src[u * 4];
      if (t < KT) {
        float m = att[0][t];
        for (int j = 1; j < QP_; ++j) m = fmaxf(m, att[j][t]);
        float s = 0.f;
        for (int j = 0; j < QP_; ++j) s += __expf(att[j][t] - m);
        cmax[t] = m;
        crcp[t] = 1.f / s;
      }
    }
    __syncthreads();
    for (int e = t; e < QP_ * KT; e += 256) {
      const int jj = e >> 6;
      const int cc = e & 63;
      att[jj][cc] = __expf(att[jj][cc] - cmax[cc]) * crcp[cc];
    }
    __syncthreads();
    {
      for (int ck = 0; ck < KT; ++ck) {
        const float a = att[j2][ck];
#pragma unroll
        for (int u = 0; u < 4; ++u) {
          const float4 vv = *(const float4*)&kv[ck][cg + u * 4];
          oacc[u * 4 + 0] = fmaf(a, vv.x, oacc[u * 4 + 0]);
          oacc[u * 4 + 1] = fmaf(a, vv.y, oacc[u * 4 + 1]);
          oacc[u * 4 + 2] = fmaf(a, vv.z, oacc[u * 4 + 2]);
          oacc[u * 4 + 3] = fmaf(a, vv.w, oacc[u * 4 + 3]);
        }
      }
      if (t < 4) {  // row j = 64
        const int cg2 = t * 16;
        for (int ck = 0; ck < KT; ++ck) {
          const float a = att[64][ck];
#pragma unroll
          for (int u = 0; u < 4; ++u) {
            const float4 vv = *(const float4*)&kv[ck][cg2 + u * 4];
            oacc2[u * 4 + 0] = fmaf(a, vv.x, oacc2[u * 4 + 0]);
            oacc2[u * 4 + 1] = fmaf(a, vv.y, oacc2[u * 4 + 1]);
            oacc2[u * 4 + 2] = fmaf(a, vv.z, oacc2[u * 4 + 2]);
            oacc2[u * 4 + 3] = fmaf(a, vv.w, oacc2[u * 4 + 3]);
          }
        }
      }
    }
    __syncthreads();
  }
  {
    float* dst = &opre[((size_t)(b * QP_ + j2)) * DIM_ + h * HD_ + cg];
    *(float4*)&dst[0] = make_float4(oacc[0], oacc[1], oacc[2], oacc[3]);
    *(float4*)&dst[4] = make_float4(oacc[4], oacc[5], oacc[6], oacc[7]);
    *(float4*)&dst[8] = make_float4(oacc[8], oacc[9], oacc[10], oacc[11]);
    *(float4*)&dst[12] = make_float4(oacc[12], oacc[13], oacc[14], oacc[15]);
    if (t < 4) {
      float* dst2 = &opre[((size_t)(b * QP_ + 64)) * DIM_ + h * HD_ + t * 16];
      *(float4*)&dst2[0] = make_float4(oacc2[0], oacc2[1], oacc2[2], oacc2[3]);
      *(float4*)&dst2[4] = make_float4(oacc2[4], oacc2[5], oacc2[6], oacc2[7]);
      *(float4*)&dst2[8] = make_float4(oacc2[8], oacc2[9], oacc2[10], oacc2[11]);
      *(float4*)&dst2[12] = make_float4(oacc2[12], oacc2[13], oacc2[14], oacc2[15]);
    }
  }
}

extern "C" void kernel_launch(void* const* d_in, const int* in_sizes, int n_in,
                              void* d_out, int out_size, void* d_ws, size_t ws_size,
                              hipStream_t stream) {
  const float* q  = (const float*)d_in[0];
  const float* k  = (const float*)d_in[1];
  const float* v  = (const float*)d_in[2];
  const float* Wq = (const float*)d_in[3];
  const float* Wk = (const float*)d_in[4];
  const float* Wv = (const float*)d_in[5];
  const float* Wo = (const float*)d_in[6];
  const float* bo = (const float*)d_in[7];
  float* out = (float*)d_out;

  char* base = (char*)d_ws;
  size_t off = 0;
  auto alloc = [&](size_t bytes) {
    char* p = base + off;
    off = (off + bytes + 255) & ~(size_t)255;
    return (void*)p;
  };
  float* qh   = (float*)alloc((size_t)B_ * Q_ * DIM_ * 4);
  float* kh   = (float*)alloc((size_t)B_ * K_ * DIM_ * 4);
  float* vh   = (float*)alloc((size_t)B_ * K_ * DIM_ * 4);
  float* opre = (float*)alloc((size_t)B_ * QP_ * DIM_ * 4);
  unsigned* sbuf = (unsigned*)alloc((size_t)B_ * Q_ * 4);
  int* keep   = (int*)alloc((size_t)B_ * QP_ * 4);
  u16* kHi = (u16*)alloc((size_t)B_ * K_ * DIM_ * 2);
  u16* kLo = (u16*)alloc((size_t)B_ * K_ * DIM_ * 2);
  u16* wHi = (u16*)alloc((size_t)DIM_ * DIM_ * 2);
  u16* wLo = (u16*)alloc((size_t)DIM_ * DIM_ * 2);
  const bool big = (off <= ws_size);
  float* keepf = out + (size_t)B_ * QP_ * DIM_;

  hipMemsetAsync(sbuf, 0, B_ * Q_ * sizeof(unsigned), stream);

  const dim3 blk(256);
  if (big) {
    const long nKV8 = (long)B_ * K_ * DIM_ / 8;
    const long nW8 = (long)DIM_ * DIM_ / 8;
    split_bf16<<<2048, blk, 0, stream>>>(k, kHi, kLo, nKV8, 1);
    split_bf16<<<512, blk, 0, stream>>>(Wk, wHi, wLo, nW8, 1);
    mfma_gemm<3><<<dim3(DIM_ / 128, B_ * K_ / 128), blk, 0, stream>>>(
        kHi, kLo, wHi, wLo, kh);
    // reuse limb buffers for V (sequential on one stream)
    split_bf16<<<2048, blk, 0, stream>>>(v, kHi, nullptr, nKV8, 0);
    split_bf16<<<512, blk, 0, stream>>>(Wv, wHi, nullptr, nW8, 0);
    mfma_gemm<1><<<dim3(DIM_ / 128, B_ * K_ / 128), blk, 0, stream>>>(
        kHi, nullptr, wHi, nullptr, vh);
  } else {
    gemm_nt<<<dim3(B_ * K_ / GM, DIM_ / GN), blk, 0, stream>>>(k, Wk, kh, B_ * K_, nullptr);
    gemm_nt<<<dim3(B_ * K_ / GM, DIM_ / GN), blk, 0, stream>>>(v, Wv, vh, B_ * K_, nullptr);
  }
  gemm_nt<<<dim3(B_ * Q_ / GM, DIM_ / GN), blk, 0, stream>>>(q, Wq, qh, B_ * Q_, nullptr);
  pass_a<<<dim3(B_ * H_ * KSPLIT), blk, 0, stream>>>(qh, kh, sbuf);
  topk_kernel<<<dim3(B_), dim3(64), 0, stream>>>(sbuf, keep, keepf);
  pass_b<<<dim3(B_ * H_), blk, 0, stream>>>(qh, kh, vh, keep, opre);
  gemm_nt<<<dim3((B_ * QP_ + GM - 1) / GM, DIM_ / GN), blk, 0, stream>>>(
      opre, Wo, out, B_ * QP_, bo);
}

// Round 3
// 2765.758 us; speedup vs baseline: 1.9886x; 1.0077x over previous
//
#include <hip/hip_runtime.h>
#include <hip/hip_bf16.h>
#include <math.h>

#define B_ 16
#define Q_ 256
#define K_ 4096
#define DIM_ 1024
#define H_ 16
#define HD_ 64
#define MQ_ 64
#define QP_ 65
#define SCALE_INV 0.125f

typedef unsigned short u16;
typedef __attribute__((ext_vector_type(8))) short bf16x8;
typedef __attribute__((ext_vector_type(4))) float f32x4;

// ---------------- helpers -----------------------------------------------------
__device__ __forceinline__ u16 f2bf_rne(float f) {
  unsigned u = __float_as_uint(f);
  u += 0x7fffu + ((u >> 16) & 1u);
  return (u16)(u >> 16);
}
__device__ __forceinline__ float bf2f(u16 h) {
  return __uint_as_float(((unsigned)h) << 16);
}
__device__ __forceinline__ void gload16(const void* g, void* l) {
  __builtin_amdgcn_global_load_lds(
      (const __attribute__((address_space(1))) unsigned int*)g,
      (__attribute__((address_space(3))) unsigned int*)l, 16, 0, 0);
}

// ---------------- split fp32 -> bf16 hi/lo ------------------------------------
__global__ __launch_bounds__(256) void split_bf16(
    const float* __restrict__ x, u16* __restrict__ hi, u16* __restrict__ lo,
    long n8, int wlo) {
  long i = (long)blockIdx.x * 256 + threadIdx.x;
  const long stride = (long)gridDim.x * 256;
  for (; i < n8; i += stride) {
    const float4 a = ((const float4*)x)[2 * i];
    const float4 b = ((const float4*)x)[2 * i + 1];
    const float xs[8] = {a.x, a.y, a.z, a.w, b.x, b.y, b.z, b.w};
    u16 h[8], l[8];
#pragma unroll
    for (int j = 0; j < 8; ++j) {
      h[j] = f2bf_rne(xs[j]);
      l[j] = f2bf_rne(xs[j] - bf2f(h[j]));
    }
    uint4 hv;
    hv.x = h[0] | ((unsigned)h[1] << 16);
    hv.y = h[2] | ((unsigned)h[3] << 16);
    hv.z = h[4] | ((unsigned)h[5] << 16);
    hv.w = h[6] | ((unsigned)h[7] << 16);
    ((uint4*)hi)[i] = hv;
    if (wlo) {
      uint4 lv;
      lv.x = l[0] | ((unsigned)l[1] << 16);
      lv.y = l[2] | ((unsigned)l[3] << 16);
      lv.z = l[4] | ((unsigned)l[5] << 16);
      lv.w = l[6] | ((unsigned)l[7] << 16);
      ((uint4*)lo)[i] = lv;
    }
  }
}

// ---------------- MFMA GEMM: C[M,1024] = A @ W^T, split-bf16 limbs ------------
template <int NPROD>
__global__ __launch_bounds__(256) void mfma_gemm(
    const u16* __restrict__ Ahp, const u16* __restrict__ Alp,
    const u16* __restrict__ Bhp, const u16* __restrict__ Blp,
    float* __restrict__ C) {
  __shared__ u16 Ah_s[128 * 32];
  __shared__ u16 Bh_s[128 * 32];
  __shared__ u16 Al_s[128 * 32];
  __shared__ u16 Bl_s[128 * 32];
  const int t = threadIdx.x;
  const int wave = t >> 6;
  const int lane = t & 63;
  const int wr = wave >> 1;
  const int wc = wave & 1;
  const int n0 = blockIdx.x * 128;
  const int m0 = blockIdx.y * 128;

  const int sr0 = wave * 32 + (lane >> 2);
  const int sr1 = sr0 + 16;
  const int sw0 = ((sr0 ^ (sr0 >> 2)) & 3) ^ (lane & 3);
  const int sw1 = ((sr1 ^ (sr1 >> 2)) & 3) ^ (lane & 3);
  const size_t gA0 = (size_t)(m0 + sr0) * DIM_ + sw0 * 8;
  const size_t gA1 = (size_t)(m0 + sr1) * DIM_ + sw1 * 8;
  const size_t gB0 = (size_t)(n0 + sr0) * DIM_ + sw0 * 8;
  const size_t gB1 = (size_t)(n0 + sr1) * DIM_ + sw1 * 8;
  u16* const lA0 = &Ah_s[(wave * 32) * 32];
  u16* const lA1 = &Ah_s[(wave * 32 + 16) * 32];
  u16* const lB0 = &Bh_s[(wave * 32) * 32];
  u16* const lB1 = &Bh_s[(wave * 32 + 16) * 32];
  u16* const lAl0 = &Al_s[(wave * 32) * 32];
  u16* const lAl1 = &Al_s[(wave * 32 + 16) * 32];
  u16* const lBl0 = &Bl_s[(wave * 32) * 32];
  u16* const lBl1 = &Bl_s[(wave * 32 + 16) * 32];

  int aoff[4], boff[4];
#pragma unroll
  for (int m = 0; m < 4; ++m) {
    const int r = wr * 64 + m * 16 + (lane & 15);
    const int p = ((r ^ (r >> 2)) & 3) ^ (lane >> 4);
    aoff[m] = r * 32 + p * 8;
  }
#pragma unroll
  for (int n = 0; n < 4; ++n) {
    const int r = wc * 64 + n * 16 + (lane & 15);
    const int p = ((r ^ (r >> 2)) & 3) ^ (lane >> 4);
    boff[n] = r * 32 + p * 8;
  }

  f32x4 acc[4][4];
#pragma unroll
  for (int m = 0; m < 4; ++m)
#pragma unroll
    for (int n = 0; n < 4; ++n) acc[m][n] = (f32x4)(0.f);

  for (int k0 = 0; k0 < DIM_; k0 += 32) {
    gload16(Ahp + gA0 + k0, lA0);
    gload16(Ahp + gA1 + k0, lA1);
    gload16(Bhp + gB0 + k0, lB0);
    gload16(Bhp + gB1 + k0, lB1);
    if (NPROD == 3) {
      gload16(Alp + gA0 + k0, lAl0);
      gload16(Alp + gA1 + k0, lAl1);
      gload16(Blp + gB0 + k0, lBl0);
      gload16(Blp + gB1 + k0, lBl1);
    }
    __syncthreads();
    {
      bf16x8 af[4], bfr[4];
#pragma unroll
      for (int m = 0; m < 4; ++m) af[m] = *(const bf16x8*)&Ah_s[aoff[m]];
#pragma unroll
      for (int n = 0; n < 4; ++n) bfr[n] = *(const bf16x8*)&Bh_s[boff[n]];
#pragma unroll
      for (int m = 0; m < 4; ++m)
#pragma unroll
        for (int n = 0; n < 4; ++n)
          acc[m][n] = __builtin_amdgcn_mfma_f32_16x16x32_bf16(
              af[m], bfr[n], acc[m][n], 0, 0, 0);
      if (NPROD == 3) {
#pragma unroll
        for (int n = 0; n < 4; ++n) bfr[n] = *(const bf16x8*)&Bl_s[boff[n]];
#pragma unroll
        for (int m = 0; m < 4; ++m)
#pragma unroll
          for (int n = 0; n < 4; ++n)
            acc[m][n] = __builtin_amdgcn_mfma_f32_16x16x32_bf16(
                af[m], bfr[n], acc[m][n], 0, 0, 0);
#pragma unroll
        for (int m = 0; m < 4; ++m) af[m] = *(const bf16x8*)&Al_s[aoff[m]];
#pragma unroll
        for (int n = 0; n < 4; ++n) bfr[n] = *(const bf16x8*)&Bh_s[boff[n]];
#pragma unroll
        for (int m = 0; m < 4; ++m)
#pragma unroll
          for (int n = 0; n < 4; ++n)
            acc[m][n] = __builtin_amdgcn_mfma_f32_16x16x32_bf16(
                af[m], bfr[n], acc[m][n], 0, 0, 0);
      }
    }
    __syncthreads();
  }
#pragma unroll
  for (int m = 0; m < 4; ++m) {
    const int row = m0 + wr * 64 + m * 16 + (lane >> 4) * 4;
#pragma unroll
    for (int n = 0; n < 4; ++n) {
      const int col = n0 + wc * 64 + n * 16 + (lane & 15);
#pragma unroll
      for (int j = 0; j < 4; ++j)
        C[(size_t)(row + j) * DIM_ + col] = acc[m][n][j];
    }
  }
}

// ---------------- fp32 GEMM (q-proj, Wo, and fallback) ------------------------
#define GM 128
#define GN 128
#define GK 16

__global__ __launch_bounds__(256) void gemm_nt(
    const float* __restrict__ A, const float* __restrict__ W,
    float* __restrict__ C, int M, const float* __restrict__ bias) {
  __shared__ float As[GK][GM + 4];
  __shared__ float Ws[GK][GN + 4];
  const int t = threadIdx.x;
  const int m0 = blockIdx.x * GM;
  const int n0 = blockIdx.y * GN;
  const int lrow = t >> 2;
  const int lq = (t & 3) * 4;
  const int tm = (t >> 4) * 8;
  const int tn = (t & 15) * 8;
  float acc[8][8];
#pragma unroll
  for (int i = 0; i < 8; ++i)
#pragma unroll
    for (int j = 0; j < 8; ++j) acc[i][j] = 0.f;

  for (int k0 = 0; k0 < DIM_; k0 += GK) {
#pragma unroll
    for (int half = 0; half < 2; ++half) {
      const int row = lrow + half * 64;
      const int gm = m0 + row;
      float4 av = make_float4(0.f, 0.f, 0.f, 0.f);
      if (gm < M) av = *(const float4*)&A[(size_t)gm * DIM_ + k0 + lq];
      As[lq + 0][row] = av.x; As[lq + 1][row] = av.y;
      As[lq + 2][row] = av.z; As[lq + 3][row] = av.w;
      const int gn = n0 + row;
      const float4 wv = *(const float4*)&W[(size_t)gn * DIM_ + k0 + lq];
      Ws[lq + 0][row] = wv.x; Ws[lq + 1][row] = wv.y;
      Ws[lq + 2][row] = wv.z; Ws[lq + 3][row] = wv.w;
    }
    __syncthreads();
#pragma unroll
    for (int kk = 0; kk < GK; ++kk) {
      float a[8], bb[8];
      *(float4*)&a[0] = *(const float4*)&As[kk][tm];
      *(float4*)&a[4] = *(const float4*)&As[kk][tm + 4];
      *(float4*)&bb[0] = *(const float4*)&Ws[kk][tn];
      *(float4*)&bb[4] = *(const float4*)&Ws[kk][tn + 4];
#pragma unroll
      for (int i = 0; i < 8; ++i)
#pragma unroll
        for (int j = 0; j < 8; ++j)
          acc[i][j] = fmaf(a[i], bb[j], acc[i][j]);
    }
    __syncthreads();
  }
#pragma unroll
  for (int i = 0; i < 8; ++i) {
    const int gm = m0 + tm + i;
    if (gm < M) {
#pragma unroll
      for (int j = 0; j < 8; j += 4) {
        const int gn = n0 + tn + j;
        float4 ov;
        ov.x = acc[i][j + 0]; ov.y = acc[i][j + 1];
        ov.z = acc[i][j + 2]; ov.w = acc[i][j + 3];
        if (bias) {
          ov.x += bias[gn + 0]; ov.y += bias[gn + 1];
          ov.z += bias[gn + 2]; ov.w += bias[gn + 3];
        }
        *(float4*)&C[(size_t)gm * DIM_ + gn] = ov;
      }
    }
  }
}

// ---------------- Pass A: running max over (h,k) of (dots - lse) -------------
#define KT 64
#define DC 32
#define KSPLIT 8

__device__ __forceinline__ unsigned fflip(float x) {
  const unsigned u = __float_as_uint(x);
  return (u & 0x80000000u) ? ~u : (u | 0x80000000u);
}

__global__ __launch_bounds__(256) void pass_a(
    const float* __restrict__ qh, const float* __restrict__ kh,
    unsigned* __restrict__ sbuf) {
  __shared__ float qs[DC][Q_ + 4];
  __shared__ float ksm[DC][KT + 4];
  __shared__ float red[32][KT + 1];
  __shared__ float cmax[KT];
  __shared__ float clse[KT];
  const int blk = blockIdx.x;
  const int b = blk >> 7;             // /(H_*KSPLIT)
  const int h = (blk >> 3) & 15;
  const int ks0 = (blk & 7) * (K_ / KSPLIT);
  const int t = threadIdx.x;
  const int tq = t >> 3;
  const int tk = t & 7;
  float rmax[8];
#pragma unroll
  for (int i = 0; i < 8; ++i) rmax[i] = -3.4e38f;

  for (int k0 = ks0; k0 < ks0 + K_ / KSPLIT; k0 += KT) {
    float acc[8][8];
#pragma unroll
    for (int i = 0; i < 8; ++i)
#pragma unroll
      for (int j = 0; j < 8; ++j) acc[i][j] = 0.f;

    for (int dc = 0; dc < HD_; dc += DC) {
      {
        const float* src = &qh[((size_t)(b * Q_ + t)) * DIM_ + h * HD_ + dc];
#pragma unroll
        for (int u = 0; u < DC / 4; ++u) {
          const float4 vv = *(const float4*)&src[u * 4];
          qs[u * 4 + 0][t] = vv.x * SCALE_INV;
          qs[u * 4 + 1][t] = vv.y * SCALE_INV;
          qs[u * 4 + 2][t] = vv.z * SCALE_INV;
          qs[u * 4 + 3][t] = vv.w * SCALE_INV;
        }
      }
      {
        const int r = t >> 2;
        const int qd = (t & 3) * 8;
        const float* src =
            &kh[((size_t)(b * K_ + k0 + r)) * DIM_ + h * HD_ + dc + qd];
#pragma unroll
        for (int u = 0; u < 2; ++u) {
          const float4 vv = *(const float4*)&src[u * 4];
          ksm[qd + u * 4 + 0][r] = vv.x; ksm[qd + u * 4 + 1][r] = vv.y;
          ksm[qd + u * 4 + 2][r] = vv.z; ksm[qd + u * 4 + 3][r] = vv.w;
        }
      }
      __syncthreads();
#pragma unroll
      for (int d = 0; d < DC; ++d) {
        float a[8], bb[8];
        *(float4*)&a[0] = *(const float4*)&qs[d][tq * 8];
        *(float4*)&a[4] = *(const float4*)&qs[d][tq * 8 + 4];
        *(float4*)&bb[0] = *(const float4*)&ksm[d][tk * 8];
        *(float4*)&bb[4] = *(const float4*)&ksm[d][tk * 8 + 4];
#pragma unroll
        for (int i = 0; i < 8; ++i)
#pragma unroll
          for (int j = 0; j < 8; ++j)
            acc[i][j] = fmaf(a[i], bb[j], acc[i][j]);
      }
      __syncthreads();
    }
#pragma unroll
    for (int j = 0; j < 8; ++j) {
      float m = -3.4e38f;
#pragma unroll
      for (int i = 0; i < 8; ++i) {
        if (tq == 0 && i == 0) continue;
        m = fmaxf(m, acc[i][j]);
      }
      red[tq][tk * 8 + j] = m;
    }
    __syncthreads();
    if (t < KT) {
      float m = -3.4e38f;
      for (int g = 0; g < 32; ++g) m = fmaxf(m, red[g][t]);
      cmax[t] = m;
    }
    __syncthreads();
#pragma unroll
    for (int j = 0; j < 8; ++j) {
      const float m = cmax[tk * 8 + j];
      float s = 0.f;
#pragma unroll
      for (int i = 0; i < 8; ++i) {
        if (tq == 0 && i == 0) continue;
        s += __expf(acc[i][j] - m);
      }
      red[tq][tk * 8 + j] = s;
    }
    __syncthreads();
    if (t < KT) {
      float s = 0.f;
      for (int g = 0; g < 32; ++g) s += red[g][t];
      clse[t] = cmax[t] + logf(s);
    }
    __syncthreads();
#pragma unroll
    for (int i = 0; i < 8; ++i) {
      float v = -3.4e38f;
#pragma unroll
      for (int j = 0; j < 8; ++j) v = fmaxf(v, acc[i][j] - clse[tk * 8 + j]);
      v = fmaxf(v, __shfl_xor(v, 1, 64));
      v = fmaxf(v, __shfl_xor(v, 2, 64));
      v = fmaxf(v, __shfl_xor(v, 4, 64));
      rmax[i] = fmaxf(rmax[i], v);
    }
    __syncthreads();
  }
  if (tk == 0) {
#pragma unroll
    for (int i = 0; i < 8; ++i) {
      const int qi = tq * 8 + i;
      if (qi > 0) atomicMax(&sbuf[b * Q_ + qi], fflip(rmax[i]));
    }
  }
}

// ---------------- top-k (exact jax.lax.top_k semantics) ----------------------
__global__ void topk_kernel(const unsigned* __restrict__ sbuf,
                            int* __restrict__ keep, float* __restrict__ keepf) {
  const int b = blockIdx.x;
  const int lane = threadIdx.x;
  unsigned long long pk[4];
#pragma unroll
  for (int j = 0; j < 4; ++j) {
    const int q = 1 + lane + 64 * j;
    if (q <= 255) {
      const unsigned s = sbuf[b * Q_ + q];
      pk[j] = (((unsigned long long)s) << 32) | (unsigned)(256 - q);
    } else {
      pk[j] = 0ull;
    }
  }
  if (lane == 0) { keep[b * QP_] = 0; keepf[b * QP_] = 0.f; }
  for (int it = 0; it < MQ_; ++it) {
    unsigned long long best = pk[0];
#pragma unroll
    for (int j = 1; j < 4; ++j) best = (pk[j] > best) ? pk[j] : best;
    for (int m = 1; m < 64; m <<= 1) {
      const unsigned long long o = __shfl_xor(best, m, 64);
      best = (o > best) ? o : best;
    }
    const int q = 256 - (int)(best & 0xffffffffu);
#pragma unroll
    for (int j = 0; j < 4; ++j)
      if (pk[j] == best) pk[j] = 0ull;
    if (lane == 0) {
      keep[b * QP_ + 1 + it] = q;
      keepf[b * QP_ + 1 + it] = (float)q;
    }
  }
}

// ---------------- Pass B: competitive softmax over kept queries + PV ---------
// Split over K: softmax is per (b,h,k) column over the query axis, so k-chunks
// are fully independent; partial PV sums add exactly.
#define PSPL 8

__global__ __launch_bounds__(256) void pass_b(
    const float* __restrict__ qh, const float* __restrict__ kh,
    const float* __restrict__ vh, const int* __restrict__ keep,
    float* __restrict__ part) {
  __shared__ float qs[QP_][HD_ + 4];
  __shared__ float kv[KT][HD_ + 4];
  __shared__ float att[QP_][KT + 4];
  __shared__ float cmax[KT];
  __shared__ float crcp[KT];
  const int bx = blockIdx.x;
  const int b = bx >> 7;              // /(H_*PSPL)
  const int h = (bx >> 3) & 15;
  const int sp = bx & 7;
  const int t = threadIdx.x;

  if (t < QP_) {
    const int kq = keep[b * QP_ + t];
    const float* src = &qh[((size_t)(b * Q_ + kq)) * DIM_ + h * HD_];
#pragma unroll
    for (int u = 0; u < HD_ / 4; ++u) {
      float4 vv = *(const float4*)&src[u * 4];
      vv.x *= SCALE_INV; vv.y *= SCALE_INV;
      vv.z *= SCALE_INV; vv.w *= SCALE_INV;
      *(float4*)&qs[t][u * 4] = vv;
    }
  }
  const int c = t & 63;
  const int jg = t >> 6;
  const int j0 = jg * 17;
  const int j1 = (jg == 3) ? QP_ : (j0 + 17);
  const int j2 = t >> 2;
  const int cg = (t & 3) * 16;
  const int r = t >> 2;
  const int qd = (t & 3) * 16;
  float oacc[16], oacc2[16];
#pragma unroll
  for (int u = 0; u < 16; ++u) { oacc[u] = 0.f; oacc2[u] = 0.f; }

  __syncthreads();

  const int kbeg = sp * (K_ / PSPL);
  const int kend = kbeg + K_ / PSPL;
  for (int k0 = kbeg; k0 < kend; k0 += KT) {
    {
      const float* src = &kh[((size_t)(b * K_ + k0 + r)) * DIM_ + h * HD_ + qd];
#pragma unroll
      for (int u = 0; u < 4; ++u)
        *(float4*)&kv[r][qd + u * 4] = *(const float4*)&src[u * 4];
    }
    __syncthreads();
    {
      float4 kr[16];
#pragma unroll
      for (int u = 0; u < 16; ++u) kr[u] = *(const float4*)&kv[c][u * 4];
      for (int j = j0; j < j1; ++j) {
        float4 s4 = make_float4(0.f, 0.f, 0.f, 0.f);
#pragma unroll
        for (int u = 0; u < 16; ++u) {
          const float4 qv = *(const float4*)&qs[j][u * 4];
          s4.x = fmaf(qv.x, kr[u].x, s4.x);
          s4.y = fmaf(qv.y, kr[u].y, s4.y);
          s4.z = fmaf(qv.z, kr[u].z, s4.z);
          s4.w = fmaf(qv.w, kr[u].w, s4.w);
        }
        att[j][c] = (s4.x + s4.y) + (s4.z + s4.w);
      }
    }
    __syncthreads();
    {
      const float* src = &vh[((size_t)(b * K_ + k0 + r)) * DIM_ + h * HD_ + qd];
#pragma unroll
      for (int u = 0; u < 4; ++u)
        *(float4*)&kv[r][qd + u * 4] = *(const float4*)&src[u * 4];
      if (t < KT) {
        float m = att[0][t];
        for (int j = 1; j < QP_; ++j) m = fmaxf(m, att[j][t]);
        float s = 0.f;
        for (int j = 0; j < QP_; ++j) s += __expf(att[j][t] - m);
        cmax[t] = m;
        crcp[t] = 1.f / s;
      }
    }
    __syncthreads();
    for (int e = t; e < QP_ * KT; e += 256) {
      const int jj = e >> 6;
      const int cc = e & 63;
      att[jj][cc] = __expf(att[jj][cc] - cmax[cc]) * crcp[cc];
    }
    __syncthreads();
    {
      for (int ck = 0; ck < KT; ++ck) {
        const float a = att[j2][ck];
#pragma unroll
        for (int u = 0; u < 4; ++u) {
          const float4 vv = *(const float4*)&kv[ck][cg + u * 4];
          oacc[u * 4 + 0] = fmaf(a, vv.x, oacc[u * 4 + 0]);
          oacc[u * 4 + 1] = fmaf(a, vv.y, oacc[u * 4 + 1]);
          oacc[u * 4 + 2] = fmaf(a, vv.z, oacc[u * 4 + 2]);
          oacc[u * 4 + 3] = fmaf(a, vv.w, oacc[u * 4 + 3]);
        }
      }
      if (t < 4) {  // row j = 64
        const int cg2 = t * 16;
        for (int ck = 0; ck < KT; ++ck) {
          const float a = att[64][ck];
#pragma unroll
          for (int u = 0; u < 4; ++u) {
            const float4 vv = *(const float4*)&kv[ck][cg2 + u * 4];
            oacc2[u * 4 + 0] = fmaf(a, vv.x, oacc2[u * 4 + 0]);
            oacc2[u * 4 + 1] = fmaf(a, vv.y, oacc2[u * 4 + 1]);
            oacc2[u * 4 + 2] = fmaf(a, vv.z, oacc2[u * 4 + 2]);
            oacc2[u * 4 + 3] = fmaf(a, vv.w, oacc2[u * 4 + 3]);
          }
        }
      }
    }
    __syncthreads();
  }
  {
    float* dst =
        &part[(((size_t)sp * B_ + b) * QP_ + j2) * DIM_ + h * HD_ + cg];
    *(float4*)&dst[0] = make_float4(oacc[0], oacc[1], oacc[2], oacc[3]);
    *(float4*)&dst[4] = make_float4(oacc[4], oacc[5], oacc[6], oacc[7]);
    *(float4*)&dst[8] = make_float4(oacc[8], oacc[9], oacc[10], oacc[11]);
    *(float4*)&dst[12] = make_float4(oacc[12], oacc[13], oacc[14], oacc[15]);
    if (t < 4) {
      float* dst2 =
          &part[(((size_t)sp * B_ + b) * QP_ + 64) * DIM_ + h * HD_ + t * 16];
      *(float4*)&dst2[0] = make_float4(oacc2[0], oacc2[1], oacc2[2], oacc2[3]);
      *(float4*)&dst2[4] = make_float4(oacc2[4], oacc2[5], oacc2[6], oacc2[7]);
      *(float4*)&dst2[8] = make_float4(oacc2[8], oacc2[9], oacc2[10], oacc2[11]);
      *(float4*)&dst2[12] = make_float4(oacc2[12], oacc2[13], oacc2[14], oacc2[15]);
    }
  }
}

// ---------------- reduce partial O over splits --------------------------------
__global__ __launch_bounds__(256) void reduce_part(
    const float* __restrict__ part, float* __restrict__ opre) {
  const long n4 = (long)B_ * QP_ * DIM_ / 4;
  const long i = (long)blockIdx.x * 256 + threadIdx.x;
  if (i >= n4) return;
  float4 s = ((const float4*)part)[i];
#pragma unroll
  for (int sp = 1; sp < PSPL; ++sp) {
    const float4 p = ((const float4*)part)[(long)sp * n4 + i];
    s.x += p.x; s.y += p.y; s.z += p.z; s.w += p.w;
  }
  ((float4*)opre)[i] = s;
}

extern "C" void kernel_launch(void* const* d_in, const int* in_sizes, int n_in,
                              void* d_out, int out_size, void* d_ws, size_t ws_size,
                              hipStream_t stream) {
  const float* q  = (const float*)d_in[0];
  const float* k  = (const float*)d_in[1];
  const float* v  = (const float*)d_in[2];
  const float* Wq = (const float*)d_in[3];
  const float* Wk = (const float*)d_in[4];
  const float* Wv = (const float*)d_in[5];
  const float* Wo = (const float*)d_in[6];
  const float* bo = (const float*)d_in[7];
  float* out = (float*)d_out;

  char* base = (char*)d_ws;
  size_t off = 0;
  auto alloc = [&](size_t bytes) {
    char* p = base + off;
    off = (off + bytes + 255) & ~(size_t)255;
    return (void*)p;
  };
  float* qh   = (float*)alloc((size_t)B_ * Q_ * DIM_ * 4);
  float* kh   = (float*)alloc((size_t)B_ * K_ * DIM_ * 4);
  float* vh   = (float*)alloc((size_t)B_ * K_ * DIM_ * 4);
  float* opre = (float*)alloc((size_t)B_ * QP_ * DIM_ * 4);
  unsigned* sbuf = (unsigned*)alloc((size_t)B_ * Q_ * 4);
  int* keep   = (int*)alloc((size_t)B_ * QP_ * 4);
  u16* kHi = (u16*)alloc((size_t)B_ * K_ * DIM_ * 2);
  u16* kLo = (u16*)alloc((size_t)B_ * K_ * DIM_ * 2);
  u16* wHi = (u16*)alloc((size_t)DIM_ * DIM_ * 2);
  u16* wLo = (u16*)alloc((size_t)DIM_ * DIM_ * 2);
  const bool big = (off <= ws_size);
  // partials for pass_b: alias the (dead-by-then) kHi limb buffer when big.
  float* part = big ? (float*)kHi
                    : (float*)alloc((size_t)PSPL * B_ * QP_ * DIM_ * 4);
  float* keepf = out + (size_t)B_ * QP_ * DIM_;

  hipMemsetAsync(sbuf, 0, B_ * Q_ * sizeof(unsigned), stream);

  const dim3 blk(256);
  if (big) {
    const long nKV8 = (long)B_ * K_ * DIM_ / 8;
    const long nW8 = (long)DIM_ * DIM_ / 8;
    split_bf16<<<2048, blk, 0, stream>>>(k, kHi, kLo, nKV8, 1);
    split_bf16<<<512, blk, 0, stream>>>(Wk, wHi, wLo, nW8, 1);
    mfma_gemm<3><<<dim3(DIM_ / 128, B_ * K_ / 128), blk, 0, stream>>>(
        kHi, kLo, wHi, wLo, kh);
    split_bf16<<<2048, blk, 0, stream>>>(v, kHi, nullptr, nKV8, 0);
    split_bf16<<<512, blk, 0, stream>>>(Wv, wHi, nullptr, nW8, 0);
    mfma_gemm<1><<<dim3(DIM_ / 128, B_ * K_ / 128), blk, 0, stream>>>(
        kHi, nullptr, wHi, nullptr, vh);
  } else {
    gemm_nt<<<dim3(B_ * K_ / GM, DIM_ / GN), blk, 0, stream>>>(k, Wk, kh, B_ * K_, nullptr);
    gemm_nt<<<dim3(B_ * K_ / GM, DIM_ / GN), blk, 0, stream>>>(v, Wv, vh, B_ * K_, nullptr);
  }
  gemm_nt<<<dim3(B_ * Q_ / GM, DIM_ / GN), blk, 0, stream>>>(q, Wq, qh, B_ * Q_, nullptr);
  pass_a<<<dim3(B_ * H_ * KSPLIT), blk, 0, stream>>>(qh, kh, sbuf);
  topk_kernel<<<dim3(B_), dim3(64), 0, stream>>>(sbuf, keep, keepf);
  pass_b<<<dim3(B_ * H_ * PSPL), blk, 0, stream>>>(qh, kh, vh, keep, part);
  reduce_part<<<dim3((B_ * QP_ * DIM_ / 4 + 255) / 256), blk, 0, stream>>>(part, opre);
  gemm_nt<<<dim3((B_ * QP_ + GM - 1) / GM, DIM_ / GN), blk, 0, stream>>>(
      opre, Wo, out, B_ * QP_, bo);
}

// Round 5
// 1827.979 us; speedup vs baseline: 3.0088x; 1.5130x over previous
//
#include <hip/hip_runtime.h>
#include <hip/hip_bf16.h>
#include <math.h>

#define B_ 16
#define Q_ 256
#define K_ 4096
#define DIM_ 1024
#define H_ 16
#define HD_ 64
#define MQ_ 64
#define QP_ 65
#define SCALE_INV 0.125f

typedef unsigned short u16;
typedef __attribute__((ext_vector_type(8))) short bf16x8;
typedef __attribute__((ext_vector_type(4))) float f32x4;

// ---------------- helpers -----------------------------------------------------
__device__ __forceinline__ u16 f2bf_rne(float f) {
  unsigned u = __float_as_uint(f);
  u += 0x7fffu + ((u >> 16) & 1u);
  return (u16)(u >> 16);
}
__device__ __forceinline__ float bf2f(u16 h) {
  return __uint_as_float(((unsigned)h) << 16);
}
__device__ __forceinline__ void gload16(const void* g, void* l) {
  __builtin_amdgcn_global_load_lds(
      (const __attribute__((address_space(1))) unsigned int*)g,
      (__attribute__((address_space(3))) unsigned int*)l, 16, 0, 0);
}

// ---------------- split fp32 -> bf16 hi/lo ------------------------------------
__global__ __launch_bounds__(256) void split_bf16(
    const float* __restrict__ x, u16* __restrict__ hi, u16* __restrict__ lo,
    long n8, int wlo) {
  long i = (long)blockIdx.x * 256 + threadIdx.x;
  const long stride = (long)gridDim.x * 256;
  for (; i < n8; i += stride) {
    const float4 a = ((const float4*)x)[2 * i];
    const float4 b = ((const float4*)x)[2 * i + 1];
    const float xs[8] = {a.x, a.y, a.z, a.w, b.x, b.y, b.z, b.w};
    u16 h[8], l[8];
#pragma unroll
    for (int j = 0; j < 8; ++j) {
      h[j] = f2bf_rne(xs[j]);
      l[j] = f2bf_rne(xs[j] - bf2f(h[j]));
    }
    uint4 hv;
    hv.x = h[0] | ((unsigned)h[1] << 16);
    hv.y = h[2] | ((unsigned)h[3] << 16);
    hv.z = h[4] | ((unsigned)h[5] << 16);
    hv.w = h[6] | ((unsigned)h[7] << 16);
    ((uint4*)hi)[i] = hv;
    if (wlo) {
      uint4 lv;
      lv.x = l[0] | ((unsigned)l[1] << 16);
      lv.y = l[2] | ((unsigned)l[3] << 16);
      lv.z = l[4] | ((unsigned)l[5] << 16);
      lv.w = l[6] | ((unsigned)l[7] << 16);
      ((uint4*)lo)[i] = lv;
    }
  }
}

// ---------------- MFMA GEMM: C[M,1024] = A @ W^T, split-bf16 limbs ------------
// OUTM bit0: write fp32 C. OUTM bit1: write bf16 Cb.
template <int NPROD, int OUTM>
__global__ __launch_bounds__(256) void mfma_gemm(
    const u16* __restrict__ Ahp, const u16* __restrict__ Alp,
    const u16* __restrict__ Bhp, const u16* __restrict__ Blp,
    float* __restrict__ C, u16* __restrict__ Cb) {
  __shared__ u16 Ah_s[128 * 32];
  __shared__ u16 Bh_s[128 * 32];
  __shared__ u16 Al_s[128 * 32];
  __shared__ u16 Bl_s[128 * 32];
  const int t = threadIdx.x;
  const int wave = t >> 6;
  const int lane = t & 63;
  const int wr = wave >> 1;
  const int wc = wave & 1;
  const int n0 = blockIdx.x * 128;
  const int m0 = blockIdx.y * 128;

  const int sr0 = wave * 32 + (lane >> 2);
  const int sr1 = sr0 + 16;
  const int sw0 = ((sr0 ^ (sr0 >> 2)) & 3) ^ (lane & 3);
  const int sw1 = ((sr1 ^ (sr1 >> 2)) & 3) ^ (lane & 3);
  const size_t gA0 = (size_t)(m0 + sr0) * DIM_ + sw0 * 8;
  const size_t gA1 = (size_t)(m0 + sr1) * DIM_ + sw1 * 8;
  const size_t gB0 = (size_t)(n0 + sr0) * DIM_ + sw0 * 8;
  const size_t gB1 = (size_t)(n0 + sr1) * DIM_ + sw1 * 8;
  u16* const lA0 = &Ah_s[(wave * 32) * 32];
  u16* const lA1 = &Ah_s[(wave * 32 + 16) * 32];
  u16* const lB0 = &Bh_s[(wave * 32) * 32];
  u16* const lB1 = &Bh_s[(wave * 32 + 16) * 32];
  u16* const lAl0 = &Al_s[(wave * 32) * 32];
  u16* const lAl1 = &Al_s[(wave * 32 + 16) * 32];
  u16* const lBl0 = &Bl_s[(wave * 32) * 32];
  u16* const lBl1 = &Bl_s[(wave * 32 + 16) * 32];

  int aoff[4], boff[4];
#pragma unroll
  for (int m = 0; m < 4; ++m) {
    const int r = wr * 64 + m * 16 + (lane & 15);
    const int p = ((r ^ (r >> 2)) & 3) ^ (lane >> 4);
    aoff[m] = r * 32 + p * 8;
  }
#pragma unroll
  for (int n = 0; n < 4; ++n) {
    const int r = wc * 64 + n * 16 + (lane & 15);
    const int p = ((r ^ (r >> 2)) & 3) ^ (lane >> 4);
    boff[n] = r * 32 + p * 8;
  }

  f32x4 acc[4][4];
#pragma unroll
  for (int m = 0; m < 4; ++m)
#pragma unroll
    for (int n = 0; n < 4; ++n) acc[m][n] = (f32x4)(0.f);

  for (int k0 = 0; k0 < DIM_; k0 += 32) {
    gload16(Ahp + gA0 + k0, lA0);
    gload16(Ahp + gA1 + k0, lA1);
    gload16(Bhp + gB0 + k0, lB0);
    gload16(Bhp + gB1 + k0, lB1);
    if (NPROD == 3) {
      gload16(Alp + gA0 + k0, lAl0);
      gload16(Alp + gA1 + k0, lAl1);
      gload16(Blp + gB0 + k0, lBl0);
      gload16(Blp + gB1 + k0, lBl1);
    }
    __syncthreads();
    {
      bf16x8 af[4], bfr[4];
#pragma unroll
      for (int m = 0; m < 4; ++m) af[m] = *(const bf16x8*)&Ah_s[aoff[m]];
#pragma unroll
      for (int n = 0; n < 4; ++n) bfr[n] = *(const bf16x8*)&Bh_s[boff[n]];
#pragma unroll
      for (int m = 0; m < 4; ++m)
#pragma unroll
        for (int n = 0; n < 4; ++n)
          acc[m][n] = __builtin_amdgcn_mfma_f32_16x16x32_bf16(
              af[m], bfr[n], acc[m][n], 0, 0, 0);
      if (NPROD == 3) {
#pragma unroll
        for (int n = 0; n < 4; ++n) bfr[n] = *(const bf16x8*)&Bl_s[boff[n]];
#pragma unroll
        for (int m = 0; m < 4; ++m)
#pragma unroll
          for (int n = 0; n < 4; ++n)
            acc[m][n] = __builtin_amdgcn_mfma_f32_16x16x32_bf16(
                af[m], bfr[n], acc[m][n], 0, 0, 0);
#pragma unroll
        for (int m = 0; m < 4; ++m) af[m] = *(const bf16x8*)&Al_s[aoff[m]];
#pragma unroll
        for (int n = 0; n < 4; ++n) bfr[n] = *(const bf16x8*)&Bh_s[boff[n]];
#pragma unroll
        for (int m = 0; m < 4; ++m)
#pragma unroll
          for (int n = 0; n < 4; ++n)
            acc[m][n] = __builtin_amdgcn_mfma_f32_16x16x32_bf16(
                af[m], bfr[n], acc[m][n], 0, 0, 0);
      }
    }
    __syncthreads();
  }
#pragma unroll
  for (int m = 0; m < 4; ++m) {
    const int row = m0 + wr * 64 + m * 16 + (lane >> 4) * 4;
#pragma unroll
    for (int n = 0; n < 4; ++n) {
      const int col = n0 + wc * 64 + n * 16 + (lane & 15);
#pragma unroll
      for (int j = 0; j < 4; ++j) {
        if (OUTM & 1) C[(size_t)(row + j) * DIM_ + col] = acc[m][n][j];
        if (OUTM & 2) Cb[(size_t)(row + j) * DIM_ + col] = f2bf_rne(acc[m][n][j]);
      }
    }
  }
}

// ---------------- fp32 GEMM (q-proj, Wo, and fallback) ------------------------
#define GM 128
#define GN 128
#define GK 16

__global__ __launch_bounds__(256) void gemm_nt(
    const float* __restrict__ A, const float* __restrict__ W,
    float* __restrict__ C, int M, const float* __restrict__ bias) {
  __shared__ float As[GK][GM + 4];
  __shared__ float Ws[GK][GN + 4];
  const int t = threadIdx.x;
  const int m0 = blockIdx.x * GM;
  const int n0 = blockIdx.y * GN;
  const int lrow = t >> 2;
  const int lq = (t & 3) * 4;
  const int tm = (t >> 4) * 8;
  const int tn = (t & 15) * 8;
  float acc[8][8];
#pragma unroll
  for (int i = 0; i < 8; ++i)
#pragma unroll
    for (int j = 0; j < 8; ++j) acc[i][j] = 0.f;

  for (int k0 = 0; k0 < DIM_; k0 += GK) {
#pragma unroll
    for (int half = 0; half < 2; ++half) {
      const int row = lrow + half * 64;
      const int gm = m0 + row;
      float4 av = make_float4(0.f, 0.f, 0.f, 0.f);
      if (gm < M) av = *(const float4*)&A[(size_t)gm * DIM_ + k0 + lq];
      As[lq + 0][row] = av.x; As[lq + 1][row] = av.y;
      As[lq + 2][row] = av.z; As[lq + 3][row] = av.w;
      const int gn = n0 + row;
      const float4 wv = *(const float4*)&W[(size_t)gn * DIM_ + k0 + lq];
      Ws[lq + 0][row] = wv.x; Ws[lq + 1][row] = wv.y;
      Ws[lq + 2][row] = wv.z; Ws[lq + 3][row] = wv.w;
    }
    __syncthreads();
#pragma unroll
    for (int kk = 0; kk < GK; ++kk) {
      float a[8], bb[8];
      *(float4*)&a[0] = *(const float4*)&As[kk][tm];
      *(float4*)&a[4] = *(const float4*)&As[kk][tm + 4];
      *(float4*)&bb[0] = *(const float4*)&Ws[kk][tn];
      *(float4*)&bb[4] = *(const float4*)&Ws[kk][tn + 4];
#pragma unroll
      for (int i = 0; i < 8; ++i)
#pragma unroll
        for (int j = 0; j < 8; ++j)
          acc[i][j] = fmaf(a[i], bb[j], acc[i][j]);
    }
    __syncthreads();
  }
#pragma unroll
  for (int i = 0; i < 8; ++i) {
    const int gm = m0 + tm + i;
    if (gm < M) {
#pragma unroll
      for (int j = 0; j < 8; j += 4) {
        const int gn = n0 + tn + j;
        float4 ov;
        ov.x = acc[i][j + 0]; ov.y = acc[i][j + 1];
        ov.z = acc[i][j + 2]; ov.w = acc[i][j + 3];
        if (bias) {
          ov.x += bias[gn + 0]; ov.y += bias[gn + 1];
          ov.z += bias[gn + 2]; ov.w += bias[gn + 3];
        }
        *(float4*)&C[(size_t)gm * DIM_ + gn] = ov;
      }
    }
  }
}

// ---------------- Pass A: running max over (h,k) of (dots - lse) -------------
#define KT 64
#define DC 32
#define KSPLIT 8

__device__ __forceinline__ unsigned fflip(float x) {
  const unsigned u = __float_as_uint(x);
  return (u & 0x80000000u) ? ~u : (u | 0x80000000u);
}

__global__ __launch_bounds__(256) void pass_a(
    const float* __restrict__ qh, const float* __restrict__ kh,
    unsigned* __restrict__ sbuf) {
  __shared__ float qs[DC][Q_ + 4];
  __shared__ float ksm[DC][KT + 4];
  __shared__ float red[32][KT + 1];
  __shared__ float cmax[KT];
  __shared__ float clse[KT];
  const int blk = blockIdx.x;
  const int b = blk >> 7;
  const int h = (blk >> 3) & 15;
  const int ks0 = (blk & 7) * (K_ / KSPLIT);
  const int t = threadIdx.x;
  const int tq = t >> 3;
  const int tk = t & 7;
  float rmax[8];
#pragma unroll
  for (int i = 0; i < 8; ++i) rmax[i] = -3.4e38f;

  for (int k0 = ks0; k0 < ks0 + K_ / KSPLIT; k0 += KT) {
    float acc[8][8];
#pragma unroll
    for (int i = 0; i < 8; ++i)
#pragma unroll
      for (int j = 0; j < 8; ++j) acc[i][j] = 0.f;

    for (int dc = 0; dc < HD_; dc += DC) {
      {
        const float* src = &qh[((size_t)(b * Q_ + t)) * DIM_ + h * HD_ + dc];
#pragma unroll
        for (int u = 0; u < DC / 4; ++u) {
          const float4 vv = *(const float4*)&src[u * 4];
          qs[u * 4 + 0][t] = vv.x * SCALE_INV;
          qs[u * 4 + 1][t] = vv.y * SCALE_INV;
          qs[u * 4 + 2][t] = vv.z * SCALE_INV;
          qs[u * 4 + 3][t] = vv.w * SCALE_INV;
        }
      }
      {
        const int r = t >> 2;
        const int qd = (t & 3) * 8;
        const float* src =
            &kh[((size_t)(b * K_ + k0 + r)) * DIM_ + h * HD_ + dc + qd];
#pragma unroll
        for (int u = 0; u < 2; ++u) {
          const float4 vv = *(const float4*)&src[u * 4];
          ksm[qd + u * 4 + 0][r] = vv.x; ksm[qd + u * 4 + 1][r] = vv.y;
          ksm[qd + u * 4 + 2][r] = vv.z; ksm[qd + u * 4 + 3][r] = vv.w;
        }
      }
      __syncthreads();
#pragma unroll
      for (int d = 0; d < DC; ++d) {
        float a[8], bb[8];
        *(float4*)&a[0] = *(const float4*)&qs[d][tq * 8];
        *(float4*)&a[4] = *(const float4*)&qs[d][tq * 8 + 4];
        *(float4*)&bb[0] = *(const float4*)&ksm[d][tk * 8];
        *(float4*)&bb[4] = *(const float4*)&ksm[d][tk * 8 + 4];
#pragma unroll
        for (int i = 0; i < 8; ++i)
#pragma unroll
          for (int j = 0; j < 8; ++j)
            acc[i][j] = fmaf(a[i], bb[j], acc[i][j]);
      }
      __syncthreads();
    }
#pragma unroll
    for (int j = 0; j < 8; ++j) {
      float m = -3.4e38f;
#pragma unroll
      for (int i = 0; i < 8; ++i) {
        if (tq == 0 && i == 0) continue;
        m = fmaxf(m, acc[i][j]);
      }
      red[tq][tk * 8 + j] = m;
    }
    __syncthreads();
    if (t < KT) {
      float m = -3.4e38f;
      for (int g = 0; g < 32; ++g) m = fmaxf(m, red[g][t]);
      cmax[t] = m;
    }
    __syncthreads();
#pragma unroll
    for (int j = 0; j < 8; ++j) {
      const float m = cmax[tk * 8 + j];
      float s = 0.f;
#pragma unroll
      for (int i = 0; i < 8; ++i) {
        if (tq == 0 && i == 0) continue;
        s += __expf(acc[i][j] - m);
      }
      red[tq][tk * 8 + j] = s;
    }
    __syncthreads();
    if (t < KT) {
      float s = 0.f;
      for (int g = 0; g < 32; ++g) s += red[g][t];
      clse[t] = cmax[t] + logf(s);
    }
    __syncthreads();
#pragma unroll
    for (int i = 0; i < 8; ++i) {
      float v = -3.4e38f;
#pragma unroll
      for (int j = 0; j < 8; ++j) v = fmaxf(v, acc[i][j] - clse[tk * 8 + j]);
      v = fmaxf(v, __shfl_xor(v, 1, 64));
      v = fmaxf(v, __shfl_xor(v, 2, 64));
      v = fmaxf(v, __shfl_xor(v, 4, 64));
      rmax[i] = fmaxf(rmax[i], v);
    }
    __syncthreads();
  }
  if (tk == 0) {
#pragma unroll
    for (int i = 0; i < 8; ++i) {
      const int qi = tq * 8 + i;
      if (qi > 0) atomicMax(&sbuf[b * Q_ + qi], fflip(rmax[i]));
    }
  }
}

// ---------------- top-k (exact jax.lax.top_k semantics) ----------------------
__global__ void topk_kernel(const unsigned* __restrict__ sbuf,
                            int* __restrict__ keep, float* __restrict__ keepf) {
  const int b = blockIdx.x;
  const int lane = threadIdx.x;
  unsigned long long pk[4];
#pragma unroll
  for (int j = 0; j < 4; ++j) {
    const int q = 1 + lane + 64 * j;
    if (q <= 255) {
      const unsigned s = sbuf[b * Q_ + q];
      pk[j] = (((unsigned long long)s) << 32) | (unsigned)(256 - q);
    } else {
      pk[j] = 0ull;
    }
  }
  if (lane == 0) { keep[b * QP_] = 0; keepf[b * QP_] = 0.f; }
  for (int it = 0; it < MQ_; ++it) {
    unsigned long long best = pk[0];
#pragma unroll
    for (int j = 1; j < 4; ++j) best = (pk[j] > best) ? pk[j] : best;
    for (int m = 1; m < 64; m <<= 1) {
      const unsigned long long o = __shfl_xor(best, m, 64);
      best = (o > best) ? o : best;
    }
    const int q = 256 - (int)(best & 0xffffffffu);
#pragma unroll
    for (int j = 0; j < 4; ++j)
      if (pk[j] == best) pk[j] = 0ull;
    if (lane == 0) {
      keep[b * QP_ + 1 + it] = q;
      keepf[b * QP_ + 1 + it] = (float)q;
    }
  }
}

// ---------------- Pass B (MFMA): competitive softmax + PV, bf16 ---------------
#define PSPL 4

__global__ __launch_bounds__(256) void pass_b_mfma(
    const float* __restrict__ qh, const u16* __restrict__ khb,
    const u16* __restrict__ vhb, const int* __restrict__ keep,
    float* __restrict__ part) {
  __shared__ __align__(16) char SH[72960];
  u16* const Qs = (u16*)SH;                  // [80][72] bf16
  u16* const Ks = (u16*)(SH + 11520);        // [128][72] bf16
  u16* const Vs = (u16*)(SH + 29952);        // [128][68] bf16
  u16* const Ps = (u16*)(SH + 47360);        // [4][80][40] bf16 (per-wave)
  float* const osum = (float*)(SH + 11520);  // [4][80][17] f32 (aliases K/V)

  const int bx = blockIdx.x;
  const int b = bx >> 6;
  const int h = (bx >> 2) & 15;
  const int sp = bx & 3;
  const int t = threadIdx.x;
  const int w = t >> 6;
  const int l = t & 63;
  const int g = l >> 4;
  const int a15 = l & 15;

  // ---- stage Q: 65 kept rows (scaled 1/8) -> bf16 LDS; rows 65..79 zero ----
  for (int idx = t; idx < 80 * 8; idx += 256) {
    const int row = idx >> 3, ch = idx & 7;
    uint4 pk;
    if (row < QP_) {
      const int kq = keep[b * QP_ + row];
      const float* src = &qh[((size_t)(b * Q_ + kq)) * DIM_ + h * HD_ + ch * 8];
      const float4 x0 = *(const float4*)&src[0];
      const float4 x1 = *(const float4*)&src[4];
      pk.x = f2bf_rne(x0.x * SCALE_INV) | ((unsigned)f2bf_rne(x0.y * SCALE_INV) << 16);
      pk.y = f2bf_rne(x0.z * SCALE_INV) | ((unsigned)f2bf_rne(x0.w * SCALE_INV) << 16);
      pk.z = f2bf_rne(x1.x * SCALE_INV) | ((unsigned)f2bf_rne(x1.y * SCALE_INV) << 16);
      pk.w = f2bf_rne(x1.z * SCALE_INV) | ((unsigned)f2bf_rne(x1.w * SCALE_INV) << 16);
    } else {
      pk = make_uint4(0, 0, 0, 0);
    }
    *(uint4*)&Qs[row * 72 + ch * 8] = pk;
  }
  __syncthreads();

  f32x4 oacc[5][4];
#pragma unroll
  for (int mt = 0; mt < 5; ++mt)
#pragma unroll
    for (int dt = 0; dt < 4; ++dt) oacc[mt][dt] = (f32x4)(0.f);

  const int kt0 = sp * (K_ / PSPL);
  for (int kt = 0; kt < K_ / PSPL; kt += 128) {
    const int k0 = kt0 + kt;
    // ---- reg-stage K,V tiles (128x64 bf16 each) ----
    uint4 kreg[4], vreg[4];
    int srow[4], sch[4];
#pragma unroll
    for (int s = 0; s < 4; ++s) {
      const int c = t + 256 * s;
      srow[s] = c >> 3;
      sch[s] = c & 7;
      const size_t gidx =
          ((size_t)(b * K_ + k0 + srow[s])) * DIM_ + h * HD_ + sch[s] * 8;
      kreg[s] = *(const uint4*)&khb[gidx];
      vreg[s] = *(const uint4*)&vhb[gidx];
    }
    __syncthreads();  // previous iter's LDS reads done
#pragma unroll
    for (int s = 0; s < 4; ++s) {
      *(uint4*)&Ks[srow[s] * 72 + sch[s] * 8] = kreg[s];
      uint2 v0; v0.x = vreg[s].x; v0.y = vreg[s].y;
      uint2 v1; v1.x = vreg[s].z; v1.y = vreg[s].w;
      *(uint2*)&Vs[srow[s] * 68 + sch[s] * 8] = v0;
      *(uint2*)&Vs[srow[s] * 68 + sch[s] * 8 + 4] = v1;
    }
    __syncthreads();

    // ---- QK^T: S[q 80][k 32] per wave ----
    f32x4 S[5][2];
#pragma unroll
    for (int mt = 0; mt < 5; ++mt)
#pragma unroll
      for (int nt = 0; nt < 2; ++nt) S[mt][nt] = (f32x4)(0.f);
#pragma unroll
    for (int kk = 0; kk < 2; ++kk) {
      bf16x8 aq[5];
#pragma unroll
      for (int mt = 0; mt < 5; ++mt)
        aq[mt] = *(const bf16x8*)&Qs[(mt * 16 + a15) * 72 + kk * 32 + g * 8];
#pragma unroll
      for (int nt = 0; nt < 2; ++nt) {
        const bf16x8 bk =
            *(const bf16x8*)&Ks[(w * 32 + nt * 16 + a15) * 72 + kk * 32 + g * 8];
#pragma unroll
        for (int mt = 0; mt < 5; ++mt)
          S[mt][nt] = __builtin_amdgcn_mfma_f32_16x16x32_bf16(aq[mt], bk,
                                                              S[mt][nt], 0, 0, 0);
      }
    }
    // ---- per-column softmax over q (mask q>64) + P to LDS (bf16) ----
#pragma unroll
    for (int nt = 0; nt < 2; ++nt) {
      float m = -3.4e38f;
#pragma unroll
      for (int mt = 0; mt < 5; ++mt)
#pragma unroll
        for (int j = 0; j < 4; ++j) {
          const bool valid = (mt < 4) | ((g == 0) & (j == 0));
          if (valid) m = fmaxf(m, S[mt][nt][j]);
        }
      m = fmaxf(m, __shfl_xor(m, 16, 64));
      m = fmaxf(m, __shfl_xor(m, 32, 64));
      float s = 0.f;
#pragma unroll
      for (int mt = 0; mt < 5; ++mt)
#pragma unroll
        for (int j = 0; j < 4; ++j) {
          const bool valid = (mt < 4) | ((g == 0) & (j == 0));
          const float p = valid ? __expf(S[mt][nt][j] - m) : 0.f;
          S[mt][nt][j] = p;
          s += p;
        }
      s += __shfl_xor(s, 16, 64);
      s += __shfl_xor(s, 32, 64);
      const float r = 1.f / s;
#pragma unroll
      for (int mt = 0; mt < 5; ++mt)
#pragma unroll
        for (int j = 0; j < 4; ++j)
          Ps[w * 3200 + (mt * 16 + g * 4 + j) * 40 + nt * 16 + a15] =
              f2bf_rne(S[mt][nt][j] * r);
    }
    // ---- PV: O[q 80][d 64] += P[q][32k] * V[32k][d] ----
    bf16x8 ap[5];
#pragma unroll
    for (int mt = 0; mt < 5; ++mt)
      ap[mt] = *(const bf16x8*)&Ps[w * 3200 + (mt * 16 + a15) * 40 + g * 8];
#pragma unroll
    for (int dt = 0; dt < 4; ++dt) {
      bf16x8 bv;
#pragma unroll
      for (int e = 0; e < 8; ++e)
        bv[e] = (short)Vs[(w * 32 + g * 8 + e) * 68 + dt * 16 + a15];
#pragma unroll
      for (int mt = 0; mt < 5; ++mt)
        oacc[mt][dt] = __builtin_amdgcn_mfma_f32_16x16x32_bf16(ap[mt], bv,
                                                               oacc[mt][dt], 0, 0, 0);
    }
  }

  // ---- combine 4 waves' partial O and write block partial ----
#pragma unroll
  for (int dt = 0; dt < 4; ++dt) {
    __syncthreads();
#pragma unroll
    for (int mt = 0; mt < 5; ++mt)
#pragma unroll
      for (int j = 0; j < 4; ++j)
        osum[w * 1360 + (mt * 16 + g * 4 + j) * 17 + a15] = oacc[mt][dt][j];
    __syncthreads();
    for (int idx = t; idx < QP_ * 16; idx += 256) {
      const int q = idx >> 4, c = idx & 15;
      const float sm = osum[q * 17 + c] + osum[1360 + q * 17 + c] +
                       osum[2720 + q * 17 + c] + osum[4080 + q * 17 + c];
      part[(((size_t)sp * B_ + b) * QP_ + q) * DIM_ + h * 64 + dt * 16 + c] = sm;
    }
  }
}

// ---------------- Pass B fallback (fp32 VALU, small-ws path) ------------------
__global__ __launch_bounds__(256) void pass_b(
    const float* __restrict__ qh, const float* __restrict__ kh,
    const float* __restrict__ vh, const int* __restrict__ keep,
    float* __restrict__ part) {
  __shared__ float qs[QP_][HD_ + 4];
  __shared__ float kv[KT][HD_ + 4];
  __shared__ float att[QP_][KT + 4];
  __shared__ float cmax[KT];
  __shared__ float crcp[KT];
  const int bx = blockIdx.x;
  const int b = bx >> 6;
  const int h = (bx >> 2) & 15;
  const int sp = bx & 3;
  const int t = threadIdx.x;

  if (t < QP_) {
    const int kq = keep[b * QP_ + t];
    const float* src = &qh[((size_t)(b * Q_ + kq)) * DIM_ + h * HD_];
#pragma unroll
    for (int u = 0; u < HD_ / 4; ++u) {
      float4 vv = *(const float4*)&src[u * 4];
      vv.x *= SCALE_INV; vv.y *= SCALE_INV;
      vv.z *= SCALE_INV; vv.w *= SCALE_INV;
      *(float4*)&qs[t][u * 4] = vv;
    }
  }
  const int c = t & 63;
  const int jg = t >> 6;
  const int j0 = jg * 17;
  const int j1 = (jg == 3) ? QP_ : (j0 + 17);
  const int j2 = t >> 2;
  const int cg = (t & 3) * 16;
  const int r = t >> 2;
  const int qd = (t & 3) * 16;
  float oacc[16], oacc2[16];
#pragma unroll
  for (int u = 0; u < 16; ++u) { oacc[u] = 0.f; oacc2[u] = 0.f; }

  __syncthreads();

  const int kbeg = sp * (K_ / PSPL);
  const int kend = kbeg + K_ / PSPL;
  for (int k0 = kbeg; k0 < kend; k0 += KT) {
    {
      const float* src = &kh[((size_t)(b * K_ + k0 + r)) * DIM_ + h * HD_ + qd];
#pragma unroll
      for (int u = 0; u < 4; ++u)
        *(float4*)&kv[r][qd + u * 4] = *(const float4*)&src[u * 4];
    }
    __syncthreads();
    {
      float4 kr[16];
#pragma unroll
      for (int u = 0; u < 16; ++u) kr[u] = *(const float4*)&kv[c][u * 4];
      for (int j = j0; j < j1; ++j) {
        float4 s4 = make_float4(0.f, 0.f, 0.f, 0.f);
#pragma unroll
        for (int u = 0; u < 16; ++u) {
          const float4 qv = *(const float4*)&qs[j][u * 4];
          s4.x = fmaf(qv.x, kr[u].x, s4.x);
          s4.y = fmaf(qv.y, kr[u].y, s4.y);
          s4.z = fmaf(qv.z, kr[u].z, s4.z);
          s4.w = fmaf(qv.w, kr[u].w, s4.w);
        }
        att[j][c] = (s4.x + s4.y) + (s4.z + s4.w);
      }
    }
    __syncthreads();
    {
      const float* src = &vh[((size_t)(b * K_ + k0 + r)) * DIM_ + h * HD_ + qd];
#pragma unroll
      for (int u = 0; u < 4; ++u)
        *(float4*)&kv[r][qd + u * 4] = *(const float4*)&src[u * 4];
      if (t < KT) {
        float m = att[0][t];
        for (int j = 1; j < QP_; ++j) m = fmaxf(m, att[j][t]);
        float s = 0.f;
        for (int j = 0; j < QP_; ++j) s += __expf(att[j][t] - m);
        cmax[t] = m;
        crcp[t] = 1.f / s;
      }
    }
    __syncthreads();
    for (int e = t; e < QP_ * KT; e += 256) {
      const int jj = e >> 6;
      const int cc = e & 63;
      att[jj][cc] = __expf(att[jj][cc] - cmax[cc]) * crcp[cc];
    }
    __syncthreads();
    {
      for (int ck = 0; ck < KT; ++ck) {
        const float a = att[j2][ck];
#pragma unroll
        for (int u = 0; u < 4; ++u) {
          const float4 vv = *(const float4*)&kv[ck][cg + u * 4];
          oacc[u * 4 + 0] = fmaf(a, vv.x, oacc[u * 4 + 0]);
          oacc[u * 4 + 1] = fmaf(a, vv.y, oacc[u * 4 + 1]);
          oacc[u * 4 + 2] = fmaf(a, vv.z, oacc[u * 4 + 2]);
          oacc[u * 4 + 3] = fmaf(a, vv.w, oacc[u * 4 + 3]);
        }
      }
      if (t < 4) {
        const int cg2 = t * 16;
        for (int ck = 0; ck < KT; ++ck) {
          const float a = att[64][ck];
#pragma unroll
          for (int u = 0; u < 4; ++u) {
            const float4 vv = *(const float4*)&kv[ck][cg2 + u * 4];
            oacc2[u * 4 + 0] = fmaf(a, vv.x, oacc2[u * 4 + 0]);
            oacc2[u * 4 + 1] = fmaf(a, vv.y, oacc2[u * 4 + 1]);
            oacc2[u * 4 + 2] = fmaf(a, vv.z, oacc2[u * 4 + 2]);
            oacc2[u * 4 + 3] = fmaf(a, vv.w, oacc2[u * 4 + 3]);
          }
        }
      }
    }
    __syncthreads();
  }
  {
    float* dst =
        &part[(((size_t)sp * B_ + b) * QP_ + j2) * DIM_ + h * HD_ + cg];
    *(float4*)&dst[0] = make_float4(oacc[0], oacc[1], oacc[2], oacc[3]);
    *(float4*)&dst[4] = make_float4(oacc[4], oacc[5], oacc[6], oacc[7]);
    *(float4*)&dst[8] = make_float4(oacc[8], oacc[9], oacc[10], oacc[11]);
    *(float4*)&dst[12] = make_float4(oacc[12], oacc[13], oacc[14], oacc[15]);
    if (t < 4) {
      float* dst2 =
          &part[(((size_t)sp * B_ + b) * QP_ + 64) * DIM_ + h * HD_ + t * 16];
      *(float4*)&dst2[0] = make_float4(oacc2[0], oacc2[1], oacc2[2], oacc2[3]);
      *(float4*)&dst2[4] = make_float4(oacc2[4], oacc2[5], oacc2[6], oacc2[7]);
      *(float4*)&dst2[8] = make_float4(oacc2[8], oacc2[9], oacc2[10], oacc2[11]);
      *(float4*)&dst2[12] = make_float4(oacc2[12], oacc2[13], oacc2[14], oacc2[15]);
    }
  }
}

// ---------------- reduce partial O over splits --------------------------------
__global__ __launch_bounds__(256) void reduce_part(
    const float* __restrict__ part, float* __restrict__ opre) {
  const long n4 = (long)B_ * QP_ * DIM_ / 4;
  const long i = (long)blockIdx.x * 256 + threadIdx.x;
  if (i >= n4) return;
  float4 s = ((const float4*)part)[i];
#pragma unroll
  for (int sp = 1; sp < PSPL; ++sp) {
    const float4 p = ((const float4*)part)[(long)sp * n4 + i];
    s.x += p.x; s.y += p.y; s.z += p.z; s.w += p.w;
  }
  ((float4*)opre)[i] = s;
}

extern "C" void kernel_launch(void* const* d_in, const int* in_sizes, int n_in,
                              void* d_out, int out_size, void* d_ws, size_t ws_size,
                              hipStream_t stream) {
  const float* q  = (const float*)d_in[0];
  const float* k  = (const float*)d_in[1];
  const float* v  = (const float*)d_in[2];
  const float* Wq = (const float*)d_in[3];
  const float* Wk = (const float*)d_in[4];
  const float* Wv = (const float*)d_in[5];
  const float* Wo = (const float*)d_in[6];
  const float* bo = (const float*)d_in[7];
  float* out = (float*)d_out;

  char* base = (char*)d_ws;
  size_t off = 0;
  auto alloc = [&](size_t bytes) {
    char* p = base + off;
    off = (off + bytes + 255) & ~(size_t)255;
    return (void*)p;
  };
  float* qh   = (float*)alloc((size_t)B_ * Q_ * DIM_ * 4);
  float* kh   = (float*)alloc((size_t)B_ * K_ * DIM_ * 4);
  float* opre = (float*)alloc((size_t)B_ * QP_ * DIM_ * 4);
  unsigned* sbuf = (unsigned*)alloc((size_t)B_ * Q_ * 4);
  int* keep   = (int*)alloc((size_t)B_ * QP_ * 4);
  u16* kh_b = (u16*)alloc((size_t)B_ * K_ * DIM_ * 2);
  u16* vh_b = (u16*)alloc((size_t)B_ * K_ * DIM_ * 2);
  u16* kHi = (u16*)alloc((size_t)B_ * K_ * DIM_ * 2);
  u16* kLo = (u16*)alloc((size_t)B_ * K_ * DIM_ * 2);
  u16* wHi = (u16*)alloc((size_t)DIM_ * DIM_ * 2);
  u16* wLo = (u16*)alloc((size_t)DIM_ * DIM_ * 2);
  const bool big = (off <= ws_size);
  // partials alias the (dead-by-then) kHi region (17MB << 128MB) when big.
  float* part = big ? (float*)kHi
                    : (float*)alloc((size_t)PSPL * B_ * QP_ * DIM_ * 4);
  // fallback fp32 vh aliases kh_b+vh_b (256MB)
  float* vh_f = (float*)kh_b;
  float* keepf = out + (size_t)B_ * QP_ * DIM_;

  hipMemsetAsync(sbuf, 0, B_ * Q_ * sizeof(unsigned), stream);

  const dim3 blk(256);
  if (big) {
    const long nKV8 = (long)B_ * K_ * DIM_ / 8;
    const long nW8 = (long)DIM_ * DIM_ / 8;
    split_bf16<<<2048, blk, 0, stream>>>(k, kHi, kLo, nKV8, 1);
    split_bf16<<<512, blk, 0, stream>>>(Wk, wHi, wLo, nW8, 1);
    mfma_gemm<3, 3><<<dim3(DIM_ / 128, B_ * K_ / 128), blk, 0, stream>>>(
        kHi, kLo, wHi, wLo, kh, kh_b);
    split_bf16<<<2048, blk, 0, stream>>>(v, kHi, nullptr, nKV8, 0);
    split_bf16<<<512, blk, 0, stream>>>(Wv, wHi, nullptr, nW8, 0);
    mfma_gemm<1, 2><<<dim3(DIM_ / 128, B_ * K_ / 128), blk, 0, stream>>>(
        kHi, nullptr, wHi, nullptr, nullptr, vh_b);
  } else {
    gemm_nt<<<dim3(B_ * K_ / GM, DIM_ / GN), blk, 0, stream>>>(k, Wk, kh, B_ * K_, nullptr);
    gemm_nt<<<dim3(B_ * K_ / GM, DIM_ / GN), blk, 0, stream>>>(v, Wv, vh_f, B_ * K_, nullptr);
  }
  gemm_nt<<<dim3(B_ * Q_ / GM, DIM_ / GN), blk, 0, stream>>>(q, Wq, qh, B_ * Q_, nullptr);
  pass_a<<<dim3(B_ * H_ * KSPLIT), blk, 0, stream>>>(qh, kh, sbuf);
  topk_kernel<<<dim3(B_), dim3(64), 0, stream>>>(sbuf, keep, keepf);
  if (big) {
    pass_b_mfma<<<dim3(B_ * H_ * PSPL), blk, 0, stream>>>(qh, kh_b, vh_b, keep, part);
  } else {
    pass_b<<<dim3(B_ * H_ * PSPL), blk, 0, stream>>>(qh, kh, vh_f, keep, part);
  }
  reduce_part<<<dim3((B_ * QP_ * DIM_ / 4 + 255) / 256), blk, 0, stream>>>(part, opre);
  gemm_nt<<<dim3((B_ * QP_ + GM - 1) / GM, DIM_ / GN), blk, 0, stream>>>(
      opre, Wo, out, B_ * QP_, bo);
}

// Round 6
// 1511.554 us; speedup vs baseline: 3.6387x; 1.2093x over previous
//
#include <hip/hip_runtime.h>
#include <hip/hip_bf16.h>
#include <math.h>

#define B_ 16
#define Q_ 256
#define K_ 4096
#define DIM_ 1024
#define H_ 16
#define HD_ 64
#define MQ_ 64
#define QP_ 65
#define SCALE_INV 0.125f

typedef unsigned short u16;
typedef __attribute__((ext_vector_type(8))) short bf16x8;
typedef __attribute__((ext_vector_type(8))) _Float16 f16x8;
typedef __attribute__((ext_vector_type(8))) short s16x8;
typedef __attribute__((ext_vector_type(4))) float f32x4;

// ---------------- helpers -----------------------------------------------------
__device__ __forceinline__ u16 f2bf_rne(float f) {
  unsigned u = __float_as_uint(f);
  u += 0x7fffu + ((u >> 16) & 1u);
  return (u16)(u >> 16);
}
__device__ __forceinline__ float bf2f(u16 h) {
  return __uint_as_float(((unsigned)h) << 16);
}
__device__ __forceinline__ u16 f2h_bits(float f) {
  _Float16 h = (_Float16)f;
  return *(u16*)&h;
}
__device__ __forceinline__ f16x8 as_f16x8(s16x8 v) {
  return __builtin_bit_cast(f16x8, v);
}
__device__ __forceinline__ void gload16(const void* g, void* l) {
  __builtin_amdgcn_global_load_lds(
      (const __attribute__((address_space(1))) unsigned int*)g,
      (__attribute__((address_space(3))) unsigned int*)l, 16, 0, 0);
}

// ---------------- split fp32 -> bf16 hi/lo (for GEMM inputs) ------------------
__global__ __launch_bounds__(256) void split_bf16(
    const float* __restrict__ x, u16* __restrict__ hi, u16* __restrict__ lo,
    long n8, int wlo) {
  long i = (long)blockIdx.x * 256 + threadIdx.x;
  const long stride = (long)gridDim.x * 256;
  for (; i < n8; i += stride) {
    const float4 a = ((const float4*)x)[2 * i];
    const float4 b = ((const float4*)x)[2 * i + 1];
    const float xs[8] = {a.x, a.y, a.z, a.w, b.x, b.y, b.z, b.w};
    u16 h[8], l[8];
#pragma unroll
    for (int j = 0; j < 8; ++j) {
      h[j] = f2bf_rne(xs[j]);
      l[j] = f2bf_rne(xs[j] - bf2f(h[j]));
    }
    uint4 hv;
    hv.x = h[0] | ((unsigned)h[1] << 16);
    hv.y = h[2] | ((unsigned)h[3] << 16);
    hv.z = h[4] | ((unsigned)h[5] << 16);
    hv.w = h[6] | ((unsigned)h[7] << 16);
    ((uint4*)hi)[i] = hv;
    if (wlo) {
      uint4 lv;
      lv.x = l[0] | ((unsigned)l[1] << 16);
      lv.y = l[2] | ((unsigned)l[3] << 16);
      lv.z = l[4] | ((unsigned)l[5] << 16);
      lv.w = l[6] | ((unsigned)l[7] << 16);
      ((uint4*)lo)[i] = lv;
    }
  }
}

// ---------------- split fp32 -> f16 hi/lo (for pass_a QK) ---------------------
__global__ __launch_bounds__(256) void split_f16(
    const float* __restrict__ x, u16* __restrict__ hi, u16* __restrict__ lo,
    long n8) {
  long i = (long)blockIdx.x * 256 + threadIdx.x;
  const long stride = (long)gridDim.x * 256;
  for (; i < n8; i += stride) {
    const float4 a = ((const float4*)x)[2 * i];
    const float4 b = ((const float4*)x)[2 * i + 1];
    const float xs[8] = {a.x, a.y, a.z, a.w, b.x, b.y, b.z, b.w};
    u16 h[8], l[8];
#pragma unroll
    for (int j = 0; j < 8; ++j) {
      _Float16 hh = (_Float16)xs[j];
      _Float16 ll = (_Float16)(xs[j] - (float)hh);
      h[j] = *(u16*)&hh;
      l[j] = *(u16*)&ll;
    }
    uint4 hv;
    hv.x = h[0] | ((unsigned)h[1] << 16);
    hv.y = h[2] | ((unsigned)h[3] << 16);
    hv.z = h[4] | ((unsigned)h[5] << 16);
    hv.w = h[6] | ((unsigned)h[7] << 16);
    ((uint4*)hi)[i] = hv;
    uint4 lv;
    lv.x = l[0] | ((unsigned)l[1] << 16);
    lv.y = l[2] | ((unsigned)l[3] << 16);
    lv.z = l[4] | ((unsigned)l[5] << 16);
    lv.w = l[6] | ((unsigned)l[7] << 16);
    ((uint4*)lo)[i] = lv;
  }
}

// ---------------- MFMA GEMM: C[M,1024] = A @ W^T, split-bf16 limbs ------------
// OUTM bit0(1): fp32 C. bit2(4): f16 hi limb -> ChH. bit3(8): f16 lo -> ChL.
template <int NPROD, int OUTM>
__global__ __launch_bounds__(256) void mfma_gemm(
    const u16* __restrict__ Ahp, const u16* __restrict__ Alp,
    const u16* __restrict__ Bhp, const u16* __restrict__ Blp,
    float* __restrict__ C, u16* __restrict__ ChH, u16* __restrict__ ChL) {
  __shared__ u16 Ah_s[128 * 32];
  __shared__ u16 Bh_s[128 * 32];
  __shared__ u16 Al_s[128 * 32];
  __shared__ u16 Bl_s[128 * 32];
  const int t = threadIdx.x;
  const int wave = t >> 6;
  const int lane = t & 63;
  const int wr = wave >> 1;
  const int wc = wave & 1;
  const int n0 = blockIdx.x * 128;
  const int m0 = blockIdx.y * 128;

  const int sr0 = wave * 32 + (lane >> 2);
  const int sr1 = sr0 + 16;
  const int sw0 = ((sr0 ^ (sr0 >> 2)) & 3) ^ (lane & 3);
  const int sw1 = ((sr1 ^ (sr1 >> 2)) & 3) ^ (lane & 3);
  const size_t gA0 = (size_t)(m0 + sr0) * DIM_ + sw0 * 8;
  const size_t gA1 = (size_t)(m0 + sr1) * DIM_ + sw1 * 8;
  const size_t gB0 = (size_t)(n0 + sr0) * DIM_ + sw0 * 8;
  const size_t gB1 = (size_t)(n0 + sr1) * DIM_ + sw1 * 8;
  u16* const lA0 = &Ah_s[(wave * 32) * 32];
  u16* const lA1 = &Ah_s[(wave * 32 + 16) * 32];
  u16* const lB0 = &Bh_s[(wave * 32) * 32];
  u16* const lB1 = &Bh_s[(wave * 32 + 16) * 32];
  u16* const lAl0 = &Al_s[(wave * 32) * 32];
  u16* const lAl1 = &Al_s[(wave * 32 + 16) * 32];
  u16* const lBl0 = &Bl_s[(wave * 32) * 32];
  u16* const lBl1 = &Bl_s[(wave * 32 + 16) * 32];

  int aoff[4], boff[4];
#pragma unroll
  for (int m = 0; m < 4; ++m) {
    const int r = wr * 64 + m * 16 + (lane & 15);
    const int p = ((r ^ (r >> 2)) & 3) ^ (lane >> 4);
    aoff[m] = r * 32 + p * 8;
  }
#pragma unroll
  for (int n = 0; n < 4; ++n) {
    const int r = wc * 64 + n * 16 + (lane & 15);
    const int p = ((r ^ (r >> 2)) & 3) ^ (lane >> 4);
    boff[n] = r * 32 + p * 8;
  }

  f32x4 acc[4][4];
#pragma unroll
  for (int m = 0; m < 4; ++m)
#pragma unroll
    for (int n = 0; n < 4; ++n) acc[m][n] = (f32x4)(0.f);

  for (int k0 = 0; k0 < DIM_; k0 += 32) {
    gload16(Ahp + gA0 + k0, lA0);
    gload16(Ahp + gA1 + k0, lA1);
    gload16(Bhp + gB0 + k0, lB0);
    gload16(Bhp + gB1 + k0, lB1);
    if (NPROD == 3) {
      gload16(Alp + gA0 + k0, lAl0);
      gload16(Alp + gA1 + k0, lAl1);
      gload16(Blp + gB0 + k0, lBl0);
      gload16(Blp + gB1 + k0, lBl1);
    }
    __syncthreads();
    {
      bf16x8 af[4], bfr[4];
#pragma unroll
      for (int m = 0; m < 4; ++m) af[m] = *(const bf16x8*)&Ah_s[aoff[m]];
#pragma unroll
      for (int n = 0; n < 4; ++n) bfr[n] = *(const bf16x8*)&Bh_s[boff[n]];
#pragma unroll
      for (int m = 0; m < 4; ++m)
#pragma unroll
        for (int n = 0; n < 4; ++n)
          acc[m][n] = __builtin_amdgcn_mfma_f32_16x16x32_bf16(
              af[m], bfr[n], acc[m][n], 0, 0, 0);
      if (NPROD == 3) {
#pragma unroll
        for (int n = 0; n < 4; ++n) bfr[n] = *(const bf16x8*)&Bl_s[boff[n]];
#pragma unroll
        for (int m = 0; m < 4; ++m)
#pragma unroll
          for (int n = 0; n < 4; ++n)
            acc[m][n] = __builtin_amdgcn_mfma_f32_16x16x32_bf16(
                af[m], bfr[n], acc[m][n], 0, 0, 0);
#pragma unroll
        for (int m = 0; m < 4; ++m) af[m] = *(const bf16x8*)&Al_s[aoff[m]];
#pragma unroll
        for (int n = 0; n < 4; ++n) bfr[n] = *(const bf16x8*)&Bh_s[boff[n]];
#pragma unroll
        for (int m = 0; m < 4; ++m)
#pragma unroll
          for (int n = 0; n < 4; ++n)
            acc[m][n] = __builtin_amdgcn_mfma_f32_16x16x32_bf16(
                af[m], bfr[n], acc[m][n], 0, 0, 0);
      }
    }
    __syncthreads();
  }
#pragma unroll
  for (int m = 0; m < 4; ++m) {
    const int row = m0 + wr * 64 + m * 16 + (lane >> 4) * 4;
#pragma unroll
    for (int n = 0; n < 4; ++n) {
      const int col = n0 + wc * 64 + n * 16 + (lane & 15);
#pragma unroll
      for (int j = 0; j < 4; ++j) {
        const size_t idx = (size_t)(row + j) * DIM_ + col;
        const float a = acc[m][n][j];
        if (OUTM & 1) C[idx] = a;
        if (OUTM & 4) {
          _Float16 hi = (_Float16)a;
          ChH[idx] = *(u16*)&hi;
          if (OUTM & 8) {
            _Float16 lo = (_Float16)(a - (float)hi);
            ChL[idx] = *(u16*)&lo;
          }
        }
      }
    }
  }
}

// ---------------- fp32 GEMM (q-proj, Wo, and fallback) ------------------------
#define GM 128
#define GN 128
#define GK 16

__global__ __launch_bounds__(256) void gemm_nt(
    const float* __restrict__ A, const float* __restrict__ W,
    float* __restrict__ C, int M, const float* __restrict__ bias) {
  __shared__ float As[GK][GM + 4];
  __shared__ float Ws[GK][GN + 4];
  const int t = threadIdx.x;
  const int m0 = blockIdx.x * GM;
  const int n0 = blockIdx.y * GN;
  const int lrow = t >> 2;
  const int lq = (t & 3) * 4;
  const int tm = (t >> 4) * 8;
  const int tn = (t & 15) * 8;
  float acc[8][8];
#pragma unroll
  for (int i = 0; i < 8; ++i)
#pragma unroll
    for (int j = 0; j < 8; ++j) acc[i][j] = 0.f;

  for (int k0 = 0; k0 < DIM_; k0 += GK) {
#pragma unroll
    for (int half = 0; half < 2; ++half) {
      const int row = lrow + half * 64;
      const int gm = m0 + row;
      float4 av = make_float4(0.f, 0.f, 0.f, 0.f);
      if (gm < M) av = *(const float4*)&A[(size_t)gm * DIM_ + k0 + lq];
      As[lq + 0][row] = av.x; As[lq + 1][row] = av.y;
      As[lq + 2][row] = av.z; As[lq + 3][row] = av.w;
      const int gn = n0 + row;
      const float4 wv = *(const float4*)&W[(size_t)gn * DIM_ + k0 + lq];
      Ws[lq + 0][row] = wv.x; Ws[lq + 1][row] = wv.y;
      Ws[lq + 2][row] = wv.z; Ws[lq + 3][row] = wv.w;
    }
    __syncthreads();
#pragma unroll
    for (int kk = 0; kk < GK; ++kk) {
      float a[8], bb[8];
      *(float4*)&a[0] = *(const float4*)&As[kk][tm];
      *(float4*)&a[4] = *(const float4*)&As[kk][tm + 4];
      *(float4*)&bb[0] = *(const float4*)&Ws[kk][tn];
      *(float4*)&bb[4] = *(const float4*)&Ws[kk][tn + 4];
#pragma unroll
      for (int i = 0; i < 8; ++i)
#pragma unroll
        for (int j = 0; j < 8; ++j)
          acc[i][j] = fmaf(a[i], bb[j], acc[i][j]);
    }
    __syncthreads();
  }
#pragma unroll
  for (int i = 0; i < 8; ++i) {
    const int gm = m0 + tm + i;
    if (gm < M) {
#pragma unroll
      for (int j = 0; j < 8; j += 4) {
        const int gn = n0 + tn + j;
        float4 ov;
        ov.x = acc[i][j + 0]; ov.y = acc[i][j + 1];
        ov.z = acc[i][j + 2]; ov.w = acc[i][j + 3];
        if (bias) {
          ov.x += bias[gn + 0]; ov.y += bias[gn + 1];
          ov.z += bias[gn + 2]; ov.w += bias[gn + 3];
        }
        *(float4*)&C[(size_t)gm * DIM_ + gn] = ov;
      }
    }
  }
}

__device__ __forceinline__ unsigned fflip(float x) {
  const unsigned u = __float_as_uint(x);
  return (u & 0x80000000u) ? ~u : (u | 0x80000000u);
}

// ---------------- Pass A (MFMA, f16 limbs): max over (h,k) of (dots-lse) -----
// Grid B*H*8, 4 waves. Per block: all 256 q rows (Q A-frags in regs, both
// limbs), 512 k-cols in tiles of 64. 3 products hh+hl+lh -> ~2e-6 dots error.
#define AKT 64

__global__ __launch_bounds__(256) void pass_a_mfma(
    const u16* __restrict__ qhH, const u16* __restrict__ qhL,
    const u16* __restrict__ khH, const u16* __restrict__ khL,
    unsigned* __restrict__ sbuf) {
  __shared__ u16 KsH[AKT * 72];
  __shared__ u16 KsL[AKT * 72];
  __shared__ float red[4][2 * AKT];
  const int bx = blockIdx.x;
  const int b = bx >> 7;
  const int h = (bx >> 3) & 15;
  const int ks0 = (bx & 7) * (K_ / 8);
  const int t = threadIdx.x;
  const int w = t >> 6;
  const int l = t & 63;
  const int g = l >> 4;
  const int a15 = l & 15;

  // Q A-frags: q row = w*64 + mt*16 + a15, k-chunk = ks*32 + g*8
  f16x8 qA[2][4][2];
#pragma unroll
  for (int mt = 0; mt < 4; ++mt) {
    const int qrow = w * 64 + mt * 16 + a15;
    const size_t base = ((size_t)(b * Q_ + qrow)) * DIM_ + h * HD_;
#pragma unroll
    for (int ks = 0; ks < 2; ++ks) {
      qA[0][mt][ks] = *(const f16x8*)&qhH[base + ks * 32 + g * 8];
      qA[1][mt][ks] = *(const f16x8*)&qhL[base + ks * 32 + g * 8];
    }
  }
  float rmax[4][4];
#pragma unroll
  for (int mt = 0; mt < 4; ++mt)
#pragma unroll
    for (int j = 0; j < 4; ++j) rmax[mt][j] = -3.4e38f;

  for (int k0 = ks0; k0 < ks0 + K_ / 8; k0 += AKT) {
    // reg-stage K limbs (64 rows x 64 cols): 512 chunk-slots / 256 thr = 2 each
    uint4 sH[2], sL[2];
    int sr[2], sc[2];
#pragma unroll
    for (int s = 0; s < 2; ++s) {
      const int c = t + 256 * s;
      sr[s] = c >> 3;
      sc[s] = c & 7;
      const size_t gidx =
          ((size_t)(b * K_ + k0 + sr[s])) * DIM_ + h * HD_ + sc[s] * 8;
      sH[s] = *(const uint4*)&khH[gidx];
      sL[s] = *(const uint4*)&khL[gidx];
    }
    __syncthreads();  // prior iter's LDS reads (red + Ks) complete
#pragma unroll
    for (int s = 0; s < 2; ++s) {
      *(uint4*)&KsH[sr[s] * 72 + sc[s] * 8] = sH[s];
      *(uint4*)&KsL[sr[s] * 72 + sc[s] * 8] = sL[s];
    }
    __syncthreads();

    f32x4 acc[4][4];
#pragma unroll
    for (int mt = 0; mt < 4; ++mt)
#pragma unroll
      for (int kt = 0; kt < 4; ++kt) acc[mt][kt] = (f32x4)(0.f);
#pragma unroll
    for (int ks = 0; ks < 2; ++ks) {
#pragma unroll
      for (int kt = 0; kt < 4; ++kt) {
        const f16x8 bH =
            *(const f16x8*)&KsH[(kt * 16 + a15) * 72 + ks * 32 + g * 8];
        const f16x8 bL =
            *(const f16x8*)&KsL[(kt * 16 + a15) * 72 + ks * 32 + g * 8];
#pragma unroll
        for (int mt = 0; mt < 4; ++mt) {
          acc[mt][kt] = __builtin_amdgcn_mfma_f32_16x16x32_f16(
              qA[0][mt][ks], bH, acc[mt][kt], 0, 0, 0);
          acc[mt][kt] = __builtin_amdgcn_mfma_f32_16x16x32_f16(
              qA[0][mt][ks], bL, acc[mt][kt], 0, 0, 0);
          acc[mt][kt] = __builtin_amdgcn_mfma_f32_16x16x32_f16(
              qA[1][mt][ks], bH, acc[mt][kt], 0, 0, 0);
        }
      }
    }
    // scale by 1/8 (exact)
#pragma unroll
    for (int mt = 0; mt < 4; ++mt)
#pragma unroll
      for (int kt = 0; kt < 4; ++kt) acc[mt][kt] = acc[mt][kt] * 0.125f;

    // ---- column max over q (exclude global q==0) ----
    float cmax[4];
#pragma unroll
    for (int kt = 0; kt < 4; ++kt) {
      float m = -3.4e38f;
#pragma unroll
      for (int mt = 0; mt < 4; ++mt)
#pragma unroll
        for (int j = 0; j < 4; ++j) {
          const bool ex = (w == 0) & (mt == 0) & (g == 0) & (j == 0);
          if (!ex) m = fmaxf(m, acc[mt][kt][j]);
        }
      m = fmaxf(m, __shfl_xor(m, 16, 64));
      m = fmaxf(m, __shfl_xor(m, 32, 64));
      cmax[kt] = m;
    }
    if (l < 16) {
#pragma unroll
      for (int kt = 0; kt < 4; ++kt) red[w][kt * 16 + l] = cmax[kt];
    }
    __syncthreads();
#pragma unroll
    for (int kt = 0; kt < 4; ++kt)
      cmax[kt] = fmaxf(fmaxf(red[0][kt * 16 + a15], red[1][kt * 16 + a15]),
                       fmaxf(red[2][kt * 16 + a15], red[3][kt * 16 + a15]));
    // ---- column sum of exp ----
    float csum[4];
#pragma unroll
    for (int kt = 0; kt < 4; ++kt) {
      float s = 0.f;
#pragma unroll
      for (int mt = 0; mt < 4; ++mt)
#pragma unroll
        for (int j = 0; j < 4; ++j) {
          const bool ex = (w == 0) & (mt == 0) & (g == 0) & (j == 0);
          if (!ex) s += __expf(acc[mt][kt][j] - cmax[kt]);
        }
      s += __shfl_xor(s, 16, 64);
      s += __shfl_xor(s, 32, 64);
      csum[kt] = s;
    }
    if (l < 16) {
#pragma unroll
      for (int kt = 0; kt < 4; ++kt) red[w][AKT + kt * 16 + l] = csum[kt];
    }
    __syncthreads();
    float lse[4];
#pragma unroll
    for (int kt = 0; kt < 4; ++kt) {
      const float s = red[0][AKT + kt * 16 + a15] + red[1][AKT + kt * 16 + a15] +
                      red[2][AKT + kt * 16 + a15] + red[3][AKT + kt * 16 + a15];
      lse[kt] = cmax[kt] + logf(s);
    }
    // ---- per-q running max of (dots - lse) ----
#pragma unroll
    for (int mt = 0; mt < 4; ++mt)
#pragma unroll
      for (int j = 0; j < 4; ++j) {
        float v = -3.4e38f;
#pragma unroll
        for (int kt = 0; kt < 4; ++kt)
          v = fmaxf(v, acc[mt][kt][j] - lse[kt]);
        v = fmaxf(v, __shfl_xor(v, 1, 64));
        v = fmaxf(v, __shfl_xor(v, 2, 64));
        v = fmaxf(v, __shfl_xor(v, 4, 64));
        v = fmaxf(v, __shfl_xor(v, 8, 64));
        rmax[mt][j] = fmaxf(rmax[mt][j], v);
      }
  }
  if (a15 == 0) {
#pragma unroll
    for (int mt = 0; mt < 4; ++mt)
#pragma unroll
      for (int j = 0; j < 4; ++j) {
        const int qi = w * 64 + mt * 16 + g * 4 + j;
        if (qi > 0) atomicMax(&sbuf[b * Q_ + qi], fflip(rmax[mt][j]));
      }
  }
}

// ---------------- Pass A fallback (fp32 VALU) ---------------------------------
#define KT 64
#define DC 32
#define KSPLIT 8

__global__ __launch_bounds__(256) void pass_a(
    const float* __restrict__ qh, const float* __restrict__ kh,
    unsigned* __restrict__ sbuf) {
  __shared__ float qs[DC][Q_ + 4];
  __shared__ float ksm[DC][KT + 4];
  __shared__ float red[32][KT + 1];
  __shared__ float cmax[KT];
  __shared__ float clse[KT];
  const int blk = blockIdx.x;
  const int b = blk >> 7;
  const int h = (blk >> 3) & 15;
  const int ks0 = (blk & 7) * (K_ / KSPLIT);
  const int t = threadIdx.x;
  const int tq = t >> 3;
  const int tk = t & 7;
  float rmax[8];
#pragma unroll
  for (int i = 0; i < 8; ++i) rmax[i] = -3.4e38f;

  for (int k0 = ks0; k0 < ks0 + K_ / KSPLIT; k0 += KT) {
    float acc[8][8];
#pragma unroll
    for (int i = 0; i < 8; ++i)
#pragma unroll
      for (int j = 0; j < 8; ++j) acc[i][j] = 0.f;

    for (int dc = 0; dc < HD_; dc += DC) {
      {
        const float* src = &qh[((size_t)(b * Q_ + t)) * DIM_ + h * HD_ + dc];
#pragma unroll
        for (int u = 0; u < DC / 4; ++u) {
          const float4 vv = *(const float4*)&src[u * 4];
          qs[u * 4 + 0][t] = vv.x * SCALE_INV;
          qs[u * 4 + 1][t] = vv.y * SCALE_INV;
          qs[u * 4 + 2][t] = vv.z * SCALE_INV;
          qs[u * 4 + 3][t] = vv.w * SCALE_INV;
        }
      }
      {
        const int r = t >> 2;
        const int qd = (t & 3) * 8;
        const float* src =
            &kh[((size_t)(b * K_ + k0 + r)) * DIM_ + h * HD_ + dc + qd];
#pragma unroll
        for (int u = 0; u < 2; ++u) {
          const float4 vv = *(const float4*)&src[u * 4];
          ksm[qd + u * 4 + 0][r] = vv.x; ksm[qd + u * 4 + 1][r] = vv.y;
          ksm[qd + u * 4 + 2][r] = vv.z; ksm[qd + u * 4 + 3][r] = vv.w;
        }
      }
      __syncthreads();
#pragma unroll
      for (int d = 0; d < DC; ++d) {
        float a[8], bb[8];
        *(float4*)&a[0] = *(const float4*)&qs[d][tq * 8];
        *(float4*)&a[4] = *(const float4*)&qs[d][tq * 8 + 4];
        *(float4*)&bb[0] = *(const float4*)&ksm[d][tk * 8];
        *(float4*)&bb[4] = *(const float4*)&ksm[d][tk * 8 + 4];
#pragma unroll
        for (int i = 0; i < 8; ++i)
#pragma unroll
          for (int j = 0; j < 8; ++j)
            acc[i][j] = fmaf(a[i], bb[j], acc[i][j]);
      }
      __syncthreads();
    }
#pragma unroll
    for (int j = 0; j < 8; ++j) {
      float m = -3.4e38f;
#pragma unroll
      for (int i = 0; i < 8; ++i) {
        if (tq == 0 && i == 0) continue;
        m = fmaxf(m, acc[i][j]);
      }
      red[tq][tk * 8 + j] = m;
    }
    __syncthreads();
    if (t < KT) {
      float m = -3.4e38f;
      for (int g = 0; g < 32; ++g) m = fmaxf(m, red[g][t]);
      cmax[t] = m;
    }
    __syncthreads();
#pragma unroll
    for (int j = 0; j < 8; ++j) {
      const float m = cmax[tk * 8 + j];
      float s = 0.f;
#pragma unroll
      for (int i = 0; i < 8; ++i) {
        if (tq == 0 && i == 0) continue;
        s += __expf(acc[i][j] - m);
      }
      red[tq][tk * 8 + j] = s;
    }
    __syncthreads();
    if (t < KT) {
      float s = 0.f;
      for (int g = 0; g < 32; ++g) s += red[g][t];
      clse[t] = cmax[t] + logf(s);
    }
    __syncthreads();
#pragma unroll
    for (int i = 0; i < 8; ++i) {
      float v = -3.4e38f;
#pragma unroll
      for (int j = 0; j < 8; ++j) v = fmaxf(v, acc[i][j] - clse[tk * 8 + j]);
      v = fmaxf(v, __shfl_xor(v, 1, 64));
      v = fmaxf(v, __shfl_xor(v, 2, 64));
      v = fmaxf(v, __shfl_xor(v, 4, 64));
      rmax[i] = fmaxf(rmax[i], v);
    }
    __syncthreads();
  }
  if (tk == 0) {
#pragma unroll
    for (int i = 0; i < 8; ++i) {
      const int qi = tq * 8 + i;
      if (qi > 0) atomicMax(&sbuf[b * Q_ + qi], fflip(rmax[i]));
    }
  }
}

// ---------------- top-k (exact jax.lax.top_k semantics) ----------------------
__global__ void topk_kernel(const unsigned* __restrict__ sbuf,
                            int* __restrict__ keep, float* __restrict__ keepf) {
  const int b = blockIdx.x;
  const int lane = threadIdx.x;
  unsigned long long pk[4];
#pragma unroll
  for (int j = 0; j < 4; ++j) {
    const int q = 1 + lane + 64 * j;
    if (q <= 255) {
      const unsigned s = sbuf[b * Q_ + q];
      pk[j] = (((unsigned long long)s) << 32) | (unsigned)(256 - q);
    } else {
      pk[j] = 0ull;
    }
  }
  if (lane == 0) { keep[b * QP_] = 0; keepf[b * QP_] = 0.f; }
  for (int it = 0; it < MQ_; ++it) {
    unsigned long long best = pk[0];
#pragma unroll
    for (int j = 1; j < 4; ++j) best = (pk[j] > best) ? pk[j] : best;
    for (int m = 1; m < 64; m <<= 1) {
      const unsigned long long o = __shfl_xor(best, m, 64);
      best = (o > best) ? o : best;
    }
    const int q = 256 - (int)(best & 0xffffffffu);
#pragma unroll
    for (int j = 0; j < 4; ++j)
      if (pk[j] == best) pk[j] = 0ull;
    if (lane == 0) {
      keep[b * QP_ + 1 + it] = q;
      keepf[b * QP_ + 1 + it] = (float)q;
    }
  }
}

// ---------------- Pass B (MFMA, f16): competitive softmax + PV ----------------
#define PSPL 4

__global__ __launch_bounds__(256) void pass_b_mfma(
    const float* __restrict__ qh, const u16* __restrict__ khb,
    const u16* __restrict__ vhb, const int* __restrict__ keep,
    float* __restrict__ part) {
  __shared__ __align__(16) char SH[72960];
  u16* const Qs = (u16*)SH;                  // [80][72] f16
  u16* const Ks = (u16*)(SH + 11520);        // [128][72] f16
  u16* const Vs = (u16*)(SH + 29952);        // [128][68] f16
  u16* const Ps = (u16*)(SH + 47360);        // [4][80][40] f16 (per-wave)
  float* const osum = (float*)(SH + 11520);  // [4][80][17] f32 (aliases K/V)

  const int bx = blockIdx.x;
  const int b = bx >> 6;
  const int h = (bx >> 2) & 15;
  const int sp = bx & 3;
  const int t = threadIdx.x;
  const int w = t >> 6;
  const int l = t & 63;
  const int g = l >> 4;
  const int a15 = l & 15;

  for (int idx = t; idx < 80 * 8; idx += 256) {
    const int row = idx >> 3, ch = idx & 7;
    uint4 pk;
    if (row < QP_) {
      const int kq = keep[b * QP_ + row];
      const float* src = &qh[((size_t)(b * Q_ + kq)) * DIM_ + h * HD_ + ch * 8];
      const float4 x0 = *(const float4*)&src[0];
      const float4 x1 = *(const float4*)&src[4];
      pk.x = f2h_bits(x0.x * SCALE_INV) | ((unsigned)f2h_bits(x0.y * SCALE_INV) << 16);
      pk.y = f2h_bits(x0.z * SCALE_INV) | ((unsigned)f2h_bits(x0.w * SCALE_INV) << 16);
      pk.z = f2h_bits(x1.x * SCALE_INV) | ((unsigned)f2h_bits(x1.y * SCALE_INV) << 16);
      pk.w = f2h_bits(x1.z * SCALE_INV) | ((unsigned)f2h_bits(x1.w * SCALE_INV) << 16);
    } else {
      pk = make_uint4(0, 0, 0, 0);
    }
    *(uint4*)&Qs[row * 72 + ch * 8] = pk;
  }
  __syncthreads();

  f32x4 oacc[5][4];
#pragma unroll
  for (int mt = 0; mt < 5; ++mt)
#pragma unroll
    for (int dt = 0; dt < 4; ++dt) oacc[mt][dt] = (f32x4)(0.f);

  const int kt0 = sp * (K_ / PSPL);
  for (int kt = 0; kt < K_ / PSPL; kt += 128) {
    const int k0 = kt0 + kt;
    uint4 kreg[4], vreg[4];
    int srow[4], sch[4];
#pragma unroll
    for (int s = 0; s < 4; ++s) {
      const int c = t + 256 * s;
      srow[s] = c >> 3;
      sch[s] = c & 7;
      const size_t gidx =
          ((size_t)(b * K_ + k0 + srow[s])) * DIM_ + h * HD_ + sch[s] * 8;
      kreg[s] = *(const uint4*)&khb[gidx];
      vreg[s] = *(const uint4*)&vhb[gidx];
    }
    __syncthreads();
#pragma unroll
    for (int s = 0; s < 4; ++s) {
      *(uint4*)&Ks[srow[s] * 72 + sch[s] * 8] = kreg[s];
      uint2 v0; v0.x = vreg[s].x; v0.y = vreg[s].y;
      uint2 v1; v1.x = vreg[s].z; v1.y = vreg[s].w;
      *(uint2*)&Vs[srow[s] * 68 + sch[s] * 8] = v0;
      *(uint2*)&Vs[srow[s] * 68 + sch[s] * 8 + 4] = v1;
    }
    __syncthreads();

    f32x4 S[5][2];
#pragma unroll
    for (int mt = 0; mt < 5; ++mt)
#pragma unroll
      for (int nt = 0; nt < 2; ++nt) S[mt][nt] = (f32x4)(0.f);
#pragma unroll
    for (int kk = 0; kk < 2; ++kk) {
      f16x8 aq[5];
#pragma unroll
      for (int mt = 0; mt < 5; ++mt)
        aq[mt] = *(const f16x8*)&Qs[(mt * 16 + a15) * 72 + kk * 32 + g * 8];
#pragma unroll
      for (int nt = 0; nt < 2; ++nt) {
        const f16x8 bk =
            *(const f16x8*)&Ks[(w * 32 + nt * 16 + a15) * 72 + kk * 32 + g * 8];
#pragma unroll
        for (int mt = 0; mt < 5; ++mt)
          S[mt][nt] = __builtin_amdgcn_mfma_f32_16x16x32_f16(aq[mt], bk,
                                                             S[mt][nt], 0, 0, 0);
      }
    }
#pragma unroll
    for (int nt = 0; nt < 2; ++nt) {
      float m = -3.4e38f;
#pragma unroll
      for (int mt = 0; mt < 5; ++mt)
#pragma unroll
        for (int j = 0; j < 4; ++j) {
          const bool valid = (mt < 4) | ((g == 0) & (j == 0));
          if (valid) m = fmaxf(m, S[mt][nt][j]);
        }
      m = fmaxf(m, __shfl_xor(m, 16, 64));
      m = fmaxf(m, __shfl_xor(m, 32, 64));
      float s = 0.f;
#pragma unroll
      for (int mt = 0; mt < 5; ++mt)
#pragma unroll
        for (int j = 0; j < 4; ++j) {
          const bool valid = (mt < 4) | ((g == 0) & (j == 0));
          const float p = valid ? __expf(S[mt][nt][j] - m) : 0.f;
          S[mt][nt][j] = p;
          s += p;
        }
      s += __shfl_xor(s, 16, 64);
      s += __shfl_xor(s, 32, 64);
      const float r = 1.f / s;
#pragma unroll
      for (int mt = 0; mt < 5; ++mt)
#pragma unroll
        for (int j = 0; j < 4; ++j)
          Ps[w * 3200 + (mt * 16 + g * 4 + j) * 40 + nt * 16 + a15] =
              f2h_bits(S[mt][nt][j] * r);
    }
    f16x8 ap[5];
#pragma unroll
    for (int mt = 0; mt < 5; ++mt)
      ap[mt] = *(const f16x8*)&Ps[w * 3200 + (mt * 16 + a15) * 40 + g * 8];
#pragma unroll
    for (int dt = 0; dt < 4; ++dt) {
      s16x8 bv;
#pragma unroll
      for (int e = 0; e < 8; ++e)
        bv[e] = (short)Vs[(w * 32 + g * 8 + e) * 68 + dt * 16 + a15];
#pragma unroll
      for (int mt = 0; mt < 5; ++mt)
        oacc[mt][dt] = __builtin_amdgcn_mfma_f32_16x16x32_f16(
            ap[mt], as_f16x8(bv), oacc[mt][dt], 0, 0, 0);
    }
  }

#pragma unroll
  for (int dt = 0; dt < 4; ++dt) {
    __syncthreads();
#pragma unroll
    for (int mt = 0; mt < 5; ++mt)
#pragma unroll
      for (int j = 0; j < 4; ++j)
        osum[w * 1360 + (mt * 16 + g * 4 + j) * 17 + a15] = oacc[mt][dt][j];
    __syncthreads();
    for (int idx = t; idx < QP_ * 16; idx += 256) {
      const int q = idx >> 4, c = idx & 15;
      const float sm = osum[q * 17 + c] + osum[1360 + q * 17 + c] +
                       osum[2720 + q * 17 + c] + osum[4080 + q * 17 + c];
      part[(((size_t)sp * B_ + b) * QP_ + q) * DIM_ + h * 64 + dt * 16 + c] = sm;
    }
  }
}

// ---------------- Pass B fallback (fp32 VALU) ---------------------------------
__global__ __launch_bounds__(256) void pass_b(
    const float* __restrict__ qh, const float* __restrict__ kh,
    const float* __restrict__ vh, const int* __restrict__ keep,
    float* __restrict__ part) {
  __shared__ float qs[QP_][HD_ + 4];
  __shared__ float kv[KT][HD_ + 4];
  __shared__ float att[QP_][KT + 4];
  __shared__ float cmax[KT];
  __shared__ float crcp[KT];
  const int bx = blockIdx.x;
  const int b = bx >> 6;
  const int h = (bx >> 2) & 15;
  const int sp = bx & 3;
  const int t = threadIdx.x;

  if (t < QP_) {
    const int kq = keep[b * QP_ + t];
    const float* src = &qh[((size_t)(b * Q_ + kq)) * DIM_ + h * HD_];
#pragma unroll
    for (int u = 0; u < HD_ / 4; ++u) {
      float4 vv = *(const float4*)&src[u * 4];
      vv.x *= SCALE_INV; vv.y *= SCALE_INV;
      vv.z *= SCALE_INV; vv.w *= SCALE_INV;
      *(float4*)&qs[t][u * 4] = vv;
    }
  }
  const int c = t & 63;
  const int jg = t >> 6;
  const int j0 = jg * 17;
  const int j1 = (jg == 3) ? QP_ : (j0 + 17);
  const int j2 = t >> 2;
  const int cg = (t & 3) * 16;
  const int r = t >> 2;
  const int qd = (t & 3) * 16;
  float oacc[16], oacc2[16];
#pragma unroll
  for (int u = 0; u < 16; ++u) { oacc[u] = 0.f; oacc2[u] = 0.f; }

  __syncthreads();

  const int kbeg = sp * (K_ / PSPL);
  const int kend = kbeg + K_ / PSPL;
  for (int k0 = kbeg; k0 < kend; k0 += KT) {
    {
      const float* src = &kh[((size_t)(b * K_ + k0 + r)) * DIM_ + h * HD_ + qd];
#pragma unroll
      for (int u = 0; u < 4; ++u)
        *(float4*)&kv[r][qd + u * 4] = *(const float4*)&src[u * 4];
    }
    __syncthreads();
    {
      float4 kr[16];
#pragma unroll
      for (int u = 0; u < 16; ++u) kr[u] = *(const float4*)&kv[c][u * 4];
      for (int j = j0; j < j1; ++j) {
        float4 s4 = make_float4(0.f, 0.f, 0.f, 0.f);
#pragma unroll
        for (int u = 0; u < 16; ++u) {
          const float4 qv = *(const float4*)&qs[j][u * 4];
          s4.x = fmaf(qv.x, kr[u].x, s4.x);
          s4.y = fmaf(qv.y, kr[u].y, s4.y);
          s4.z = fmaf(qv.z, kr[u].z, s4.z);
          s4.w = fmaf(qv.w, kr[u].w, s4.w);
        }
        att[j][c] = (s4.x + s4.y) + (s4.z + s4.w);
      }
    }
    __syncthreads();
    {
      const float* src = &vh[((size_t)(b * K_ + k0 + r)) * DIM_ + h * HD_ + qd];
#pragma unroll
      for (int u = 0; u < 4; ++u)
        *(float4*)&kv[r][qd + u * 4] = *(const float4*)&src[u * 4];
      if (t < KT) {
        float m = att[0][t];
        for (int j = 1; j < QP_; ++j) m = fmaxf(m, att[j][t]);
        float s = 0.f;
        for (int j = 0; j < QP_; ++j) s += __expf(att[j][t] - m);
        cmax[t] = m;
        crcp[t] = 1.f / s;
      }
    }
    __syncthreads();
    for (int e = t; e < QP_ * KT; e += 256) {
      const int jj = e >> 6;
      const int cc = e & 63;
      att[jj][cc] = __expf(att[jj][cc] - cmax[cc]) * crcp[cc];
    }
    __syncthreads();
    {
      for (int ck = 0; ck < KT; ++ck) {
        const float a = att[j2][ck];
#pragma unroll
        for (int u = 0; u < 4; ++u) {
          const float4 vv = *(const float4*)&kv[ck][cg + u * 4];
          oacc[u * 4 + 0] = fmaf(a, vv.x, oacc[u * 4 + 0]);
          oacc[u * 4 + 1] = fmaf(a, vv.y, oacc[u * 4 + 1]);
          oacc[u * 4 + 2] = fmaf(a, vv.z, oacc[u * 4 + 2]);
          oacc[u * 4 + 3] = fmaf(a, vv.w, oacc[u * 4 + 3]);
        }
      }
      if (t < 4) {
        const int cg2 = t * 16;
        for (int ck = 0; ck < KT; ++ck) {
          const float a = att[64][ck];
#pragma unroll
          for (int u = 0; u < 4; ++u) {
            const float4 vv = *(const float4*)&kv[ck][cg2 + u * 4];
            oacc2[u * 4 + 0] = fmaf(a, vv.x, oacc2[u * 4 + 0]);
            oacc2[u * 4 + 1] = fmaf(a, vv.y, oacc2[u * 4 + 1]);
            oacc2[u * 4 + 2] = fmaf(a, vv.z, oacc2[u * 4 + 2]);
            oacc2[u * 4 + 3] = fmaf(a, vv.w, oacc2[u * 4 + 3]);
          }
        }
      }
    }
    __syncthreads();
  }
  {
    float* dst =
        &part[(((size_t)sp * B_ + b) * QP_ + j2) * DIM_ + h * HD_ + cg];
    *(float4*)&dst[0] = make_float4(oacc[0], oacc[1], oacc[2], oacc[3]);
    *(float4*)&dst[4] = make_float4(oacc[4], oacc[5], oacc[6], oacc[7]);
    *(float4*)&dst[8] = make_float4(oacc[8], oacc[9], oacc[10], oacc[11]);
    *(float4*)&dst[12] = make_float4(oacc[12], oacc[13], oacc[14], oacc[15]);
    if (t < 4) {
      float* dst2 =
          &part[(((size_t)sp * B_ + b) * QP_ + 64) * DIM_ + h * HD_ + t * 16];
      *(float4*)&dst2[0] = make_float4(oacc2[0], oacc2[1], oacc2[2], oacc2[3]);
      *(float4*)&dst2[4] = make_float4(oacc2[4], oacc2[5], oacc2[6], oacc2[7]);
      *(float4*)&dst2[8] = make_float4(oacc2[8], oacc2[9], oacc2[10], oacc2[11]);
      *(float4*)&dst2[12] = make_float4(oacc2[12], oacc2[13], oacc2[14], oacc2[15]);
    }
  }
}

// ---------------- reduce partial O over splits --------------------------------
__global__ __launch_bounds__(256) void reduce_part(
    const float* __restrict__ part, float* __restrict__ opre) {
  const long n4 = (long)B_ * QP_ * DIM_ / 4;
  const long i = (long)blockIdx.x * 256 + threadIdx.x;
  if (i >= n4) return;
  float4 s = ((const float4*)part)[i];
#pragma unroll
  for (int sp = 1; sp < PSPL; ++sp) {
    const float4 p = ((const float4*)part)[(long)sp * n4 + i];
    s.x += p.x; s.y += p.y; s.z += p.z; s.w += p.w;
  }
  ((float4*)opre)[i] = s;
}

extern "C" void kernel_launch(void* const* d_in, const int* in_sizes, int n_in,
                              void* d_out, int out_size, void* d_ws, size_t ws_size,
                              hipStream_t stream) {
  const float* q  = (const float*)d_in[0];
  const float* k  = (const float*)d_in[1];
  const float* v  = (const float*)d_in[2];
  const float* Wq = (const float*)d_in[3];
  const float* Wk = (const float*)d_in[4];
  const float* Wv = (const float*)d_in[5];
  const float* Wo = (const float*)d_in[6];
  const float* bo = (const float*)d_in[7];
  float* out = (float*)d_out;

  char* base = (char*)d_ws;
  size_t off = 0;
  auto alloc = [&](size_t bytes) {
    char* p = base + off;
    off = (off + bytes + 255) & ~(size_t)255;
    return (void*)p;
  };
  // common
  float* qh   = (float*)alloc((size_t)B_ * Q_ * DIM_ * 4);
  float* opre = (float*)alloc((size_t)B_ * QP_ * DIM_ * 4);
  unsigned* sbuf = (unsigned*)alloc((size_t)B_ * Q_ * 4);
  int* keep   = (int*)alloc((size_t)B_ * QP_ * 4);
  const size_t common_off = off;
  // big path
  u16* qhH = (u16*)alloc((size_t)B_ * Q_ * DIM_ * 2);
  u16* qhL = (u16*)alloc((size_t)B_ * Q_ * DIM_ * 2);
  u16* khH = (u16*)alloc((size_t)B_ * K_ * DIM_ * 2);
  u16* khL = (u16*)alloc((size_t)B_ * K_ * DIM_ * 2);
  u16* vhH = (u16*)alloc((size_t)B_ * K_ * DIM_ * 2);
  u16* kHi = (u16*)alloc((size_t)B_ * K_ * DIM_ * 2);
  u16* kLo = (u16*)alloc((size_t)B_ * K_ * DIM_ * 2);
  u16* wHi = (u16*)alloc((size_t)DIM_ * DIM_ * 2);
  u16* wLo = (u16*)alloc((size_t)DIM_ * DIM_ * 2);
  const bool big = (off <= ws_size);
  float* keepf = out + (size_t)B_ * QP_ * DIM_;
  const dim3 blk(256);

  hipMemsetAsync(sbuf, 0, B_ * Q_ * sizeof(unsigned), stream);

  if (big) {
    float* part = (float*)kHi;  // kHi dead after the V projection
    const long nKV8 = (long)B_ * K_ * DIM_ / 8;
    const long nW8 = (long)DIM_ * DIM_ / 8;
    const long nQ8 = (long)B_ * Q_ * DIM_ / 8;
    split_bf16<<<2048, blk, 0, stream>>>(k, kHi, kLo, nKV8, 1);
    split_bf16<<<512, blk, 0, stream>>>(Wk, wHi, wLo, nW8, 1);
    mfma_gemm<3, 12><<<dim3(DIM_ / 128, B_ * K_ / 128), blk, 0, stream>>>(
        kHi, kLo, wHi, wLo, nullptr, khH, khL);
    split_bf16<<<2048, blk, 0, stream>>>(v, kHi, nullptr, nKV8, 0);
    split_bf16<<<512, blk, 0, stream>>>(Wv, wHi, nullptr, nW8, 0);
    mfma_gemm<1, 4><<<dim3(DIM_ / 128, B_ * K_ / 128), blk, 0, stream>>>(
        kHi, nullptr, wHi, nullptr, nullptr, vhH, nullptr);
    gemm_nt<<<dim3(B_ * Q_ / GM, DIM_ / GN), blk, 0, stream>>>(
        q, Wq, qh, B_ * Q_, nullptr);
    split_f16<<<512, blk, 0, stream>>>(qh, qhH, qhL, nQ8);
    pass_a_mfma<<<dim3(B_ * H_ * 8), blk, 0, stream>>>(qhH, qhL, khH, khL, sbuf);
    topk_kernel<<<dim3(B_), dim3(64), 0, stream>>>(sbuf, keep, keepf);
    pass_b_mfma<<<dim3(B_ * H_ * PSPL), blk, 0, stream>>>(qh, khH, vhH, keep, part);
    reduce_part<<<dim3((B_ * QP_ * DIM_ / 4 + 255) / 256), blk, 0, stream>>>(part, opre);
    gemm_nt<<<dim3((B_ * QP_ + GM - 1) / GM, DIM_ / GN), blk, 0, stream>>>(
        opre, Wo, out, B_ * QP_, bo);
  } else {
    // fp32 fallback (small workspace)
    off = common_off;
    float* kh = (float*)alloc((size_t)B_ * K_ * DIM_ * 4);
    float* vh = (float*)alloc((size_t)B_ * K_ * DIM_ * 4);
    float* part = (float*)alloc((size_t)PSPL * B_ * QP_ * DIM_ * 4);
    gemm_nt<<<dim3(B_ * K_ / GM, DIM_ / GN), blk, 0, stream>>>(k, Wk, kh, B_ * K_, nullptr);
    gemm_nt<<<dim3(B_ * K_ / GM, DIM_ / GN), blk, 0, stream>>>(v, Wv, vh, B_ * K_, nullptr);
    gemm_nt<<<dim3(B_ * Q_ / GM, DIM_ / GN), blk, 0, stream>>>(q, Wq, qh, B_ * Q_, nullptr);
    pass_a<<<dim3(B_ * H_ * KSPLIT), blk, 0, stream>>>(qh, kh, sbuf);
    topk_kernel<<<dim3(B_), dim3(64), 0, stream>>>(sbuf, keep, keepf);
    pass_b<<<dim3(B_ * H_ * PSPL), blk, 0, stream>>>(qh, kh, vh, keep, part);
    reduce_part<<<dim3((B_ * QP_ * DIM_ / 4 + 255) / 256), blk, 0, stream>>>(part, opre);
    gemm_nt<<<dim3((B_ * QP_ + GM - 1) / GM, DIM_ / GN), blk, 0, stream>>>(
        opre, Wo, out, B_ * QP_, bo);
  }
}

// Round 8
// 1501.281 us; speedup vs baseline: 3.6636x; 1.0068x over previous
//
#include <hip/hip_runtime.h>
#include <hip/hip_bf16.h>
#include <math.h>

#define B_ 16
#define Q_ 256
#define K_ 4096
#define DIM_ 1024
#define H_ 16
#define HD_ 64
#define MQ_ 64
#define QP_ 65
#define SCALE_INV 0.125f

typedef unsigned short u16;
typedef __attribute__((ext_vector_type(8))) short bf16x8;
typedef __attribute__((ext_vector_type(8))) _Float16 f16x8;
typedef __attribute__((ext_vector_type(8))) short s16x8;
typedef __attribute__((ext_vector_type(4))) float f32x4;

// ---------------- helpers -----------------------------------------------------
__device__ __forceinline__ u16 f2bf_rne(float f) {
  unsigned u = __float_as_uint(f);
  u += 0x7fffu + ((u >> 16) & 1u);
  return (u16)(u >> 16);
}
__device__ __forceinline__ float bf2f(u16 h) {
  return __uint_as_float(((unsigned)h) << 16);
}
__device__ __forceinline__ u16 f2h_bits(float f) {
  _Float16 h = (_Float16)f;
  return *(u16*)&h;
}
__device__ __forceinline__ f16x8 as_f16x8(s16x8 v) {
  return __builtin_bit_cast(f16x8, v);
}
__device__ __forceinline__ void gload16(const void* g, void* l) {
  __builtin_amdgcn_global_load_lds(
      (const __attribute__((address_space(1))) unsigned int*)g,
      (__attribute__((address_space(3))) unsigned int*)l, 16, 0, 0);
}

// ---------------- split fp32 -> bf16 hi/lo (for GEMM inputs) ------------------
__global__ __launch_bounds__(256) void split_bf16(
    const float* __restrict__ x, u16* __restrict__ hi, u16* __restrict__ lo,
    long n8, int wlo) {
  long i = (long)blockIdx.x * 256 + threadIdx.x;
  const long stride = (long)gridDim.x * 256;
  for (; i < n8; i += stride) {
    const float4 a = ((const float4*)x)[2 * i];
    const float4 b = ((const float4*)x)[2 * i + 1];
    const float xs[8] = {a.x, a.y, a.z, a.w, b.x, b.y, b.z, b.w};
    u16 h[8], l[8];
#pragma unroll
    for (int j = 0; j < 8; ++j) {
      h[j] = f2bf_rne(xs[j]);
      l[j] = f2bf_rne(xs[j] - bf2f(h[j]));
    }
    uint4 hv;
    hv.x = h[0] | ((unsigned)h[1] << 16);
    hv.y = h[2] | ((unsigned)h[3] << 16);
    hv.z = h[4] | ((unsigned)h[5] << 16);
    hv.w = h[6] | ((unsigned)h[7] << 16);
    ((uint4*)hi)[i] = hv;
    if (wlo) {
      uint4 lv;
      lv.x = l[0] | ((unsigned)l[1] << 16);
      lv.y = l[2] | ((unsigned)l[3] << 16);
      lv.z = l[4] | ((unsigned)l[5] << 16);
      lv.w = l[6] | ((unsigned)l[7] << 16);
      ((uint4*)lo)[i] = lv;
    }
  }
}

// ---------------- split fp32 -> f16 hi/lo (for pass_a QK) ---------------------
__global__ __launch_bounds__(256) void split_f16(
    const float* __restrict__ x, u16* __restrict__ hi, u16* __restrict__ lo,
    long n8) {
  long i = (long)blockIdx.x * 256 + threadIdx.x;
  const long stride = (long)gridDim.x * 256;
  for (; i < n8; i += stride) {
    const float4 a = ((const float4*)x)[2 * i];
    const float4 b = ((const float4*)x)[2 * i + 1];
    const float xs[8] = {a.x, a.y, a.z, a.w, b.x, b.y, b.z, b.w};
    u16 h[8], l[8];
#pragma unroll
    for (int j = 0; j < 8; ++j) {
      _Float16 hh = (_Float16)xs[j];
      _Float16 ll = (_Float16)(xs[j] - (float)hh);
      h[j] = *(u16*)&hh;
      l[j] = *(u16*)&ll;
    }
    uint4 hv;
    hv.x = h[0] | ((unsigned)h[1] << 16);
    hv.y = h[2] | ((unsigned)h[3] << 16);
    hv.z = h[4] | ((unsigned)h[5] << 16);
    hv.w = h[6] | ((unsigned)h[7] << 16);
    ((uint4*)hi)[i] = hv;
    uint4 lv;
    lv.x = l[0] | ((unsigned)l[1] << 16);
    lv.y = l[2] | ((unsigned)l[3] << 16);
    lv.z = l[4] | ((unsigned)l[5] << 16);
    lv.w = l[6] | ((unsigned)l[7] << 16);
    ((uint4*)lo)[i] = lv;
  }
}

// ---------------- MFMA GEMM: C[M,1024] = A @ W^T, split-bf16 limbs ------------
// NPROD: 1 = hh; 3 = hh+hl+lh.
// OUTM bit0(1): fp32 C. bit2(4): f16 hi limb -> ChH. bit3(8): f16 lo -> ChL.
template <int NPROD, int OUTM>
__global__ __launch_bounds__(256) void mfma_gemm(
    const u16* __restrict__ Ahp, const u16* __restrict__ Alp,
    const u16* __restrict__ Bhp, const u16* __restrict__ Blp,
    float* __restrict__ C, u16* __restrict__ ChH, u16* __restrict__ ChL) {
  __shared__ u16 Ah_s[128 * 32];
  __shared__ u16 Bh_s[128 * 32];
  __shared__ u16 Al_s[NPROD >= 3 ? 128 * 32 : 16];
  __shared__ u16 Bl_s[NPROD >= 3 ? 128 * 32 : 16];
  const int t = threadIdx.x;
  const int wave = t >> 6;
  const int lane = t & 63;
  const int wr = wave >> 1;
  const int wc = wave & 1;

  // XCD-affinity swizzle (correctness-neutral, bijective when gridDim.x==8 &&
  // gridDim.y%8==0): all 8 n-tiles of one m-tile land on one XCD consecutively,
  // so each A row-panel is fetched into exactly one per-XCD L2.
  int bx = blockIdx.x, by = blockIdx.y;
  if (gridDim.x == 8 && (gridDim.y & 7) == 0) {
    const int flat = by * 8 + bx;
    const int c = flat & 7;
    const int j = flat >> 3;
    by = (j >> 3) * 8 + c;  // m tile
    bx = j & 7;             // n tile
  }
  const int n0 = bx * 128;
  const int m0 = by * 128;

  const int sr0 = wave * 32 + (lane >> 2);
  const int sr1 = sr0 + 16;
  const int sw0 = ((sr0 ^ (sr0 >> 2)) & 3) ^ (lane & 3);
  const int sw1 = ((sr1 ^ (sr1 >> 2)) & 3) ^ (lane & 3);
  const size_t gA0 = (size_t)(m0 + sr0) * DIM_ + sw0 * 8;
  const size_t gA1 = (size_t)(m0 + sr1) * DIM_ + sw1 * 8;
  const size_t gB0 = (size_t)(n0 + sr0) * DIM_ + sw0 * 8;
  const size_t gB1 = (size_t)(n0 + sr1) * DIM_ + sw1 * 8;
  u16* const lA0 = &Ah_s[(wave * 32) * 32];
  u16* const lA1 = &Ah_s[(wave * 32 + 16) * 32];
  u16* const lB0 = &Bh_s[(wave * 32) * 32];
  u16* const lB1 = &Bh_s[(wave * 32 + 16) * 32];
  u16* const lAl0 = &Al_s[(wave * 32) * 32];
  u16* const lAl1 = &Al_s[(wave * 32 + 16) * 32];
  u16* const lBl0 = &Bl_s[(wave * 32) * 32];
  u16* const lBl1 = &Bl_s[(wave * 32 + 16) * 32];

  int aoff[4], boff[4];
#pragma unroll
  for (int m = 0; m < 4; ++m) {
    const int r = wr * 64 + m * 16 + (lane & 15);
    const int p = ((r ^ (r >> 2)) & 3) ^ (lane >> 4);
    aoff[m] = r * 32 + p * 8;
  }
#pragma unroll
  for (int n = 0; n < 4; ++n) {
    const int r = wc * 64 + n * 16 + (lane & 15);
    const int p = ((r ^ (r >> 2)) & 3) ^ (lane >> 4);
    boff[n] = r * 32 + p * 8;
  }

  f32x4 acc[4][4];
#pragma unroll
  for (int m = 0; m < 4; ++m)
#pragma unroll
    for (int n = 0; n < 4; ++n) acc[m][n] = (f32x4)(0.f);

  for (int k0 = 0; k0 < DIM_; k0 += 32) {
    gload16(Ahp + gA0 + k0, lA0);
    gload16(Ahp + gA1 + k0, lA1);
    gload16(Bhp + gB0 + k0, lB0);
    gload16(Bhp + gB1 + k0, lB1);
    if (NPROD >= 3) {
      gload16(Alp + gA0 + k0, lAl0);
      gload16(Alp + gA1 + k0, lAl1);
      gload16(Blp + gB0 + k0, lBl0);
      gload16(Blp + gB1 + k0, lBl1);
    }
    __syncthreads();
    {
      bf16x8 af[4], bfr[4];
#pragma unroll
      for (int m = 0; m < 4; ++m) af[m] = *(const bf16x8*)&Ah_s[aoff[m]];
#pragma unroll
      for (int n = 0; n < 4; ++n) bfr[n] = *(const bf16x8*)&Bh_s[boff[n]];
#pragma unroll
      for (int m = 0; m < 4; ++m)
#pragma unroll
        for (int n = 0; n < 4; ++n)
          acc[m][n] = __builtin_amdgcn_mfma_f32_16x16x32_bf16(
              af[m], bfr[n], acc[m][n], 0, 0, 0);
      if (NPROD >= 3) {
        // hi * lo (af still Ah)
#pragma unroll
        for (int n = 0; n < 4; ++n) bfr[n] = *(const bf16x8*)&Bl_s[boff[n]];
#pragma unroll
        for (int m = 0; m < 4; ++m)
#pragma unroll
          for (int n = 0; n < 4; ++n)
            acc[m][n] = __builtin_amdgcn_mfma_f32_16x16x32_bf16(
                af[m], bfr[n], acc[m][n], 0, 0, 0);
        // lo * hi
#pragma unroll
        for (int m = 0; m < 4; ++m) af[m] = *(const bf16x8*)&Al_s[aoff[m]];
#pragma unroll
        for (int n = 0; n < 4; ++n) bfr[n] = *(const bf16x8*)&Bh_s[boff[n]];
#pragma unroll
        for (int m = 0; m < 4; ++m)
#pragma unroll
          for (int n = 0; n < 4; ++n)
            acc[m][n] = __builtin_amdgcn_mfma_f32_16x16x32_bf16(
                af[m], bfr[n], acc[m][n], 0, 0, 0);
      }
    }
    __syncthreads();
  }
#pragma unroll
  for (int m = 0; m < 4; ++m) {
    const int row = m0 + wr * 64 + m * 16 + (lane >> 4) * 4;
#pragma unroll
    for (int n = 0; n < 4; ++n) {
      const int col = n0 + wc * 64 + n * 16 + (lane & 15);
#pragma unroll
      for (int j = 0; j < 4; ++j) {
        const size_t idx = (size_t)(row + j) * DIM_ + col;
        const float a = acc[m][n][j];
        if (OUTM & 1) C[idx] = a;
        if (OUTM & 4) {
          _Float16 hi = (_Float16)a;
          ChH[idx] = *(u16*)&hi;
          if (OUTM & 8) {
            _Float16 lo = (_Float16)(a - (float)hi);
            ChL[idx] = *(u16*)&lo;
          }
        }
      }
    }
  }
}

// ---------------- fp32 GEMM (Q-proj, Wo, fallback) ----------------------------
#define GM 128
#define GN 128
#define GK 16

__global__ __launch_bounds__(256) void gemm_nt(
    const float* __restrict__ A, const float* __restrict__ W,
    float* __restrict__ C, int M, const float* __restrict__ bias) {
  __shared__ float As[GK][GM + 4];
  __shared__ float Ws[GK][GN + 4];
  const int t = threadIdx.x;
  const int m0 = blockIdx.x * GM;
  const int n0 = blockIdx.y * GN;
  const int lrow = t >> 2;
  const int lq = (t & 3) * 4;
  const int tm = (t >> 4) * 8;
  const int tn = (t & 15) * 8;
  float acc[8][8];
#pragma unroll
  for (int i = 0; i < 8; ++i)
#pragma unroll
    for (int j = 0; j < 8; ++j) acc[i][j] = 0.f;

  for (int k0 = 0; k0 < DIM_; k0 += GK) {
#pragma unroll
    for (int half = 0; half < 2; ++half) {
      const int row = lrow + half * 64;
      const int gm = m0 + row;
      float4 av = make_float4(0.f, 0.f, 0.f, 0.f);
      if (gm < M) av = *(const float4*)&A[(size_t)gm * DIM_ + k0 + lq];
      As[lq + 0][row] = av.x; As[lq + 1][row] = av.y;
      As[lq + 2][row] = av.z; As[lq + 3][row] = av.w;
      const int gn = n0 + row;
      const float4 wv = *(const float4*)&W[(size_t)gn * DIM_ + k0 + lq];
      Ws[lq + 0][row] = wv.x; Ws[lq + 1][row] = wv.y;
      Ws[lq + 2][row] = wv.z; Ws[lq + 3][row] = wv.w;
    }
    __syncthreads();
#pragma unroll
    for (int kk = 0; kk < GK; ++kk) {
      float a[8], bb[8];
      *(float4*)&a[0] = *(const float4*)&As[kk][tm];
      *(float4*)&a[4] = *(const float4*)&As[kk][tm + 4];
      *(float4*)&bb[0] = *(const float4*)&Ws[kk][tn];
      *(float4*)&bb[4] = *(const float4*)&Ws[kk][tn + 4];
#pragma unroll
      for (int i = 0; i < 8; ++i)
#pragma unroll
        for (int j = 0; j < 8; ++j)
          acc[i][j] = fmaf(a[i], bb[j], acc[i][j]);
    }
    __syncthreads();
  }
#pragma unroll
  for (int i = 0; i < 8; ++i) {
    const int gm = m0 + tm + i;
    if (gm < M) {
#pragma unroll
      for (int j = 0; j < 8; j += 4) {
        const int gn = n0 + tn + j;
        float4 ov;
        ov.x = acc[i][j + 0]; ov.y = acc[i][j + 1];
        ov.z = acc[i][j + 2]; ov.w = acc[i][j + 3];
        if (bias) {
          ov.x += bias[gn + 0]; ov.y += bias[gn + 1];
          ov.z += bias[gn + 2]; ov.w += bias[gn + 3];
        }
        *(float4*)&C[(size_t)gm * DIM_ + gn] = ov;
      }
    }
  }
}

__device__ __forceinline__ unsigned fflip(float x) {
  const unsigned u = __float_as_uint(x);
  return (u & 0x80000000u) ? ~u : (u | 0x80000000u);
}

// ---------------- Pass A (MFMA, f16 limbs): max over (h,k) of (dots-lse) -----
#define AKT 64

__global__ __launch_bounds__(256) void pass_a_mfma(
    const u16* __restrict__ qhH, const u16* __restrict__ qhL,
    const u16* __restrict__ khH, const u16* __restrict__ khL,
    unsigned* __restrict__ sbuf) {
  __shared__ u16 KsH[AKT * 72];
  __shared__ u16 KsL[AKT * 72];
  __shared__ float red[4][2 * AKT];
  const int bx = blockIdx.x;
  const int b = bx >> 7;
  const int h = (bx >> 3) & 15;
  const int ks0 = (bx & 7) * (K_ / 8);
  const int t = threadIdx.x;
  const int w = t >> 6;
  const int l = t & 63;
  const int g = l >> 4;
  const int a15 = l & 15;

  f16x8 qA[2][4][2];
#pragma unroll
  for (int mt = 0; mt < 4; ++mt) {
    const int qrow = w * 64 + mt * 16 + a15;
    const size_t base = ((size_t)(b * Q_ + qrow)) * DIM_ + h * HD_;
#pragma unroll
    for (int ks = 0; ks < 2; ++ks) {
      qA[0][mt][ks] = *(const f16x8*)&qhH[base + ks * 32 + g * 8];
      qA[1][mt][ks] = *(const f16x8*)&qhL[base + ks * 32 + g * 8];
    }
  }
  float rmax[4][4];
#pragma unroll
  for (int mt = 0; mt < 4; ++mt)
#pragma unroll
    for (int j = 0; j < 4; ++j) rmax[mt][j] = -3.4e38f;

  for (int k0 = ks0; k0 < ks0 + K_ / 8; k0 += AKT) {
    uint4 sH[2], sL[2];
    int sr[2], sc[2];
#pragma unroll
    for (int s = 0; s < 2; ++s) {
      const int c = t + 256 * s;
      sr[s] = c >> 3;
      sc[s] = c & 7;
      const size_t gidx =
          ((size_t)(b * K_ + k0 + sr[s])) * DIM_ + h * HD_ + sc[s] * 8;
      sH[s] = *(const uint4*)&khH[gidx];
      sL[s] = *(const uint4*)&khL[gidx];
    }
    __syncthreads();
#pragma unroll
    for (int s = 0; s < 2; ++s) {
      *(uint4*)&KsH[sr[s] * 72 + sc[s] * 8] = sH[s];
      *(uint4*)&KsL[sr[s] * 72 + sc[s] * 8] = sL[s];
    }
    __syncthreads();

    f32x4 acc[4][4];
#pragma unroll
    for (int mt = 0; mt < 4; ++mt)
#pragma unroll
      for (int kt = 0; kt < 4; ++kt) acc[mt][kt] = (f32x4)(0.f);
#pragma unroll
    for (int ks = 0; ks < 2; ++ks) {
#pragma unroll
      for (int kt = 0; kt < 4; ++kt) {
        const f16x8 bH =
            *(const f16x8*)&KsH[(kt * 16 + a15) * 72 + ks * 32 + g * 8];
        const f16x8 bL =
            *(const f16x8*)&KsL[(kt * 16 + a15) * 72 + ks * 32 + g * 8];
#pragma unroll
        for (int mt = 0; mt < 4; ++mt) {
          acc[mt][kt] = __builtin_amdgcn_mfma_f32_16x16x32_f16(
              qA[0][mt][ks], bH, acc[mt][kt], 0, 0, 0);
          acc[mt][kt] = __builtin_amdgcn_mfma_f32_16x16x32_f16(
              qA[0][mt][ks], bL, acc[mt][kt], 0, 0, 0);
          acc[mt][kt] = __builtin_amdgcn_mfma_f32_16x16x32_f16(
              qA[1][mt][ks], bH, acc[mt][kt], 0, 0, 0);
        }
      }
    }
#pragma unroll
    for (int mt = 0; mt < 4; ++mt)
#pragma unroll
      for (int kt = 0; kt < 4; ++kt) acc[mt][kt] = acc[mt][kt] * 0.125f;

    float cmax[4];
#pragma unroll
    for (int kt = 0; kt < 4; ++kt) {
      float m = -3.4e38f;
#pragma unroll
      for (int mt = 0; mt < 4; ++mt)
#pragma unroll
        for (int j = 0; j < 4; ++j) {
          const bool ex = (w == 0) & (mt == 0) & (g == 0) & (j == 0);
          if (!ex) m = fmaxf(m, acc[mt][kt][j]);
        }
      m = fmaxf(m, __shfl_xor(m, 16, 64));
      m = fmaxf(m, __shfl_xor(m, 32, 64));
      cmax[kt] = m;
    }
    if (l < 16) {
#pragma unroll
      for (int kt = 0; kt < 4; ++kt) red[w][kt * 16 + l] = cmax[kt];
    }
    __syncthreads();
#pragma unroll
    for (int kt = 0; kt < 4; ++kt)
      cmax[kt] = fmaxf(fmaxf(red[0][kt * 16 + a15], red[1][kt * 16 + a15]),
                       fmaxf(red[2][kt * 16 + a15], red[3][kt * 16 + a15]));
    float csum[4];
#pragma unroll
    for (int kt = 0; kt < 4; ++kt) {
      float s = 0.f;
#pragma unroll
      for (int mt = 0; mt < 4; ++mt)
#pragma unroll
        for (int j = 0; j < 4; ++j) {
          const bool ex = (w == 0) & (mt == 0) & (g == 0) & (j == 0);
          if (!ex) s += __expf(acc[mt][kt][j] - cmax[kt]);
        }
      s += __shfl_xor(s, 16, 64);
      s += __shfl_xor(s, 32, 64);
      csum[kt] = s;
    }
    if (l < 16) {
#pragma unroll
      for (int kt = 0; kt < 4; ++kt) red[w][AKT + kt * 16 + l] = csum[kt];
    }
    __syncthreads();
    float lse[4];
#pragma unroll
    for (int kt = 0; kt < 4; ++kt) {
      const float s = red[0][AKT + kt * 16 + a15] + red[1][AKT + kt * 16 + a15] +
                      red[2][AKT + kt * 16 + a15] + red[3][AKT + kt * 16 + a15];
      lse[kt] = cmax[kt] + logf(s);
    }
#pragma unroll
    for (int mt = 0; mt < 4; ++mt)
#pragma unroll
      for (int j = 0; j < 4; ++j) {
        float v = -3.4e38f;
#pragma unroll
        for (int kt = 0; kt < 4; ++kt)
          v = fmaxf(v, acc[mt][kt][j] - lse[kt]);
        v = fmaxf(v, __shfl_xor(v, 1, 64));
        v = fmaxf(v, __shfl_xor(v, 2, 64));
        v = fmaxf(v, __shfl_xor(v, 4, 64));
        v = fmaxf(v, __shfl_xor(v, 8, 64));
        rmax[mt][j] = fmaxf(rmax[mt][j], v);
      }
  }
  if (a15 == 0) {
#pragma unroll
    for (int mt = 0; mt < 4; ++mt)
#pragma unroll
      for (int j = 0; j < 4; ++j) {
        const int qi = w * 64 + mt * 16 + g * 4 + j;
        if (qi > 0) atomicMax(&sbuf[b * Q_ + qi], fflip(rmax[mt][j]));
      }
  }
}

// ---------------- Pass A fallback (fp32 VALU) ---------------------------------
#define KT 64
#define DC 32
#define KSPLIT 8

__global__ __launch_bounds__(256) void pass_a(
    const float* __restrict__ qh, const float* __restrict__ kh,
    unsigned* __restrict__ sbuf) {
  __shared__ float qs[DC][Q_ + 4];
  __shared__ float ksm[DC][KT + 4];
  __shared__ float red[32][KT + 1];
  __shared__ float cmax[KT];
  __shared__ float clse[KT];
  const int blk = blockIdx.x;
  const int b = blk >> 7;
  const int h = (blk >> 3) & 15;
  const int ks0 = (blk & 7) * (K_ / KSPLIT);
  const int t = threadIdx.x;
  const int tq = t >> 3;
  const int tk = t & 7;
  float rmax[8];
#pragma unroll
  for (int i = 0; i < 8; ++i) rmax[i] = -3.4e38f;

  for (int k0 = ks0; k0 < ks0 + K_ / KSPLIT; k0 += KT) {
    float acc[8][8];
#pragma unroll
    for (int i = 0; i < 8; ++i)
#pragma unroll
      for (int j = 0; j < 8; ++j) acc[i][j] = 0.f;

    for (int dc = 0; dc < HD_; dc += DC) {
      {
        const float* src = &qh[((size_t)(b * Q_ + t)) * DIM_ + h * HD_ + dc];
#pragma unroll
        for (int u = 0; u < DC / 4; ++u) {
          const float4 vv = *(const float4*)&src[u * 4];
          qs[u * 4 + 0][t] = vv.x * SCALE_INV;
          qs[u * 4 + 1][t] = vv.y * SCALE_INV;
          qs[u * 4 + 2][t] = vv.z * SCALE_INV;
          qs[u * 4 + 3][t] = vv.w * SCALE_INV;
        }
      }
      {
        const int r = t >> 2;
        const int qd = (t & 3) * 8;
        const float* src =
            &kh[((size_t)(b * K_ + k0 + r)) * DIM_ + h * HD_ + dc + qd];
#pragma unroll
        for (int u = 0; u < 2; ++u) {
          const float4 vv = *(const float4*)&src[u * 4];
          ksm[qd + u * 4 + 0][r] = vv.x; ksm[qd + u * 4 + 1][r] = vv.y;
          ksm[qd + u * 4 + 2][r] = vv.z; ksm[qd + u * 4 + 3][r] = vv.w;
        }
      }
      __syncthreads();
#pragma unroll
      for (int d = 0; d < DC; ++d) {
        float a[8], bb[8];
        *(float4*)&a[0] = *(const float4*)&qs[d][tq * 8];
        *(float4*)&a[4] = *(const float4*)&qs[d][tq * 8 + 4];
        *(float4*)&bb[0] = *(const float4*)&ksm[d][tk * 8];
        *(float4*)&bb[4] = *(const float4*)&ksm[d][tk * 8 + 4];
#pragma unroll
        for (int i = 0; i < 8; ++i)
#pragma unroll
          for (int j = 0; j < 8; ++j)
            acc[i][j] = fmaf(a[i], bb[j], acc[i][j]);
      }
      __syncthreads();
    }
#pragma unroll
    for (int j = 0; j < 8; ++j) {
      float m = -3.4e38f;
#pragma unroll
      for (int i = 0; i < 8; ++i) {
        if (tq == 0 && i == 0) continue;
        m = fmaxf(m, acc[i][j]);
      }
      red[tq][tk * 8 + j] = m;
    }
    __syncthreads();
    if (t < KT) {
      float m = -3.4e38f;
      for (int g = 0; g < 32; ++g) m = fmaxf(m, red[g][t]);
      cmax[t] = m;
    }
    __syncthreads();
#pragma unroll
    for (int j = 0; j < 8; ++j) {
      const float m = cmax[tk * 8 + j];
      float s = 0.f;
#pragma unroll
      for (int i = 0; i < 8; ++i) {
        if (tq == 0 && i == 0) continue;
        s += __expf(acc[i][j] - m);
      }
      red[tq][tk * 8 + j] = s;
    }
    __syncthreads();
    if (t < KT) {
      float s = 0.f;
      for (int g = 0; g < 32; ++g) s += red[g][t];
      clse[t] = cmax[t] + logf(s);
    }
    __syncthreads();
#pragma unroll
    for (int i = 0; i < 8; ++i) {
      float v = -3.4e38f;
#pragma unroll
      for (int j = 0; j < 8; ++j) v = fmaxf(v, acc[i][j] - clse[tk * 8 + j]);
      v = fmaxf(v, __shfl_xor(v, 1, 64));
      v = fmaxf(v, __shfl_xor(v, 2, 64));
      v = fmaxf(v, __shfl_xor(v, 4, 64));
      rmax[i] = fmaxf(rmax[i], v);
    }
    __syncthreads();
  }
  if (tk == 0) {
#pragma unroll
    for (int i = 0; i < 8; ++i) {
      const int qi = tq * 8 + i;
      if (qi > 0) atomicMax(&sbuf[b * Q_ + qi], fflip(rmax[i]));
    }
  }
}

// ---------------- top-k (exact jax.lax.top_k semantics) ----------------------
__global__ void topk_kernel(const unsigned* __restrict__ sbuf,
                            int* __restrict__ keep, float* __restrict__ keepf) {
  const int b = blockIdx.x;
  const int lane = threadIdx.x;
  unsigned long long pk[4];
#pragma unroll
  for (int j = 0; j < 4; ++j) {
    const int q = 1 + lane + 64 * j;
    if (q <= 255) {
      const unsigned s = sbuf[b * Q_ + q];
      pk[j] = (((unsigned long long)s) << 32) | (unsigned)(256 - q);
    } else {
      pk[j] = 0ull;
    }
  }
  if (lane == 0) { keep[b * QP_] = 0; keepf[b * QP_] = 0.f; }
  for (int it = 0; it < MQ_; ++it) {
    unsigned long long best = pk[0];
#pragma unroll
    for (int j = 1; j < 4; ++j) best = (pk[j] > best) ? pk[j] : best;
    for (int m = 1; m < 64; m <<= 1) {
      const unsigned long long o = __shfl_xor(best, m, 64);
      best = (o > best) ? o : best;
    }
    const int q = 256 - (int)(best & 0xffffffffu);
#pragma unroll
    for (int j = 0; j < 4; ++j)
      if (pk[j] == best) pk[j] = 0ull;
    if (lane == 0) {
      keep[b * QP_ + 1 + it] = q;
      keepf[b * QP_ + 1 + it] = (float)q;
    }
  }
}

// ---------------- Pass B (MFMA, f16): competitive softmax + PV ----------------
#define PSPL 4

__global__ __launch_bounds__(256) void pass_b_mfma(
    const float* __restrict__ qh, const u16* __restrict__ khb,
    const u16* __restrict__ vhb, const int* __restrict__ keep,
    float* __restrict__ part) {
  __shared__ __align__(16) char SH[72960];
  u16* const Qs = (u16*)SH;                  // [80][72] f16
  u16* const Ks = (u16*)(SH + 11520);        // [128][72] f16
  u16* const Vs = (u16*)(SH + 29952);        // [128][68] f16
  u16* const Ps = (u16*)(SH + 47360);        // [4][80][40] f16 (per-wave)
  float* const osum = (float*)(SH + 11520);  // [4][80][17] f32 (aliases K/V)

  const int bx = blockIdx.x;
  const int b = bx >> 6;
  const int h = (bx >> 2) & 15;
  const int sp = bx & 3;
  const int t = threadIdx.x;
  const int w = t >> 6;
  const int l = t & 63;
  const int g = l >> 4;
  const int a15 = l & 15;

  for (int idx = t; idx < 80 * 8; idx += 256) {
    const int row = idx >> 3, ch = idx & 7;
    uint4 pk;
    if (row < QP_) {
      const int kq = keep[b * QP_ + row];
      const float* src = &qh[((size_t)(b * Q_ + kq)) * DIM_ + h * HD_ + ch * 8];
      const float4 x0 = *(const float4*)&src[0];
      const float4 x1 = *(const float4*)&src[4];
      pk.x = f2h_bits(x0.x * SCALE_INV) | ((unsigned)f2h_bits(x0.y * SCALE_INV) << 16);
      pk.y = f2h_bits(x0.z * SCALE_INV) | ((unsigned)f2h_bits(x0.w * SCALE_INV) << 16);
      pk.z = f2h_bits(x1.x * SCALE_INV) | ((unsigned)f2h_bits(x1.y * SCALE_INV) << 16);
      pk.w = f2h_bits(x1.z * SCALE_INV) | ((unsigned)f2h_bits(x1.w * SCALE_INV) << 16);
    } else {
      pk = make_uint4(0, 0, 0, 0);
    }
    *(uint4*)&Qs[row * 72 + ch * 8] = pk;
  }
  __syncthreads();

  f32x4 oacc[5][4];
#pragma unroll
  for (int mt = 0; mt < 5; ++mt)
#pragma unroll
    for (int dt = 0; dt < 4; ++dt) oacc[mt][dt] = (f32x4)(0.f);

  const int kt0 = sp * (K_ / PSPL);
  for (int kt = 0; kt < K_ / PSPL; kt += 128) {
    const int k0 = kt0 + kt;
    uint4 kreg[4], vreg[4];
    int srow[4], sch[4];
#pragma unroll
    for (int s = 0; s < 4; ++s) {
      const int c = t + 256 * s;
      srow[s] = c >> 3;
      sch[s] = c & 7;
      const size_t gidx =
          ((size_t)(b * K_ + k0 + srow[s])) * DIM_ + h * HD_ + sch[s] * 8;
      kreg[s] = *(const uint4*)&khb[gidx];
      vreg[s] = *(const uint4*)&vhb[gidx];
    }
    __syncthreads();
#pragma unroll
    for (int s = 0; s < 4; ++s) {
      *(uint4*)&Ks[srow[s] * 72 + sch[s] * 8] = kreg[s];
      uint2 v0; v0.x = vreg[s].x; v0.y = vreg[s].y;
      uint2 v1; v1.x = vreg[s].z; v1.y = vreg[s].w;
      *(uint2*)&Vs[srow[s] * 68 + sch[s] * 8] = v0;
      *(uint2*)&Vs[srow[s] * 68 + sch[s] * 8 + 4] = v1;
    }
    __syncthreads();

    f32x4 S[5][2];
#pragma unroll
    for (int mt = 0; mt < 5; ++mt)
#pragma unroll
      for (int nt = 0; nt < 2; ++nt) S[mt][nt] = (f32x4)(0.f);
#pragma unroll
    for (int kk = 0; kk < 2; ++kk) {
      f16x8 aq[5];
#pragma unroll
      for (int mt = 0; mt < 5; ++mt)
        aq[mt] = *(const f16x8*)&Qs[(mt * 16 + a15) * 72 + kk * 32 + g * 8];
#pragma unroll
      for (int nt = 0; nt < 2; ++nt) {
        const f16x8 bk =
            *(const f16x8*)&Ks[(w * 32 + nt * 16 + a15) * 72 + kk * 32 + g * 8];
#pragma unroll
        for (int mt = 0; mt < 5; ++mt)
          S[mt][nt] = __builtin_amdgcn_mfma_f32_16x16x32_f16(aq[mt], bk,
                                                             S[mt][nt], 0, 0, 0);
      }
    }
#pragma unroll
    for (int nt = 0; nt < 2; ++nt) {
      float m = -3.4e38f;
#pragma unroll
      for (int mt = 0; mt < 5; ++mt)
#pragma unroll
        for (int j = 0; j < 4; ++j) {
          const bool valid = (mt < 4) | ((g == 0) & (j == 0));
          if (valid) m = fmaxf(m, S[mt][nt][j]);
        }
      m = fmaxf(m, __shfl_xor(m, 16, 64));
      m = fmaxf(m, __shfl_xor(m, 32, 64));
      float s = 0.f;
#pragma unroll
      for (int mt = 0; mt < 5; ++mt)
#pragma unroll
        for (int j = 0; j < 4; ++j) {
          const bool valid = (mt < 4) | ((g == 0) & (j == 0));
          const float p = valid ? __expf(S[mt][nt][j] - m) : 0.f;
          S[mt][nt][j] = p;
          s += p;
        }
      s += __shfl_xor(s, 16, 64);
      s += __shfl_xor(s, 32, 64);
      const float r = 1.f / s;
#pragma unroll
      for (int mt = 0; mt < 5; ++mt)
#pragma unroll
        for (int j = 0; j < 4; ++j)
          Ps[w * 3200 + (mt * 16 + g * 4 + j) * 40 + nt * 16 + a15] =
              f2h_bits(S[mt][nt][j] * r);
    }
    f16x8 ap[5];
#pragma unroll
    for (int mt = 0; mt < 5; ++mt)
      ap[mt] = *(const f16x8*)&Ps[w * 3200 + (mt * 16 + a15) * 40 + g * 8];
#pragma unroll
    for (int dt = 0; dt < 4; ++dt) {
      s16x8 bv;
#pragma unroll
      for (int e = 0; e < 8; ++e)
        bv[e] = (short)Vs[(w * 32 + g * 8 + e) * 68 + dt * 16 + a15];
#pragma unroll
      for (int mt = 0; mt < 5; ++mt)
        oacc[mt][dt] = __builtin_amdgcn_mfma_f32_16x16x32_f16(
            ap[mt], as_f16x8(bv), oacc[mt][dt], 0, 0, 0);
    }
  }

#pragma unroll
  for (int dt = 0; dt < 4; ++dt) {
    __syncthreads();
#pragma unroll
    for (int mt = 0; mt < 5; ++mt)
#pragma unroll
      for (int j = 0; j < 4; ++j)
        osum[w * 1360 + (mt * 16 + g * 4 + j) * 17 + a15] = oacc[mt][dt][j];
    __syncthreads();
    for (int idx = t; idx < QP_ * 16; idx += 256) {
      const int q = idx >> 4, c = idx & 15;
      const float sm = osum[q * 17 + c] + osum[1360 + q * 17 + c] +
                       osum[2720 + q * 17 + c] + osum[4080 + q * 17 + c];
      part[(((size_t)sp * B_ + b) * QP_ + q) * DIM_ + h * 64 + dt * 16 + c] = sm;
    }
  }
}

// ---------------- Pass B fallback (fp32 VALU) ---------------------------------
__global__ __launch_bounds__(256) void pass_b(
    const float* __restrict__ qh, const float* __restrict__ kh,
    const float* __restrict__ vh, const int* __restrict__ keep,
    float* __restrict__ part) {
  __shared__ float qs[QP_][HD_ + 4];
  __shared__ float kv[KT][HD_ + 4];
  __shared__ float att[QP_][KT + 4];
  __shared__ float cmax[KT];
  __shared__ float crcp[KT];
  const int bx = blockIdx.x;
  const int b = bx >> 6;
  const int h = (bx >> 2) & 15;
  const int sp = bx & 3;
  const int t = threadIdx.x;

  if (t < QP_) {
    const int kq = keep[b * QP_ + t];
    const float* src = &qh[((size_t)(b * Q_ + kq)) * DIM_ + h * HD_];
#pragma unroll
    for (int u = 0; u < HD_ / 4; ++u) {
      float4 vv = *(const float4*)&src[u * 4];
      vv.x *= SCALE_INV; vv.y *= SCALE_INV;
      vv.z *= SCALE_INV; vv.w *= SCALE_INV;
      *(float4*)&qs[t][u * 4] = vv;
    }
  }
  const int c = t & 63;
  const int jg = t >> 6;
  const int j0 = jg * 17;
  const int j1 = (jg == 3) ? QP_ : (j0 + 17);
  const int j2 = t >> 2;
  const int cg = (t & 3) * 16;
  const int r = t >> 2;
  const int qd = (t & 3) * 16;
  float oacc[16], oacc2[16];
#pragma unroll
  for (int u = 0; u < 16; ++u) { oacc[u] = 0.f; oacc2[u] = 0.f; }

  __syncthreads();

  const int kbeg = sp * (K_ / PSPL);
  const int kend = kbeg + K_ / PSPL;
  for (int k0 = kbeg; k0 < kend; k0 += KT) {
    {
      const float* src = &kh[((size_t)(b * K_ + k0 + r)) * DIM_ + h * HD_ + qd];
#pragma unroll
      for (int u = 0; u < 4; ++u)
        *(float4*)&kv[r][qd + u * 4] = *(const float4*)&src[u * 4];
    }
    __syncthreads();
    {
      float4 kr[16];
#pragma unroll
      for (int u = 0; u < 16; ++u) kr[u] = *(const float4*)&kv[c][u * 4];
      for (int j = j0; j < j1; ++j) {
        float4 s4 = make_float4(0.f, 0.f, 0.f, 0.f);
#pragma unroll
        for (int u = 0; u < 16; ++u) {
          const float4 qv = *(const float4*)&qs[j][u * 4];
          s4.x = fmaf(qv.x, kr[u].x, s4.x);
          s4.y = fmaf(qv.y, kr[u].y, s4.y);
          s4.z = fmaf(qv.z, kr[u].z, s4.z);
          s4.w = fmaf(qv.w, kr[u].w, s4.w);
        }
        att[j][c] = (s4.x + s4.y) + (s4.z + s4.w);
      }
    }
    __syncthreads();
    {
      const float* src = &vh[((size_t)(b * K_ + k0 + r)) * DIM_ + h * HD_ + qd];
#pragma unroll
      for (int u = 0; u < 4; ++u)
        *(float4*)&kv[r][qd + u * 4] = *(const float4*)&src[u * 4];
      if (t < KT) {
        float m = att[0][t];
        for (int j = 1; j < QP_; ++j) m = fmaxf(m, att[j][t]);
        float s = 0.f;
        for (int j = 0; j < QP_; ++j) s += __expf(att[j][t] - m);
        cmax[t] = m;
        crcp[t] = 1.f / s;
      }
    }
    __syncthreads();
    for (int e = t; e < QP_ * KT; e += 256) {
      const int jj = e >> 6;
      const int cc = e & 63;
      att[jj][cc] = __expf(att[jj][cc] - cmax[cc]) * crcp[cc];
    }
    __syncthreads();
    {
      for (int ck = 0; ck < KT; ++ck) {
        const float a = att[j2][ck];
#pragma unroll
        for (int u = 0; u < 4; ++u) {
          const float4 vv = *(const float4*)&kv[ck][cg + u * 4];
          oacc[u * 4 + 0] = fmaf(a, vv.x, oacc[u * 4 + 0]);
          oacc[u * 4 + 1] = fmaf(a, vv.y, oacc[u * 4 + 1]);
          oacc[u * 4 + 2] = fmaf(a, vv.z, oacc[u * 4 + 2]);
          oacc[u * 4 + 3] = fmaf(a, vv.w, oacc[u * 4 + 3]);
        }
      }
      if (t < 4) {
        const int cg2 = t * 16;
        for (int ck = 0; ck < KT; ++ck) {
          const float a = att[64][ck];
#pragma unroll
          for (int u = 0; u < 4; ++u) {
            const float4 vv = *(const float4*)&kv[ck][cg2 + u * 4];
            oacc2[u * 4 + 0] = fmaf(a, vv.x, oacc2[u * 4 + 0]);
            oacc2[u * 4 + 1] = fmaf(a, vv.y, oacc2[u * 4 + 1]);
            oacc2[u * 4 + 2] = fmaf(a, vv.z, oacc2[u * 4 + 2]);
            oacc2[u * 4 + 3] = fmaf(a, vv.w, oacc2[u * 4 + 3]);
          }
        }
      }
    }
    __syncthreads();
  }
  {
    float* dst =
        &part[(((size_t)sp * B_ + b) * QP_ + j2) * DIM_ + h * HD_ + cg];
    *(float4*)&dst[0] = make_float4(oacc[0], oacc[1], oacc[2], oacc[3]);
    *(float4*)&dst[4] = make_float4(oacc[4], oacc[5], oacc[6], oacc[7]);
    *(float4*)&dst[8] = make_float4(oacc[8], oacc[9], oacc[10], oacc[11]);
    *(float4*)&dst[12] = make_float4(oacc[12], oacc[13], oacc[14], oacc[15]);
    if (t < 4) {
      float* dst2 =
          &part[(((size_t)sp * B_ + b) * QP_ + 64) * DIM_ + h * HD_ + t * 16];
      *(float4*)&dst2[0] = make_float4(oacc2[0], oacc2[1], oacc2[2], oacc2[3]);
      *(float4*)&dst2[4] = make_float4(oacc2[4], oacc2[5], oacc2[6], oacc2[7]);
      *(float4*)&dst2[8] = make_float4(oacc2[8], oacc2[9], oacc2[10], oacc2[11]);
      *(float4*)&dst2[12] = make_float4(oacc2[12], oacc2[13], oacc2[14], oacc2[15]);
    }
  }
}

// ---------------- reduce partial O over splits --------------------------------
__global__ __launch_bounds__(256) void reduce_part(
    const float* __restrict__ part, float* __restrict__ opre) {
  const long n4 = (long)B_ * QP_ * DIM_ / 4;
  const long i = (long)blockIdx.x * 256 + threadIdx.x;
  if (i >= n4) return;
  float4 s = ((const float4*)part)[i];
#pragma unroll
  for (int sp = 1; sp < PSPL; ++sp) {
    const float4 p = ((const float4*)part)[(long)sp * n4 + i];
    s.x += p.x; s.y += p.y; s.z += p.z; s.w += p.w;
  }
  ((float4*)opre)[i] = s;
}

extern "C" void kernel_launch(void* const* d_in, const int* in_sizes, int n_in,
                              void* d_out, int out_size, void* d_ws, size_t ws_size,
                              hipStream_t stream) {
  const float* q  = (const float*)d_in[0];
  const float* k  = (const float*)d_in[1];
  const float* v  = (const float*)d_in[2];
  const float* Wq = (const float*)d_in[3];
  const float* Wk = (const float*)d_in[4];
  const float* Wv = (const float*)d_in[5];
  const float* Wo = (const float*)d_in[6];
  const float* bo = (const float*)d_in[7];
  float* out = (float*)d_out;

  char* base = (char*)d_ws;
  size_t off = 0;
  auto alloc = [&](size_t bytes) {
    char* p = base + off;
    off = (off + bytes + 255) & ~(size_t)255;
    return (void*)p;
  };
  // common
  float* qh   = (float*)alloc((size_t)B_ * Q_ * DIM_ * 4);
  float* opre = (float*)alloc((size_t)B_ * QP_ * DIM_ * 4);
  unsigned* sbuf = (unsigned*)alloc((size_t)B_ * Q_ * 4);
  int* keep   = (int*)alloc((size_t)B_ * QP_ * 4);
  const size_t common_off = off;
  // big path
  u16* qhH = (u16*)alloc((size_t)B_ * Q_ * DIM_ * 2);
  u16* qhL = (u16*)alloc((size_t)B_ * Q_ * DIM_ * 2);
  u16* khH = (u16*)alloc((size_t)B_ * K_ * DIM_ * 2);
  u16* khL = (u16*)alloc((size_t)B_ * K_ * DIM_ * 2);
  u16* vhH = (u16*)alloc((size_t)B_ * K_ * DIM_ * 2);
  u16* kHi = (u16*)alloc((size_t)B_ * K_ * DIM_ * 2);
  u16* kLo = (u16*)alloc((size_t)B_ * K_ * DIM_ * 2);
  u16* wHi = (u16*)alloc((size_t)DIM_ * DIM_ * 2);
  u16* wLo = (u16*)alloc((size_t)DIM_ * DIM_ * 2);
  const bool big = (off <= ws_size);
  float* keepf = out + (size_t)B_ * QP_ * DIM_;
  const dim3 blk(256);

  hipMemsetAsync(sbuf, 0, B_ * Q_ * sizeof(unsigned), stream);

  if (big) {
    float* part = (float*)kHi;  // kHi dead after the V projection
    const long nKV8 = (long)B_ * K_ * DIM_ / 8;
    const long nW8 = (long)DIM_ * DIM_ / 8;
    const long nQ8 = (long)B_ * Q_ * DIM_ / 8;
    // K projection (3-limb, f16 hi/lo out)
    split_bf16<<<2048, blk, 0, stream>>>(k, kHi, kLo, nKV8, 1);
    split_bf16<<<512, blk, 0, stream>>>(Wk, wHi, wLo, nW8, 1);
    mfma_gemm<3, 12><<<dim3(DIM_ / 128, B_ * K_ / 128), blk, 0, stream>>>(
        kHi, kLo, wHi, wLo, nullptr, khH, khL);
    // V projection (1-limb, f16 hi out)
    split_bf16<<<2048, blk, 0, stream>>>(v, kHi, nullptr, nKV8, 0);
    split_bf16<<<512, blk, 0, stream>>>(Wv, wHi, nullptr, nW8, 0);
    mfma_gemm<1, 4><<<dim3(DIM_ / 128, B_ * K_ / 128), blk, 0, stream>>>(
        kHi, nullptr, wHi, nullptr, nullptr, vhH, nullptr);
    // Q projection: exact fp32 (selection margin depends on it — round-7 lesson)
    gemm_nt<<<dim3(B_ * Q_ / GM, DIM_ / GN), blk, 0, stream>>>(
        q, Wq, qh, B_ * Q_, nullptr);
    split_f16<<<512, blk, 0, stream>>>(qh, qhH, qhL, nQ8);
    pass_a_mfma<<<dim3(B_ * H_ * 8), blk, 0, stream>>>(qhH, qhL, khH, khL, sbuf);
    topk_kernel<<<dim3(B_), dim3(64), 0, stream>>>(sbuf, keep, keepf);
    pass_b_mfma<<<dim3(B_ * H_ * PSPL), blk, 0, stream>>>(qh, khH, vhH, keep, part);
    reduce_part<<<dim3((B_ * QP_ * DIM_ / 4 + 255) / 256), blk, 0, stream>>>(part, opre);
    gemm_nt<<<dim3((B_ * QP_ + GM - 1) / GM, DIM_ / GN), blk, 0, stream>>>(
        opre, Wo, out, B_ * QP_, bo);
  } else {
    // fp32 fallback (small workspace)
    off = common_off;
    float* kh = (float*)alloc((size_t)B_ * K_ * DIM_ * 4);
    float* vh = (float*)alloc((size_t)B_ * K_ * DIM_ * 4);
    float* part = (float*)alloc((size_t)PSPL * B_ * QP_ * DIM_ * 4);
    gemm_nt<<<dim3(B_ * K_ / GM, DIM_ / GN), blk, 0, stream>>>(k, Wk, kh, B_ * K_, nullptr);
    gemm_nt<<<dim3(B_ * K_ / GM, DIM_ / GN), blk, 0, stream>>>(v, Wv, vh, B_ * K_, nullptr);
    gemm_nt<<<dim3(B_ * Q_ / GM, DIM_ / GN), blk, 0, stream>>>(q, Wq, qh, B_ * Q_, nullptr);
    pass_a<<<dim3(B_ * H_ * KSPLIT), blk, 0, stream>>>(qh, kh, sbuf);
    topk_kernel<<<dim3(B_), dim3(64), 0, stream>>>(sbuf, keep, keepf);
    pass_b<<<dim3(B_ * H_ * PSPL), blk, 0, stream>>>(qh, kh, vh, keep, part);
    reduce_part<<<dim3((B_ * QP_ * DIM_ / 4 + 255) / 256), blk, 0, stream>>>(part, opre);
    gemm_nt<<<dim3((B_ * QP_ + GM - 1) / GM, DIM_ / GN), blk, 0, stream>>>(
        opre, Wo, out, B_ * QP_, bo);
  }
}